// Round 6
// baseline (983.107 us; speedup 1.0000x reference)
//
#include <hip/hip_runtime.h>
#include <hip/hip_bf16.h>

#define B 16
#define V 1024
#define D 16
#define E 64
#define F 16
#define H 128
#define HD 64
#define BV (B*V)      // 16384
#define BVD (B*V*D)   // 262144

// ---- workspace layout (float offsets) ----
#define OFF_NODE_ENC 0
#define OFF_HBF      (OFF_NODE_ENC + BV*H)         // h edge states bf16 (BVD*H shorts = BVD*H/2 floats)
#define OFF_NMSG     (OFF_HBF + BVD*H/2)
#define OFF_NS       (OFF_NMSG + BV*H)             // node_states fp32 (B,V,H)
#define OFF_EMB      (OFF_NS + BV*H)
#define OFF_NW       (OFF_EMB + V*E)
#define OFF_DATTN    (OFF_NW + BVD)
#define OFF_NORM     (OFF_DATTN + BVD)
#define OFF_FLOWA    (OFF_NORM + BVD)
#define OFF_DV       (OFF_FLOWA + BVD)
#define OFF_ACC      (OFF_DV + BV)                 // [0:16) flow_cost, [16:32) dual, [32:48) dual_demand
#define OFF_WT       (OFF_ACC + 64)                // 512x256 bf16 GRU weights = 65536 floats
#define OFF_WTG      (OFF_WT + 65536)              // 128x128 bf16 GAT weights = 8192 floats
#define OFF_WTD      (OFF_WTG + 8192)              // 64x256  bf16 dec weights = 8192 floats

typedef __attribute__((ext_vector_type(8))) short bf16x8;
typedef __attribute__((ext_vector_type(4))) float f32x4;

__device__ __forceinline__ short f2bf(float f){
  __hip_bfloat16 b = __float2bfloat16(f);
  return *reinterpret_cast<short*>(&b);
}
__device__ __forceinline__ float bf2f(short s){
  __hip_bfloat16 b; *reinterpret_cast<short*>(&b) = s;
  return __bfloat162float(b);
}
__device__ __forceinline__ float frcp(float x){ return __builtin_amdgcn_rcpf(x); }
__device__ __forceinline__ float fsig(float x){ return frcp(1.f + __expf(-x)); }
__device__ __forceinline__ float ftanh(float x){
  float e = __expf(-2.f*fabsf(x));
  float r = (1.f - e)*frcp(1.f + e);
  return copysignf(r, x);
}

// ---- merged prep: GRU/GAT/dec weight packs + embnorm + acc zero ----
__global__ __launch_bounds__(256) void k_prep(const float* __restrict__ Wx, const float* __restrict__ Wh,
    const float* __restrict__ Wg, const float* __restrict__ W1, const float* __restrict__ emb,
    short* __restrict__ Wt, short* __restrict__ Wgt, short* __restrict__ W1t,
    float* __restrict__ embn, float* __restrict__ acc){
  int bid = blockIdx.x, tid = threadIdx.x;
  if (bid < 512){
    int n = bid, k = tid;
    int g = n >> 7, j = n & 127;
    float v;
    if (g == 0)      v = (k < 128) ? Wx[k*384 + j]       : Wh[(k-128)*384 + j];
    else if (g == 1) v = (k < 128) ? Wx[k*384 + 128 + j] : Wh[(k-128)*384 + 128 + j];
    else if (g == 2) v = (k < 128) ? Wx[k*384 + 256 + j] : 0.f;
    else             v = (k < 128) ? 0.f                 : Wh[(k-128)*384 + 256 + j];
    Wt[n*256 + k] = f2bf(v);
  } else if (bid < 576){
    int idx = (bid-512)*256 + tid;
    int n = idx >> 7, k = idx & 127;
    Wgt[n*128 + k] = f2bf(Wg[k*128 + n]);
  } else if (bid < 640){
    int n = bid - 576, k = tid;
    W1t[n*256 + k] = f2bf(W1[k*64 + n]);
  } else if (bid < 896){
    int v = (bid-640)*4 + (tid >> 6);
    int e = tid & 63;
    float val = emb[v*E + e];
    float ss = val*val;
    #pragma unroll
    for (int off=32; off>0; off>>=1) ss += __shfl_down(ss, off);
    ss = __shfl(ss, 0);
    embn[v*E + e] = val * frcp(fmaxf(sqrtf(ss), 1.f));
  } else {
    if (tid < 64) acc[tid] = 0.f;
  }
}

// node_enc = [emb_n | node_features] @ W_enc + b_enc   (M=BV, K=80, N=128)
__global__ __launch_bounds__(256) void k_enc(const float* __restrict__ embn, const float* __restrict__ nf,
                                             const float* __restrict__ Wenc, const float* __restrict__ benc,
                                             float* __restrict__ ne){
  __shared__ float As[16][80];
  int tid = threadIdx.x;
  int m0 = blockIdx.x*16;
  for (int idx=tid; idx<16*80; idx+=256){
    int i = idx/80, k = idx%80;
    int m = m0 + i; int v = m & (V-1);
    As[i][k] = (k < E) ? embn[v*E + k] : nf[m*F + (k-E)];
  }
  __syncthreads();
  int c = tid & 127, half = tid >> 7;
  float acc[8] = {0,0,0,0,0,0,0,0};
  for (int kk=0; kk<80; kk+=4){
    float w[4];
    #pragma unroll
    for (int u=0;u<4;u++) w[u] = Wenc[(kk+u)*H + c];
    #pragma unroll
    for (int i=0;i<8;i++){
      const float4 av = *reinterpret_cast<const float4*>(&As[half*8+i][kk]);
      acc[i] += av.x*w[0] + av.y*w[1] + av.z*w[2] + av.w*w[3];
    }
  }
  float bb = benc[c];
  #pragma unroll
  for (int i=0;i<8;i++){
    int m = m0 + half*8 + i;
    ne[m*H + c] = acc[i] + bb;
  }
}

// MFMA DirectionalGAT: wave-per-node. layer0: gather ne fp32 via adj; layer1: h bf16 direct copy.
__global__ __launch_bounds__(256) void k_gat_mfma(const float* __restrict__ ne, const short* __restrict__ hbf,
    const int* __restrict__ adj, const short* __restrict__ Wgt, const float* __restrict__ bg,
    const float* __restrict__ ag, float* __restrict__ nmsg, int gather0){
  __shared__ short As[4][16][136];
  int tid = threadIdx.x;
  int w = tid >> 6, lane = tid & 63;
  int node = blockIdx.x*4 + w;
  int b = node >> 10;
  if (gather0){
    #pragma unroll
    for (int e=0;e<8;e++){
      int idx = e*64 + lane;          // 512 float4s
      int r = idx >> 5, j4 = idx & 31;
      int a = adj[node*16 + r];
      float4 v = *reinterpret_cast<const float4*>(&ne[(long)(((b<<10) + a))*128 + j4*4]);
      short4 s; s.x=f2bf(v.x); s.y=f2bf(v.y); s.z=f2bf(v.z); s.w=f2bf(v.w);
      *reinterpret_cast<short4*>(&As[w][r][j4*4]) = s;
    }
  } else {
    #pragma unroll
    for (int e=0;e<4;e++){
      int idx = e*64 + lane;          // 256 bf16x8 chunks
      int r = idx >> 4, c8 = idx & 15;
      bf16x8 v = *reinterpret_cast<const bf16x8*>(&hbf[(long)(node*16 + r)*128 + c8*8]);
      *reinterpret_cast<bf16x8*>(&As[w][r][c8*8]) = v;
    }
  }
  __syncthreads();
  int l15 = lane & 15, quad = lane >> 4;
  f32x4 acc[8];
  #pragma unroll
  for (int u=0;u<8;u++) acc[u] = (f32x4){0.f,0.f,0.f,0.f};
  #pragma unroll
  for (int kc=0; kc<4; kc++){
    int k0 = kc*32;
    bf16x8 a = *reinterpret_cast<const bf16x8*>(&As[w][l15][k0 + quad*8]);
    #pragma unroll
    for (int u=0;u<8;u++){
      bf16x8 bfr = *reinterpret_cast<const bf16x8*>(&Wgt[(16*u + l15)*128 + k0 + quad*8]);
      acc[u] = __builtin_amdgcn_mfma_f32_16x16x32_bf16(a, bfr, acc[u], 0,0,0);
    }
  }
  float tv[8][4];
  float lp[4] = {0.f,0.f,0.f,0.f};
  #pragma unroll
  for (int u=0;u<8;u++){
    int c = 16*u + l15;
    float bgc = bg[c], agc = ag[c];
    #pragma unroll
    for (int reg=0;reg<4;reg++){
      float t = ftanh(acc[u][reg] + bgc);
      tv[u][reg] = t;
      lp[reg] += t * agc;
    }
  }
  #pragma unroll
  for (int reg=0;reg<4;reg++){
    lp[reg] += __shfl_xor(lp[reg], 1);
    lp[reg] += __shfl_xor(lp[reg], 2);
    lp[reg] += __shfl_xor(lp[reg], 4);
    lp[reg] += __shfl_xor(lp[reg], 8);
  }
  float m4 = fmaxf(fmaxf(lp[0],lp[1]), fmaxf(lp[2],lp[3]));
  m4 = fmaxf(m4, __shfl_xor(m4, 16));
  m4 = fmaxf(m4, __shfl_xor(m4, 32));
  float e4[4]; float s4 = 0.f;
  #pragma unroll
  for (int reg=0;reg<4;reg++){ e4[reg] = __expf(lp[reg]-m4); s4 += e4[reg]; }
  s4 += __shfl_xor(s4, 16);
  s4 += __shfl_xor(s4, 32);
  float inv = frcp(s4);
  #pragma unroll
  for (int reg=0;reg<4;reg++) e4[reg] *= inv;
  #pragma unroll
  for (int u=0;u<8;u++){
    float mp = e4[0]*tv[u][0] + e4[1]*tv[u][1] + e4[2]*tv[u][2] + e4[3]*tv[u][3];
    mp += __shfl_xor(mp, 16);
    mp += __shfl_xor(mp, 32);
    if (quad == 0) nmsg[node*128 + 16*u + l15] = mp;
  }
}

// MFMA GRU: 64 edge-rows/block. h stored bf16. Layer1 epilogue also emits node_states.
__global__ __launch_bounds__(256) void k_gru_mfma(const float* __restrict__ ne, const float* __restrict__ nmsg,
    const int* __restrict__ adj, const short* __restrict__ Wt, const float* __restrict__ bgru,
    short* __restrict__ hbf, float* __restrict__ ns_, int layer0){
  __shared__ short As[64][264];
  int tid = threadIdx.x;
  int ge0 = blockIdx.x*64;
  // x-half (and layer0 h-half) from gathered nmsg+ne fp32
  #pragma unroll
  for (int e=0;e<8;e++){
    int idx = e*256 + tid;          // 2048 float4 chunks
    int r = idx >> 5, j4 = idx & 31;
    int ge = ge0 + r;
    int nv = ge >> 4, d = ge & 15;
    int a = adj[nv*16 + d];
    long srow = (long)(((nv >> 10)<<10) + a)*128;
    float4 m4 = *reinterpret_cast<const float4*>(&nmsg[srow + j4*4]);
    float4 e4 = *reinterpret_cast<const float4*>(&ne[srow + j4*4]);
    short4 s;
    s.x = f2bf(ftanh(m4.x+e4.x)); s.y = f2bf(ftanh(m4.y+e4.y));
    s.z = f2bf(ftanh(m4.z+e4.z)); s.w = f2bf(ftanh(m4.w+e4.w));
    *reinterpret_cast<short4*>(&As[r][j4*4]) = s;
    if (layer0){
      short4 sh; sh.x=f2bf(e4.x); sh.y=f2bf(e4.y); sh.z=f2bf(e4.z); sh.w=f2bf(e4.w);
      *reinterpret_cast<short4*>(&As[r][128 + j4*4]) = sh;
    }
  }
  if (!layer0){
    #pragma unroll
    for (int e=0;e<4;e++){
      int idx = e*256 + tid;        // 1024 bf16x8 chunks
      int r = idx >> 4, c8 = idx & 15;
      bf16x8 v = *reinterpret_cast<const bf16x8*>(&hbf[(long)(ge0 + r)*128 + c8*8]);
      *reinterpret_cast<bf16x8*>(&As[r][128 + c8*8]) = v;
    }
  }
  __syncthreads();
  int w = tid >> 6, lane = tid & 63;
  int l15 = lane & 15, quad = lane >> 4;
  f32x4 acc[4][4][2];
  #pragma unroll
  for (int mt=0;mt<4;mt++)
    #pragma unroll
    for (int g=0;g<4;g++)
      #pragma unroll
      for (int u=0;u<2;u++) acc[mt][g][u] = (f32x4){0.f,0.f,0.f,0.f};

  for (int k8=0;k8<8;k8++){
    int k0 = k8*32;
    int gg = (k8 < 4) ? 2 : 3;
    bf16x8 a[4];
    #pragma unroll
    for (int mt=0;mt<4;mt++)
      a[mt] = *reinterpret_cast<const bf16x8*>(&As[16*mt + l15][k0 + quad*8]);
    bf16x8 bz[2], br[2], bc[2];
    #pragma unroll
    for (int u=0;u<2;u++){
      int ncol = 32*w + 16*u + l15;
      int koff = k0 + quad*8;
      bz[u] = *reinterpret_cast<const bf16x8*>(&Wt[(ncol      )*256 + koff]);
      br[u] = *reinterpret_cast<const bf16x8*>(&Wt[(ncol + 128)*256 + koff]);
      bc[u] = *reinterpret_cast<const bf16x8*>(&Wt[(ncol + gg*128)*256 + koff]);
    }
    #pragma unroll
    for (int mt=0;mt<4;mt++){
      #pragma unroll
      for (int u=0;u<2;u++){
        acc[mt][0][u]  = __builtin_amdgcn_mfma_f32_16x16x32_bf16(a[mt], bz[u], acc[mt][0][u], 0,0,0);
        acc[mt][1][u]  = __builtin_amdgcn_mfma_f32_16x16x32_bf16(a[mt], br[u], acc[mt][1][u], 0,0,0);
        acc[mt][gg][u] = __builtin_amdgcn_mfma_f32_16x16x32_bf16(a[mt], bc[u], acc[mt][gg][u], 0,0,0);
      }
    }
  }
  #pragma unroll
  for (int u=0;u<2;u++){
    int j = 32*w + 16*u + l15;
    float bjz = bgru[j], bjr = bgru[128 + j], bjc = bgru[256 + j];
    #pragma unroll
    for (int mt=0;mt<4;mt++){
      float psum = 0.f;
      #pragma unroll
      for (int reg=0;reg<4;reg++){
        int rl = 16*mt + quad*4 + reg;
        float z = fsig(acc[mt][0][u][reg] + bjz);
        float r = fsig(acc[mt][1][u][reg] + bjr);
        float cand = ftanh(acc[mt][2][u][reg] + bjc + r*acc[mt][3][u][reg]);
        float ho = bf2f(As[rl][128 + j]);
        float hn = z*ho + (1.f - z)*cand;
        hbf[(long)(ge0 + rl)*128 + j] = f2bf(hn);
        psum += hn;
      }
      if (!layer0){
        psum += __shfl_xor(psum, 16);
        psum += __shfl_xor(psum, 32);
        if (quad == 0) ns_[(long)((ge0 >> 4) + mt)*128 + j] = psum;
      }
    }
  }
}

// MFMA decoder: wave-per-16-edges, h bf16 input.
__global__ __launch_bounds__(256) void k_dec_mfma(const short* __restrict__ hbf, const int* __restrict__ adj,
    const short* __restrict__ W1t, const float* __restrict__ b1, const float* __restrict__ W2,
    const float* __restrict__ b2_, float* __restrict__ nw){
  __shared__ short Ds[4][16][264];
  int tid = threadIdx.x;
  int w = tid >> 6, lane = tid & 63;
  int ge0 = blockIdx.x*64 + w*16;
  #pragma unroll
  for (int e=0;e<4;e++){
    int idx = e*64 + lane;          // 256 bf16x8 chunks
    int r = idx >> 4, c8 = idx & 15;
    int ge = ge0 + r;
    int nv = ge >> 4, d = ge & 15, b = nv >> 10;
    int a = adj[nv*16 + d];
    long opp = (long)(((b<<10) + a)*16 + (d^1))*128;
    bf16x8 ov = *reinterpret_cast<const bf16x8*>(&hbf[(long)ge*128 + c8*8]);
    bf16x8 pv = *reinterpret_cast<const bf16x8*>(&hbf[opp + c8*8]);
    *reinterpret_cast<bf16x8*>(&Ds[w][r][c8*8]) = ov;
    bf16x8 sv;
    #pragma unroll
    for (int q=0;q<8;q++) sv[q] = f2bf(bf2f(ov[q]) + bf2f(pv[q]));
    *reinterpret_cast<bf16x8*>(&Ds[w][r][128 + c8*8]) = sv;
  }
  __syncthreads();
  int l15 = lane & 15, quad = lane >> 4;
  f32x4 acc[4];
  #pragma unroll
  for (int u=0;u<4;u++) acc[u] = (f32x4){0.f,0.f,0.f,0.f};
  #pragma unroll
  for (int kc=0;kc<8;kc++){
    int k0 = kc*32;
    bf16x8 av = *reinterpret_cast<const bf16x8*>(&Ds[w][l15][k0 + quad*8]);
    #pragma unroll
    for (int u=0;u<4;u++){
      bf16x8 bfr = *reinterpret_cast<const bf16x8*>(&W1t[(16*u + l15)*256 + k0 + quad*8]);
      acc[u] = __builtin_amdgcn_mfma_f32_16x16x32_bf16(av, bfr, acc[u], 0,0,0);
    }
  }
  float p[4] = {0.f,0.f,0.f,0.f};
  #pragma unroll
  for (int u=0;u<4;u++){
    int c = 16*u + l15;
    float bc = b1[c], wc = W2[c];
    #pragma unroll
    for (int reg=0;reg<4;reg++) p[reg] += ftanh(acc[u][reg] + bc) * wc;
  }
  #pragma unroll
  for (int reg=0;reg<4;reg++){
    p[reg] += __shfl_xor(p[reg], 1);
    p[reg] += __shfl_xor(p[reg], 2);
    p[reg] += __shfl_xor(p[reg], 4);
    p[reg] += __shfl_xor(p[reg], 8);
  }
  if (l15 == 0){
    float b2v = b2_[0];
    #pragma unroll
    for (int reg=0;reg<4;reg++) nw[ge0 + quad*4 + reg] = p[reg] + b2v;
  }
}

// dest_attn = softmax_d( nw[b, inv_adj[v,d], d] )
__global__ __launch_bounds__(256) void k_dattn(const float* __restrict__ nw, const int* __restrict__ invadj,
                                               float* __restrict__ dattn){
  int node = blockIdx.x*256 + threadIdx.x;
  if (node >= BV) return;
  int b = node >> 10;
  float vals[16];
  #pragma unroll
  for (int d=0; d<16; d++){
    int ia = invadj[node*D + d];
    vals[d] = nw[(b*V + ia)*D + d];
  }
  float m = vals[0];
  #pragma unroll
  for (int d=1; d<16; d++) m = fmaxf(m, vals[d]);
  float s = 0.f;
  #pragma unroll
  for (int d=0; d<16; d++){ vals[d] = __expf(vals[d]-m); s += vals[d]; }
  float inv = frcp(s);
  #pragma unroll
  for (int d=0; d<16; d++) dattn[node*D + d] = vals[d]*inv;
}

// normalized = sparsemax_d( dattn[b, adj[v,d], d] )
__global__ __launch_bounds__(256) void k_sparse(const float* __restrict__ dattn, const int* __restrict__ adj,
                                                float* __restrict__ norm_){
  int node = blockIdx.x*256 + threadIdx.x;
  if (node >= BV) return;
  int b = node >> 10;
  float z[16], s[16];
  #pragma unroll
  for (int d=0; d<16; d++){
    int a = adj[node*D + d];
    z[d] = dattn[(b*V + a)*D + d];
    s[d] = z[d];
  }
  #pragma unroll
  for (int k2 = 2; k2 <= 16; k2 <<= 1){
    #pragma unroll
    for (int jj = k2 >> 1; jj > 0; jj >>= 1){
      #pragma unroll
      for (int i = 0; i < 16; i++){
        int l = i ^ jj;
        if (l > i){
          bool up = ((i & k2) == 0);
          float a = s[i], bb = s[l];
          bool sw = up ? (a > bb) : (a < bb);
          if (sw){ s[i]=bb; s[l]=a; }
        }
      }
    }
  }
  float cs = 0.f, zcs = 0.f; int kz = 1;
  #pragma unroll
  for (int j=0;j<16;j++){
    float zj = s[15-j];
    cs += zj;
    if (1.f + (float)(j+1)*zj > cs){ kz = j+1; zcs = cs; }
  }
  float tau = (zcs - 1.f)/(float)kz;
  #pragma unroll
  for (int d=0; d<16; d++) norm_[node*D + d] = fmaxf(z[d]-tau, 0.f);
}

// all 10 MCF iterations fused: one block per batch, flow in LDS d-major.
__global__ __launch_bounds__(1024) void k_flow_fused(const float* __restrict__ norm_,
    const float* __restrict__ dem, const int* __restrict__ invadj, float* __restrict__ flowout){
  __shared__ float fl[D*V];
  int b = blockIdx.x, v = threadIdx.x;
  int base = ((b << 10) + v)*D;
  int ia[16]; float nr[16];
  #pragma unroll
  for (int d4=0; d4<4; d4++){
    int4 i4 = reinterpret_cast<const int4*>(&invadj[base])[d4];
    ia[d4*4+0]=i4.x; ia[d4*4+1]=i4.y; ia[d4*4+2]=i4.z; ia[d4*4+3]=i4.w;
    float4 n4 = reinterpret_cast<const float4*>(&norm_[base])[d4];
    nr[d4*4+0]=n4.x; nr[d4*4+1]=n4.y; nr[d4*4+2]=n4.z; nr[d4*4+3]=n4.w;
  }
  float dm = dem[(b<<10) + v];
  #pragma unroll
  for (int d=0; d<16; d++) fl[d*V + v] = 0.f;
  __syncthreads();
  float s = 0.f;
  for (int it=0; it<10; it++){
    float inflow = 0.f;
    #pragma unroll
    for (int d=0; d<16; d++) inflow += fl[d*V + ia[d]];
    __syncthreads();
    s = fmaxf(inflow - dm, 0.f);
    #pragma unroll
    for (int d=0; d<16; d++) fl[d*V + v] = nr[d]*s;
    __syncthreads();
  }
  #pragma unroll
  for (int d4=0; d4<4; d4++){
    float4 o;
    o.x = nr[d4*4+0]*s; o.y = nr[d4*4+1]*s; o.z = nr[d4*4+2]*s; o.w = nr[d4*4+3]*s;
    reinterpret_cast<float4*>(&flowout[base])[d4] = o;
  }
}

// dual_vars from precomputed node_states (8 MB) — 1 wave per node
__global__ __launch_bounds__(64) void k_dualvars(const float* __restrict__ ns_, const float* __restrict__ W1,
    const float* __restrict__ b1, const float* __restrict__ W2, const float* __restrict__ b2_,
    const float* __restrict__ dem, float* __restrict__ dv, float* __restrict__ accdd){
  __shared__ float ns[128];
  int node = blockIdx.x; int b = node >> 10;
  int tid = threadIdx.x;
  ns[tid]      = ns_[(long)node*128 + tid];
  ns[tid + 64] = ns_[(long)node*128 + 64 + tid];
  __syncthreads();
  float acc = 0.f;
  #pragma unroll 8
  for (int k=0;k<128;k++) acc += ns[k]*W1[k*HD + tid];
  float t = ftanh(acc + b1[tid]) * W2[tid];
  #pragma unroll
  for (int off=32; off>0; off>>=1) t += __shfl_down(t, off);
  if (tid == 0){
    float val = fmaxf(t + b2_[0], 0.f);
    dv[node] = val;
    atomicAdd(&accdd[b], val * dem[node]);
  }
}

// flow cost + dual flow iterations + dual cost
__global__ __launch_bounds__(256) void k_cost(const float* __restrict__ flow, const float* __restrict__ dv,
    const int* __restrict__ adj, float* __restrict__ accF, float* __restrict__ accD){
  int gid = blockIdx.x*256 + threadIdx.x;
  int b = gid >> 14;
  int a = adj[gid];
  float diff = dv[b*V + a];
  float f = 0.f, vel = 0.f;
  #pragma unroll
  for (int it=0; it<10; it++){
    float g = 2.f*f + diff;
    vel = 0.9f*vel - 0.01f*g;
    f = fmaxf(f + vel, 0.f);
  }
  float cd = f*f + diff*f;
  float fl = flow[gid];
  float cf = fl*fl;
  #pragma unroll
  for (int off=32; off>0; off>>=1){ cd += __shfl_down(cd, off); cf += __shfl_down(cf, off); }
  __shared__ float r1[4], r2[4];
  int lane = threadIdx.x & 63, w = threadIdx.x >> 6;
  if (lane==0){ r1[w]=cf; r2[w]=cd; }
  __syncthreads();
  if (threadIdx.x==0){
    atomicAdd(&accF[b], r1[0]+r1[1]+r1[2]+r1[3]);
    atomicAdd(&accD[b], r2[0]+r2[1]+r2[2]+r2[3]);
  }
}

__global__ __launch_bounds__(64) void k_final(const float* __restrict__ acc, float* __restrict__ out){
  int b = threadIdx.x;
  if (b < B){
    float fc = acc[b], dc = acc[16+b], dd = acc[32+b];
    out[b] = fc - (dc - dd);
  }
}

extern "C" void kernel_launch(void* const* d_in, const int* in_sizes, int n_in,
                              void* d_out, int out_size, void* d_ws, size_t ws_size,
                              hipStream_t stream){
  (void)in_sizes; (void)n_in; (void)out_size; (void)ws_size;
  const float* demands = (const float*)d_in[0];
  const float* nf      = (const float*)d_in[1];
  const float* emb     = (const float*)d_in[4];
  const float* Wenc    = (const float*)d_in[5];
  const float* benc    = (const float*)d_in[6];
  const float* Wgat    = (const float*)d_in[7];
  const float* bgat    = (const float*)d_in[8];
  const float* agat    = (const float*)d_in[9];
  const float* Wgx     = (const float*)d_in[10];
  const float* Wgh     = (const float*)d_in[11];
  const float* bgru    = (const float*)d_in[12];
  const float* Wd1     = (const float*)d_in[13];
  const float* bd1     = (const float*)d_in[14];
  const float* Wd2     = (const float*)d_in[15];
  const float* bd2     = (const float*)d_in[16];
  const float* Wu1     = (const float*)d_in[17];
  const float* bu1     = (const float*)d_in[18];
  const float* Wu2     = (const float*)d_in[19];
  const float* bu2     = (const float*)d_in[20];
  const int* adj       = (const int*)d_in[21];
  const int* invadj    = (const int*)d_in[22];

  float* ws    = (float*)d_ws;
  float* ne    = ws + OFF_NODE_ENC;
  short* hbf   = (short*)(ws + OFF_HBF);
  float* nmsg  = ws + OFF_NMSG;
  float* nst   = ws + OFF_NS;
  float* embn  = ws + OFF_EMB;
  float* nw    = ws + OFF_NW;
  float* dattn = ws + OFF_DATTN;
  float* nrm   = ws + OFF_NORM;
  float* fa    = ws + OFF_FLOWA;
  float* dv    = ws + OFF_DV;
  float* acc   = ws + OFF_ACC;
  short* wt    = (short*)(ws + OFF_WT);
  short* wtg   = (short*)(ws + OFF_WTG);
  short* wtd   = (short*)(ws + OFF_WTD);

  k_prep<<<897, 256, 0, stream>>>(Wgx, Wgh, Wgat, Wd1, emb, wt, wtg, wtd, embn, acc);
  k_enc<<<BV/16, 256, 0, stream>>>(embn, nf, Wenc, benc, ne);
  // layer 0: h == gather(ne, adj) — read ne directly
  k_gat_mfma<<<BV/4, 256, 0, stream>>>(ne, hbf, adj, wtg, bgat, agat, nmsg, 1);
  k_gru_mfma<<<BVD/64, 256, 0, stream>>>(ne, nmsg, adj, wt, bgru, hbf, nst, 1);
  // layer 1
  k_gat_mfma<<<BV/4, 256, 0, stream>>>(ne, hbf, adj, wtg, bgat, agat, nmsg, 0);
  k_gru_mfma<<<BVD/64, 256, 0, stream>>>(ne, nmsg, adj, wt, bgru, hbf, nst, 0);
  k_dec_mfma<<<BVD/64, 256, 0, stream>>>(hbf, adj, wtd, bd1, Wd2, bd2, nw);
  k_dattn<<<BV/256, 256, 0, stream>>>(nw, invadj, dattn);
  k_sparse<<<BV/256, 256, 0, stream>>>(dattn, adj, nrm);
  k_flow_fused<<<B, 1024, 0, stream>>>(nrm, demands, invadj, fa);
  k_dualvars<<<BV, 64, 0, stream>>>(nst, Wu1, bu1, Wu2, bu2, demands, dv, acc+32);
  k_cost<<<BVD/256, 256, 0, stream>>>(fa, dv, adj, acc, acc+16);
  k_final<<<1, 64, 0, stream>>>(acc, (float*)d_out);
}

// Round 7
// 819.960 us; speedup vs baseline: 1.1990x; 1.1990x over previous
//
#include <hip/hip_runtime.h>
#include <hip/hip_bf16.h>

#define B 16
#define V 1024
#define D 16
#define E 64
#define F 16
#define H 128
#define HD 64
#define BV (B*V)      // 16384
#define BVD (B*V*D)   // 262144

// ---- workspace layout (float offsets) ----
#define OFF_NEBF     0                             // node_enc bf16 (BV*H shorts)
#define OFF_XN       (OFF_NEBF + BV*H/2)           // xnode bf16 (BV*H shorts)
#define OFF_HBF      (OFF_XN + BV*H/2)             // h edge states bf16 (BVD*H shorts)
#define OFF_NS       (OFF_HBF + BVD*H/2)           // node_states fp32 (B,V,H)
#define OFF_EMB      (OFF_NS + BV*H)
#define OFF_NW       (OFF_EMB + V*E)
#define OFF_DATTN    (OFF_NW + BVD)
#define OFF_NORM     (OFF_DATTN + BVD)
#define OFF_FLOWA    (OFF_NORM + BVD)
#define OFF_DV       (OFF_FLOWA + BVD)
#define OFF_ACC      (OFF_DV + BV)                 // [0:16) flow_cost, [16:32) dual, [32:48) dual_demand
#define OFF_WT       (OFF_ACC + 64)                // 512x256 bf16 GRU weights = 65536 floats
#define OFF_WTG      (OFF_WT + 65536)              // 128x128 bf16 GAT weights = 8192 floats
#define OFF_WTD      (OFF_WTG + 8192)              // 64x256  bf16 dec weights = 8192 floats

typedef __attribute__((ext_vector_type(8))) short bf16x8;
typedef __attribute__((ext_vector_type(4))) float f32x4;

__device__ __forceinline__ short f2bf(float f){
  __hip_bfloat16 b = __float2bfloat16(f);
  return *reinterpret_cast<short*>(&b);
}
__device__ __forceinline__ float bf2f(short s){
  __hip_bfloat16 b; *reinterpret_cast<short*>(&b) = s;
  return __bfloat162float(b);
}
__device__ __forceinline__ float frcp(float x){ return __builtin_amdgcn_rcpf(x); }
__device__ __forceinline__ float fsig(float x){ return frcp(1.f + __expf(-x)); }
__device__ __forceinline__ float ftanh(float x){
  float e = __expf(-2.f*fabsf(x));
  float r = (1.f - e)*frcp(1.f + e);
  return copysignf(r, x);
}

// ---- merged prep: GRU/GAT/dec weight packs + embnorm + acc zero ----
__global__ __launch_bounds__(256) void k_prep(const float* __restrict__ Wx, const float* __restrict__ Wh,
    const float* __restrict__ Wg, const float* __restrict__ W1, const float* __restrict__ emb,
    short* __restrict__ Wt, short* __restrict__ Wgt, short* __restrict__ W1t,
    float* __restrict__ embn, float* __restrict__ acc){
  int bid = blockIdx.x, tid = threadIdx.x;
  if (bid < 512){
    int n = bid, k = tid;
    int g = n >> 7, j = n & 127;
    float v;
    if (g == 0)      v = (k < 128) ? Wx[k*384 + j]       : Wh[(k-128)*384 + j];
    else if (g == 1) v = (k < 128) ? Wx[k*384 + 128 + j] : Wh[(k-128)*384 + 128 + j];
    else if (g == 2) v = (k < 128) ? Wx[k*384 + 256 + j] : 0.f;
    else             v = (k < 128) ? 0.f                 : Wh[(k-128)*384 + 256 + j];
    Wt[n*256 + k] = f2bf(v);
  } else if (bid < 576){
    int idx = (bid-512)*256 + tid;
    int n = idx >> 7, k = idx & 127;
    Wgt[n*128 + k] = f2bf(Wg[k*128 + n]);
  } else if (bid < 640){
    int n = bid - 576, k = tid;
    W1t[n*256 + k] = f2bf(W1[k*64 + n]);
  } else if (bid < 896){
    int v = (bid-640)*4 + (tid >> 6);
    int e = tid & 63;
    float val = emb[v*E + e];
    float ss = val*val;
    #pragma unroll
    for (int off=32; off>0; off>>=1) ss += __shfl_down(ss, off);
    ss = __shfl(ss, 0);
    embn[v*E + e] = val * frcp(fmaxf(sqrtf(ss), 1.f));
  } else {
    if (tid < 64) acc[tid] = 0.f;
  }
}

// node_enc = [emb_n | node_features] @ W_enc + b_enc -> bf16  (M=BV, K=80, N=128)
__global__ __launch_bounds__(256) void k_enc(const float* __restrict__ embn, const float* __restrict__ nf,
                                             const float* __restrict__ Wenc, const float* __restrict__ benc,
                                             short* __restrict__ nebf){
  __shared__ float As[16][80];
  int tid = threadIdx.x;
  int m0 = blockIdx.x*16;
  for (int idx=tid; idx<16*80; idx+=256){
    int i = idx/80, k = idx%80;
    int m = m0 + i; int v = m & (V-1);
    As[i][k] = (k < E) ? embn[v*E + k] : nf[m*F + (k-E)];
  }
  __syncthreads();
  int c = tid & 127, half = tid >> 7;
  float acc[8] = {0,0,0,0,0,0,0,0};
  for (int kk=0; kk<80; kk+=4){
    float w[4];
    #pragma unroll
    for (int u=0;u<4;u++) w[u] = Wenc[(kk+u)*H + c];
    #pragma unroll
    for (int i=0;i<8;i++){
      const float4 av = *reinterpret_cast<const float4*>(&As[half*8+i][kk]);
      acc[i] += av.x*w[0] + av.y*w[1] + av.z*w[2] + av.w*w[3];
    }
  }
  float bb = benc[c];
  #pragma unroll
  for (int i=0;i<8;i++){
    int m = m0 + half*8 + i;
    nebf[m*H + c] = f2bf(acc[i] + bb);
  }
}

// MFMA DirectionalGAT: wave-per-node. Emits xnode = tanh(node_msg + node_enc) bf16.
// layer0: stage gather(nebf, adj); layer1: stage hbf copy.
__global__ __launch_bounds__(256) void k_gat_mfma(const short* __restrict__ nebf, const short* __restrict__ hbf,
    const int* __restrict__ adj, const short* __restrict__ Wgt, const float* __restrict__ bg,
    const float* __restrict__ ag, short* __restrict__ xn, int gather0){
  __shared__ short As[4][16][136];
  int tid = threadIdx.x;
  int w = tid >> 6, lane = tid & 63;
  int node = blockIdx.x*4 + w;
  int b = node >> 10;
  #pragma unroll
  for (int e=0;e<4;e++){
    int idx = e*64 + lane;          // 256 bf16x8 chunks
    int r = idx >> 4, c8 = idx & 15;
    bf16x8 v;
    if (gather0){
      int a = adj[node*16 + r];
      v = *reinterpret_cast<const bf16x8*>(&nebf[(long)(((b<<10) + a))*128 + c8*8]);
    } else {
      v = *reinterpret_cast<const bf16x8*>(&hbf[(long)(node*16 + r)*128 + c8*8]);
    }
    *reinterpret_cast<bf16x8*>(&As[w][r][c8*8]) = v;
  }
  __syncthreads();
  int l15 = lane & 15, quad = lane >> 4;
  f32x4 acc[8];
  #pragma unroll
  for (int u=0;u<8;u++) acc[u] = (f32x4){0.f,0.f,0.f,0.f};
  #pragma unroll
  for (int kc=0; kc<4; kc++){
    int k0 = kc*32;
    bf16x8 a = *reinterpret_cast<const bf16x8*>(&As[w][l15][k0 + quad*8]);
    #pragma unroll
    for (int u=0;u<8;u++){
      bf16x8 bfr = *reinterpret_cast<const bf16x8*>(&Wgt[(16*u + l15)*128 + k0 + quad*8]);
      acc[u] = __builtin_amdgcn_mfma_f32_16x16x32_bf16(a, bfr, acc[u], 0,0,0);
    }
  }
  float tv[8][4];
  float lp[4] = {0.f,0.f,0.f,0.f};
  #pragma unroll
  for (int u=0;u<8;u++){
    int c = 16*u + l15;
    float bgc = bg[c], agc = ag[c];
    #pragma unroll
    for (int reg=0;reg<4;reg++){
      float t = ftanh(acc[u][reg] + bgc);
      tv[u][reg] = t;
      lp[reg] += t * agc;
    }
  }
  #pragma unroll
  for (int reg=0;reg<4;reg++){
    lp[reg] += __shfl_xor(lp[reg], 1);
    lp[reg] += __shfl_xor(lp[reg], 2);
    lp[reg] += __shfl_xor(lp[reg], 4);
    lp[reg] += __shfl_xor(lp[reg], 8);
  }
  float m4 = fmaxf(fmaxf(lp[0],lp[1]), fmaxf(lp[2],lp[3]));
  m4 = fmaxf(m4, __shfl_xor(m4, 16));
  m4 = fmaxf(m4, __shfl_xor(m4, 32));
  float e4[4]; float s4 = 0.f;
  #pragma unroll
  for (int reg=0;reg<4;reg++){ e4[reg] = __expf(lp[reg]-m4); s4 += e4[reg]; }
  s4 += __shfl_xor(s4, 16);
  s4 += __shfl_xor(s4, 32);
  float inv = frcp(s4);
  #pragma unroll
  for (int reg=0;reg<4;reg++) e4[reg] *= inv;
  #pragma unroll
  for (int u=0;u<8;u++){
    float mp = e4[0]*tv[u][0] + e4[1]*tv[u][1] + e4[2]*tv[u][2] + e4[3]*tv[u][3];
    mp += __shfl_xor(mp, 16);
    mp += __shfl_xor(mp, 32);
    if (quad == 0){
      int c = 16*u + l15;
      float nev = bf2f(nebf[(long)node*128 + c]);
      xn[(long)node*128 + c] = f2bf(ftanh(mp + nev));
    }
  }
}

// MFMA GRU: 64 edge-rows/block. A=[xnode gathered | h] all-bf16 copy staging.
// Epilogue: gates -> hn into LDS x-half -> coalesced bf16x8 store. Layer1 emits node_states.
__global__ __launch_bounds__(256) void k_gru_mfma(const short* __restrict__ xn, const short* __restrict__ hsrc,
    const int* __restrict__ adj, const short* __restrict__ Wt, const float* __restrict__ bgru,
    short* __restrict__ hbf, float* __restrict__ ns_, int layer0){
  __shared__ short As[64][264];
  int tid = threadIdx.x;
  int ge0 = blockIdx.x*64;
  if (layer0){
    #pragma unroll
    for (int e=0;e<4;e++){
      int idx = e*256 + tid;        // 1024 bf16x8 chunks per half
      int r = idx >> 4, c8 = idx & 15;
      int ge = ge0 + r;
      int nv = ge >> 4, d = ge & 15;
      int a = adj[nv*16 + d];
      long srow = (long)(((nv >> 10)<<10) + a)*128;
      *reinterpret_cast<bf16x8*>(&As[r][c8*8])       = *reinterpret_cast<const bf16x8*>(&xn[srow + c8*8]);
      *reinterpret_cast<bf16x8*>(&As[r][128 + c8*8]) = *reinterpret_cast<const bf16x8*>(&hsrc[srow + c8*8]);
    }
  } else {
    #pragma unroll
    for (int e=0;e<4;e++){
      int idx = e*256 + tid;
      int r = idx >> 4, c8 = idx & 15;
      int ge = ge0 + r;
      int nv = ge >> 4, d = ge & 15;
      int a = adj[nv*16 + d];
      long srow = (long)(((nv >> 10)<<10) + a)*128;
      *reinterpret_cast<bf16x8*>(&As[r][c8*8])       = *reinterpret_cast<const bf16x8*>(&xn[srow + c8*8]);
      *reinterpret_cast<bf16x8*>(&As[r][128 + c8*8]) = *reinterpret_cast<const bf16x8*>(&hsrc[(long)ge*128 + c8*8]);
    }
  }
  __syncthreads();
  int w = tid >> 6, lane = tid & 63;
  int l15 = lane & 15, quad = lane >> 4;
  f32x4 acc[4][4][2];
  #pragma unroll
  for (int mt=0;mt<4;mt++)
    #pragma unroll
    for (int g=0;g<4;g++)
      #pragma unroll
      for (int u=0;u<2;u++) acc[mt][g][u] = (f32x4){0.f,0.f,0.f,0.f};

  for (int k8=0;k8<8;k8++){
    int k0 = k8*32;
    int gg = (k8 < 4) ? 2 : 3;
    bf16x8 a[4];
    #pragma unroll
    for (int mt=0;mt<4;mt++)
      a[mt] = *reinterpret_cast<const bf16x8*>(&As[16*mt + l15][k0 + quad*8]);
    bf16x8 bz[2], br[2], bc[2];
    #pragma unroll
    for (int u=0;u<2;u++){
      int ncol = 32*w + 16*u + l15;
      int koff = k0 + quad*8;
      bz[u] = *reinterpret_cast<const bf16x8*>(&Wt[(ncol      )*256 + koff]);
      br[u] = *reinterpret_cast<const bf16x8*>(&Wt[(ncol + 128)*256 + koff]);
      bc[u] = *reinterpret_cast<const bf16x8*>(&Wt[(ncol + gg*128)*256 + koff]);
    }
    #pragma unroll
    for (int mt=0;mt<4;mt++){
      #pragma unroll
      for (int u=0;u<2;u++){
        acc[mt][0][u]  = __builtin_amdgcn_mfma_f32_16x16x32_bf16(a[mt], bz[u], acc[mt][0][u], 0,0,0);
        acc[mt][1][u]  = __builtin_amdgcn_mfma_f32_16x16x32_bf16(a[mt], br[u], acc[mt][1][u], 0,0,0);
        acc[mt][gg][u] = __builtin_amdgcn_mfma_f32_16x16x32_bf16(a[mt], bc[u], acc[mt][gg][u], 0,0,0);
      }
    }
  }
  __syncthreads();   // all waves done reading As x-half; safe to overwrite with h-out
  #pragma unroll
  for (int u=0;u<2;u++){
    int j = 32*w + 16*u + l15;
    float bjz = bgru[j], bjr = bgru[128 + j], bjc = bgru[256 + j];
    #pragma unroll
    for (int mt=0;mt<4;mt++){
      float psum = 0.f;
      #pragma unroll
      for (int reg=0;reg<4;reg++){
        int rl = 16*mt + quad*4 + reg;
        float z = fsig(acc[mt][0][u][reg] + bjz);
        float r = fsig(acc[mt][1][u][reg] + bjr);
        float cand = ftanh(acc[mt][2][u][reg] + bjc + r*acc[mt][3][u][reg]);
        float ho = bf2f(As[rl][128 + j]);
        float hn = z*ho + (1.f - z)*cand;
        As[rl][j] = f2bf(hn);       // park in x-half for coalesced store
        psum += hn;
      }
      if (!layer0){
        psum += __shfl_xor(psum, 16);
        psum += __shfl_xor(psum, 32);
        if (quad == 0) ns_[(long)((ge0 >> 4) + mt)*128 + j] = psum;
      }
    }
  }
  __syncthreads();
  #pragma unroll
  for (int e=0;e<4;e++){
    int idx = e*256 + tid;
    int r = idx >> 4, c8 = idx & 15;
    *reinterpret_cast<bf16x8*>(&hbf[(long)(ge0 + r)*128 + c8*8]) =
        *reinterpret_cast<const bf16x8*>(&As[r][c8*8]);
  }
}

// MFMA decoder: wave-per-16-edges, h bf16 input.
__global__ __launch_bounds__(256) void k_dec_mfma(const short* __restrict__ hbf, const int* __restrict__ adj,
    const short* __restrict__ W1t, const float* __restrict__ b1, const float* __restrict__ W2,
    const float* __restrict__ b2_, float* __restrict__ nw){
  __shared__ short Ds[4][16][264];
  int tid = threadIdx.x;
  int w = tid >> 6, lane = tid & 63;
  int ge0 = blockIdx.x*64 + w*16;
  #pragma unroll
  for (int e=0;e<4;e++){
    int idx = e*64 + lane;          // 256 bf16x8 chunks
    int r = idx >> 4, c8 = idx & 15;
    int ge = ge0 + r;
    int nv = ge >> 4, d = ge & 15, b = nv >> 10;
    int a = adj[nv*16 + d];
    long opp = (long)(((b<<10) + a)*16 + (d^1))*128;
    bf16x8 ov = *reinterpret_cast<const bf16x8*>(&hbf[(long)ge*128 + c8*8]);
    bf16x8 pv = *reinterpret_cast<const bf16x8*>(&hbf[opp + c8*8]);
    *reinterpret_cast<bf16x8*>(&Ds[w][r][c8*8]) = ov;
    bf16x8 sv;
    #pragma unroll
    for (int q=0;q<8;q++) sv[q] = f2bf(bf2f(ov[q]) + bf2f(pv[q]));
    *reinterpret_cast<bf16x8*>(&Ds[w][r][128 + c8*8]) = sv;
  }
  __syncthreads();
  int l15 = lane & 15, quad = lane >> 4;
  f32x4 acc[4];
  #pragma unroll
  for (int u=0;u<4;u++) acc[u] = (f32x4){0.f,0.f,0.f,0.f};
  #pragma unroll
  for (int kc=0;kc<8;kc++){
    int k0 = kc*32;
    bf16x8 av = *reinterpret_cast<const bf16x8*>(&Ds[w][l15][k0 + quad*8]);
    #pragma unroll
    for (int u=0;u<4;u++){
      bf16x8 bfr = *reinterpret_cast<const bf16x8*>(&W1t[(16*u + l15)*256 + k0 + quad*8]);
      acc[u] = __builtin_amdgcn_mfma_f32_16x16x32_bf16(av, bfr, acc[u], 0,0,0);
    }
  }
  float p[4] = {0.f,0.f,0.f,0.f};
  #pragma unroll
  for (int u=0;u<4;u++){
    int c = 16*u + l15;
    float bc = b1[c], wc = W2[c];
    #pragma unroll
    for (int reg=0;reg<4;reg++) p[reg] += ftanh(acc[u][reg] + bc) * wc;
  }
  #pragma unroll
  for (int reg=0;reg<4;reg++){
    p[reg] += __shfl_xor(p[reg], 1);
    p[reg] += __shfl_xor(p[reg], 2);
    p[reg] += __shfl_xor(p[reg], 4);
    p[reg] += __shfl_xor(p[reg], 8);
  }
  if (l15 == 0){
    float b2v = b2_[0];
    #pragma unroll
    for (int reg=0;reg<4;reg++) nw[ge0 + quad*4 + reg] = p[reg] + b2v;
  }
}

// dest_attn = softmax_d( nw[b, inv_adj[v,d], d] )
__global__ __launch_bounds__(256) void k_dattn(const float* __restrict__ nw, const int* __restrict__ invadj,
                                               float* __restrict__ dattn){
  int node = blockIdx.x*256 + threadIdx.x;
  if (node >= BV) return;
  int b = node >> 10;
  float vals[16];
  #pragma unroll
  for (int d=0; d<16; d++){
    int ia = invadj[node*D + d];
    vals[d] = nw[(b*V + ia)*D + d];
  }
  float m = vals[0];
  #pragma unroll
  for (int d=1; d<16; d++) m = fmaxf(m, vals[d]);
  float s = 0.f;
  #pragma unroll
  for (int d=0; d<16; d++){ vals[d] = __expf(vals[d]-m); s += vals[d]; }
  float inv = frcp(s);
  #pragma unroll
  for (int d=0; d<16; d++) dattn[node*D + d] = vals[d]*inv;
}

// normalized = sparsemax_d( dattn[b, adj[v,d], d] )
__global__ __launch_bounds__(256) void k_sparse(const float* __restrict__ dattn, const int* __restrict__ adj,
                                                float* __restrict__ norm_){
  int node = blockIdx.x*256 + threadIdx.x;
  if (node >= BV) return;
  int b = node >> 10;
  float z[16], s[16];
  #pragma unroll
  for (int d=0; d<16; d++){
    int a = adj[node*D + d];
    z[d] = dattn[(b*V + a)*D + d];
    s[d] = z[d];
  }
  #pragma unroll
  for (int k2 = 2; k2 <= 16; k2 <<= 1){
    #pragma unroll
    for (int jj = k2 >> 1; jj > 0; jj >>= 1){
      #pragma unroll
      for (int i = 0; i < 16; i++){
        int l = i ^ jj;
        if (l > i){
          bool up = ((i & k2) == 0);
          float a = s[i], bb = s[l];
          bool sw = up ? (a > bb) : (a < bb);
          if (sw){ s[i]=bb; s[l]=a; }
        }
      }
    }
  }
  float cs = 0.f, zcs = 0.f; int kz = 1;
  #pragma unroll
  for (int j=0;j<16;j++){
    float zj = s[15-j];
    cs += zj;
    if (1.f + (float)(j+1)*zj > cs){ kz = j+1; zcs = cs; }
  }
  float tau = (zcs - 1.f)/(float)kz;
  #pragma unroll
  for (int d=0; d<16; d++) norm_[node*D + d] = fmaxf(z[d]-tau, 0.f);
}

// all 10 MCF iterations fused: one block per batch, flow in LDS d-major.
__global__ __launch_bounds__(1024) void k_flow_fused(const float* __restrict__ norm_,
    const float* __restrict__ dem, const int* __restrict__ invadj, float* __restrict__ flowout){
  __shared__ float fl[D*V];
  int b = blockIdx.x, v = threadIdx.x;
  int base = ((b << 10) + v)*D;
  int ia[16]; float nr[16];
  #pragma unroll
  for (int d4=0; d4<4; d4++){
    int4 i4 = reinterpret_cast<const int4*>(&invadj[base])[d4];
    ia[d4*4+0]=i4.x; ia[d4*4+1]=i4.y; ia[d4*4+2]=i4.z; ia[d4*4+3]=i4.w;
    float4 n4 = reinterpret_cast<const float4*>(&norm_[base])[d4];
    nr[d4*4+0]=n4.x; nr[d4*4+1]=n4.y; nr[d4*4+2]=n4.z; nr[d4*4+3]=n4.w;
  }
  float dm = dem[(b<<10) + v];
  #pragma unroll
  for (int d=0; d<16; d++) fl[d*V + v] = 0.f;
  __syncthreads();
  float s = 0.f;
  for (int it=0; it<10; it++){
    float inflow = 0.f;
    #pragma unroll
    for (int d=0; d<16; d++) inflow += fl[d*V + ia[d]];
    __syncthreads();
    s = fmaxf(inflow - dm, 0.f);
    #pragma unroll
    for (int d=0; d<16; d++) fl[d*V + v] = nr[d]*s;
    __syncthreads();
  }
  #pragma unroll
  for (int d4=0; d4<4; d4++){
    float4 o;
    o.x = nr[d4*4+0]*s; o.y = nr[d4*4+1]*s; o.z = nr[d4*4+2]*s; o.w = nr[d4*4+3]*s;
    reinterpret_cast<float4*>(&flowout[base])[d4] = o;
  }
}

// dual_vars from precomputed node_states — 1 wave per node
__global__ __launch_bounds__(64) void k_dualvars(const float* __restrict__ ns_, const float* __restrict__ W1,
    const float* __restrict__ b1, const float* __restrict__ W2, const float* __restrict__ b2_,
    const float* __restrict__ dem, float* __restrict__ dv, float* __restrict__ accdd){
  __shared__ float ns[128];
  int node = blockIdx.x; int b = node >> 10;
  int tid = threadIdx.x;
  ns[tid]      = ns_[(long)node*128 + tid];
  ns[tid + 64] = ns_[(long)node*128 + 64 + tid];
  __syncthreads();
  float acc = 0.f;
  #pragma unroll 8
  for (int k=0;k<128;k++) acc += ns[k]*W1[k*HD + tid];
  float t = ftanh(acc + b1[tid]) * W2[tid];
  #pragma unroll
  for (int off=32; off>0; off>>=1) t += __shfl_down(t, off);
  if (tid == 0){
    float val = fmaxf(t + b2_[0], 0.f);
    dv[node] = val;
    atomicAdd(&accdd[b], val * dem[node]);
  }
}

// flow cost + dual flow iterations + dual cost
__global__ __launch_bounds__(256) void k_cost(const float* __restrict__ flow, const float* __restrict__ dv,
    const int* __restrict__ adj, float* __restrict__ accF, float* __restrict__ accD){
  int gid = blockIdx.x*256 + threadIdx.x;
  int b = gid >> 14;
  int a = adj[gid];
  float diff = dv[b*V + a];
  float f = 0.f, vel = 0.f;
  #pragma unroll
  for (int it=0; it<10; it++){
    float g = 2.f*f + diff;
    vel = 0.9f*vel - 0.01f*g;
    f = fmaxf(f + vel, 0.f);
  }
  float cd = f*f + diff*f;
  float fl = flow[gid];
  float cf = fl*fl;
  #pragma unroll
  for (int off=32; off>0; off>>=1){ cd += __shfl_down(cd, off); cf += __shfl_down(cf, off); }
  __shared__ float r1[4], r2[4];
  int lane = threadIdx.x & 63, w = threadIdx.x >> 6;
  if (lane==0){ r1[w]=cf; r2[w]=cd; }
  __syncthreads();
  if (threadIdx.x==0){
    atomicAdd(&accF[b], r1[0]+r1[1]+r1[2]+r1[3]);
    atomicAdd(&accD[b], r2[0]+r2[1]+r2[2]+r2[3]);
  }
}

__global__ __launch_bounds__(64) void k_final(const float* __restrict__ acc, float* __restrict__ out){
  int b = threadIdx.x;
  if (b < B){
    float fc = acc[b], dc = acc[16+b], dd = acc[32+b];
    out[b] = fc - (dc - dd);
  }
}

extern "C" void kernel_launch(void* const* d_in, const int* in_sizes, int n_in,
                              void* d_out, int out_size, void* d_ws, size_t ws_size,
                              hipStream_t stream){
  (void)in_sizes; (void)n_in; (void)out_size; (void)ws_size;
  const float* demands = (const float*)d_in[0];
  const float* nf      = (const float*)d_in[1];
  const float* emb     = (const float*)d_in[4];
  const float* Wenc    = (const float*)d_in[5];
  const float* benc    = (const float*)d_in[6];
  const float* Wgat    = (const float*)d_in[7];
  const float* bgat    = (const float*)d_in[8];
  const float* agat    = (const float*)d_in[9];
  const float* Wgx     = (const float*)d_in[10];
  const float* Wgh     = (const float*)d_in[11];
  const float* bgru    = (const float*)d_in[12];
  const float* Wd1     = (const float*)d_in[13];
  const float* bd1     = (const float*)d_in[14];
  const float* Wd2     = (const float*)d_in[15];
  const float* bd2     = (const float*)d_in[16];
  const float* Wu1     = (const float*)d_in[17];
  const float* bu1     = (const float*)d_in[18];
  const float* Wu2     = (const float*)d_in[19];
  const float* bu2     = (const float*)d_in[20];
  const int* adj       = (const int*)d_in[21];
  const int* invadj    = (const int*)d_in[22];

  float* ws    = (float*)d_ws;
  short* nebf  = (short*)(ws + OFF_NEBF);
  short* xn    = (short*)(ws + OFF_XN);
  short* hbf   = (short*)(ws + OFF_HBF);
  float* nst   = ws + OFF_NS;
  float* embn  = ws + OFF_EMB;
  float* nw    = ws + OFF_NW;
  float* dattn = ws + OFF_DATTN;
  float* nrm   = ws + OFF_NORM;
  float* fa    = ws + OFF_FLOWA;
  float* dv    = ws + OFF_DV;
  float* acc   = ws + OFF_ACC;
  short* wt    = (short*)(ws + OFF_WT);
  short* wtg   = (short*)(ws + OFF_WTG);
  short* wtd   = (short*)(ws + OFF_WTD);

  k_prep<<<897, 256, 0, stream>>>(Wgx, Wgh, Wgat, Wd1, emb, wt, wtg, wtd, embn, acc);
  k_enc<<<BV/16, 256, 0, stream>>>(embn, nf, Wenc, benc, nebf);
  // layer 0 (h == gather(nebf, adj))
  k_gat_mfma<<<BV/4, 256, 0, stream>>>(nebf, hbf, adj, wtg, bgat, agat, xn, 1);
  k_gru_mfma<<<BVD/64, 256, 0, stream>>>(xn, nebf, adj, wt, bgru, hbf, nst, 1);
  // layer 1
  k_gat_mfma<<<BV/4, 256, 0, stream>>>(nebf, hbf, adj, wtg, bgat, agat, xn, 0);
  k_gru_mfma<<<BVD/64, 256, 0, stream>>>(xn, hbf, adj, wt, bgru, hbf, nst, 0);
  k_dec_mfma<<<BVD/64, 256, 0, stream>>>(hbf, adj, wtd, bd1, Wd2, bd2, nw);
  k_dattn<<<BV/256, 256, 0, stream>>>(nw, invadj, dattn);
  k_sparse<<<BV/256, 256, 0, stream>>>(dattn, adj, nrm);
  k_flow_fused<<<B, 1024, 0, stream>>>(nrm, demands, invadj, fa);
  k_dualvars<<<BV, 64, 0, stream>>>(nst, Wu1, bu1, Wu2, bu2, demands, dv, acc+32);
  k_cost<<<BVD/256, 256, 0, stream>>>(fa, dv, adj, acc, acc+16);
  k_final<<<1, 64, 0, stream>>>(acc, (float*)d_out);
}

// Round 8
// 623.694 us; speedup vs baseline: 1.5763x; 1.3147x over previous
//
#include <hip/hip_runtime.h>
#include <hip/hip_bf16.h>

#define B 16
#define V 1024
#define D 16
#define E 64
#define F 16
#define H 128
#define HD 64
#define BV (B*V)      // 16384
#define BVD (B*V*D)   // 262144

// ---- workspace layout (float offsets) ----
#define OFF_NEBF     0                             // node_enc bf16 (BV*H shorts)
#define OFF_XN       (OFF_NEBF + BV*H/2)           // xnode bf16 (BV*H shorts)
#define OFF_HBF      (OFF_XN + BV*H/2)             // h edge states bf16 (BVD*H shorts)
#define OFF_NS       (OFF_HBF + BVD*H/2)           // node_states fp32 (B,V,H)
#define OFF_EMB      (OFF_NS + BV*H)
#define OFF_NW       (OFF_EMB + V*E)
#define OFF_DATTN    (OFF_NW + BVD)
#define OFF_NORM     (OFF_DATTN + BVD)
#define OFF_FLOWA    (OFF_NORM + BVD)
#define OFF_DV       (OFF_FLOWA + BVD)
#define OFF_ACC      (OFF_DV + BV)                 // [0:16) flow_cost, [16:32) dual, [32:48) dual_demand
#define OFF_WT       (OFF_ACC + 64)                // 512x256 bf16 GRU weights = 65536 floats
#define OFF_WTG      (OFF_WT + 65536)              // 128x128 bf16 GAT weights = 8192 floats
#define OFF_WTD      (OFF_WTG + 8192)              // 64x256  bf16 dec weights = 8192 floats

typedef __attribute__((ext_vector_type(8))) short bf16x8;
typedef __attribute__((ext_vector_type(4))) float f32x4;

__device__ __forceinline__ short f2bf(float f){
  __hip_bfloat16 b = __float2bfloat16(f);
  return *reinterpret_cast<short*>(&b);
}
__device__ __forceinline__ float bf2f(short s){
  __hip_bfloat16 b; *reinterpret_cast<short*>(&b) = s;
  return __bfloat162float(b);
}
__device__ __forceinline__ float frcp(float x){ return __builtin_amdgcn_rcpf(x); }
__device__ __forceinline__ float fsig(float x){ return frcp(1.f + __expf(-x)); }
__device__ __forceinline__ float ftanh(float x){
  float e = __expf(-2.f*fabsf(x));
  float r = (1.f - e)*frcp(1.f + e);
  return copysignf(r, x);
}

// ---- merged prep: GRU/GAT/dec weight packs + embnorm + acc zero ----
__global__ __launch_bounds__(256) void k_prep(const float* __restrict__ Wx, const float* __restrict__ Wh,
    const float* __restrict__ Wg, const float* __restrict__ W1, const float* __restrict__ emb,
    short* __restrict__ Wt, short* __restrict__ Wgt, short* __restrict__ W1t,
    float* __restrict__ embn, float* __restrict__ acc){
  int bid = blockIdx.x, tid = threadIdx.x;
  if (bid < 512){
    int n = bid, k = tid;
    int g = n >> 7, j = n & 127;
    float v;
    if (g == 0)      v = (k < 128) ? Wx[k*384 + j]       : Wh[(k-128)*384 + j];
    else if (g == 1) v = (k < 128) ? Wx[k*384 + 128 + j] : Wh[(k-128)*384 + 128 + j];
    else if (g == 2) v = (k < 128) ? Wx[k*384 + 256 + j] : 0.f;
    else             v = (k < 128) ? 0.f                 : Wh[(k-128)*384 + 256 + j];
    Wt[n*256 + k] = f2bf(v);
  } else if (bid < 576){
    int idx = (bid-512)*256 + tid;
    int n = idx >> 7, k = idx & 127;
    Wgt[n*128 + k] = f2bf(Wg[k*128 + n]);
  } else if (bid < 640){
    int n = bid - 576, k = tid;
    W1t[n*256 + k] = f2bf(W1[k*64 + n]);
  } else if (bid < 896){
    int v = (bid-640)*4 + (tid >> 6);
    int e = tid & 63;
    float val = emb[v*E + e];
    float ss = val*val;
    #pragma unroll
    for (int off=32; off>0; off>>=1) ss += __shfl_down(ss, off);
    ss = __shfl(ss, 0);
    embn[v*E + e] = val * frcp(fmaxf(sqrtf(ss), 1.f));
  } else {
    if (tid < 64) acc[tid] = 0.f;
  }
}

// node_enc = [emb_n | node_features] @ W_enc + b_enc -> bf16  (M=BV, K=80, N=128)
__global__ __launch_bounds__(256) void k_enc(const float* __restrict__ embn, const float* __restrict__ nf,
                                             const float* __restrict__ Wenc, const float* __restrict__ benc,
                                             short* __restrict__ nebf){
  __shared__ float As[16][80];
  int tid = threadIdx.x;
  int m0 = blockIdx.x*16;
  for (int idx=tid; idx<16*80; idx+=256){
    int i = idx/80, k = idx%80;
    int m = m0 + i; int v = m & (V-1);
    As[i][k] = (k < E) ? embn[v*E + k] : nf[m*F + (k-E)];
  }
  __syncthreads();
  int c = tid & 127, half = tid >> 7;
  float acc[8] = {0,0,0,0,0,0,0,0};
  for (int kk=0; kk<80; kk+=4){
    float w[4];
    #pragma unroll
    for (int u=0;u<4;u++) w[u] = Wenc[(kk+u)*H + c];
    #pragma unroll
    for (int i=0;i<8;i++){
      const float4 av = *reinterpret_cast<const float4*>(&As[half*8+i][kk]);
      acc[i] += av.x*w[0] + av.y*w[1] + av.z*w[2] + av.w*w[3];
    }
  }
  float bb = benc[c];
  #pragma unroll
  for (int i=0;i<8;i++){
    int m = m0 + half*8 + i;
    nebf[m*H + c] = f2bf(acc[i] + bb);
  }
}

// MFMA DirectionalGAT: wave-per-node. Emits xnode = tanh(node_msg + node_enc) bf16.
__global__ __launch_bounds__(256) void k_gat_mfma(const short* __restrict__ nebf, const short* __restrict__ hbf,
    const int* __restrict__ adj, const short* __restrict__ Wgt, const float* __restrict__ bg,
    const float* __restrict__ ag, short* __restrict__ xn, int gather0){
  __shared__ short As[4][16][136];
  int tid = threadIdx.x;
  int w = tid >> 6, lane = tid & 63;
  int node = blockIdx.x*4 + w;
  int b = node >> 10;
  #pragma unroll
  for (int e=0;e<4;e++){
    int idx = e*64 + lane;          // 256 bf16x8 chunks
    int r = idx >> 4, c8 = idx & 15;
    bf16x8 v;
    if (gather0){
      int a = adj[node*16 + r];
      v = *reinterpret_cast<const bf16x8*>(&nebf[(long)(((b<<10) + a))*128 + c8*8]);
    } else {
      v = *reinterpret_cast<const bf16x8*>(&hbf[(long)(node*16 + r)*128 + c8*8]);
    }
    *reinterpret_cast<bf16x8*>(&As[w][r][c8*8]) = v;
  }
  __syncthreads();
  int l15 = lane & 15, quad = lane >> 4;
  f32x4 acc[8];
  #pragma unroll
  for (int u=0;u<8;u++) acc[u] = (f32x4){0.f,0.f,0.f,0.f};
  #pragma unroll
  for (int kc=0; kc<4; kc++){
    int k0 = kc*32;
    bf16x8 a = *reinterpret_cast<const bf16x8*>(&As[w][l15][k0 + quad*8]);
    #pragma unroll
    for (int u=0;u<8;u++){
      bf16x8 bfr = *reinterpret_cast<const bf16x8*>(&Wgt[(16*u + l15)*128 + k0 + quad*8]);
      acc[u] = __builtin_amdgcn_mfma_f32_16x16x32_bf16(a, bfr, acc[u], 0,0,0);
    }
  }
  float tv[8][4];
  float lp[4] = {0.f,0.f,0.f,0.f};
  #pragma unroll
  for (int u=0;u<8;u++){
    int c = 16*u + l15;
    float bgc = bg[c], agc = ag[c];
    #pragma unroll
    for (int reg=0;reg<4;reg++){
      float t = ftanh(acc[u][reg] + bgc);
      tv[u][reg] = t;
      lp[reg] += t * agc;
    }
  }
  #pragma unroll
  for (int reg=0;reg<4;reg++){
    lp[reg] += __shfl_xor(lp[reg], 1);
    lp[reg] += __shfl_xor(lp[reg], 2);
    lp[reg] += __shfl_xor(lp[reg], 4);
    lp[reg] += __shfl_xor(lp[reg], 8);
  }
  float m4 = fmaxf(fmaxf(lp[0],lp[1]), fmaxf(lp[2],lp[3]));
  m4 = fmaxf(m4, __shfl_xor(m4, 16));
  m4 = fmaxf(m4, __shfl_xor(m4, 32));
  float e4[4]; float s4 = 0.f;
  #pragma unroll
  for (int reg=0;reg<4;reg++){ e4[reg] = __expf(lp[reg]-m4); s4 += e4[reg]; }
  s4 += __shfl_xor(s4, 16);
  s4 += __shfl_xor(s4, 32);
  float inv = frcp(s4);
  #pragma unroll
  for (int reg=0;reg<4;reg++) e4[reg] *= inv;
  #pragma unroll
  for (int u=0;u<8;u++){
    float mp = e4[0]*tv[u][0] + e4[1]*tv[u][1] + e4[2]*tv[u][2] + e4[3]*tv[u][3];
    mp += __shfl_xor(mp, 16);
    mp += __shfl_xor(mp, 32);
    if (quad == 0){
      int c = 16*u + l15;
      float nev = bf2f(nebf[(long)node*128 + c]);
      xn[(long)node*128 + c] = f2bf(ftanh(mp + nev));
    }
  }
}

// MFMA GRU: 64 edge-rows/block. A=[xnode gathered | h] all-bf16 copy staging.
__global__ __launch_bounds__(256) void k_gru_mfma(const short* __restrict__ xn, const short* __restrict__ hsrc,
    const int* __restrict__ adj, const short* __restrict__ Wt, const float* __restrict__ bgru,
    short* __restrict__ hbf, float* __restrict__ ns_, int layer0){
  __shared__ short As[64][264];
  int tid = threadIdx.x;
  int ge0 = blockIdx.x*64;
  if (layer0){
    #pragma unroll
    for (int e=0;e<4;e++){
      int idx = e*256 + tid;        // 1024 bf16x8 chunks per half
      int r = idx >> 4, c8 = idx & 15;
      int ge = ge0 + r;
      int nv = ge >> 4, d = ge & 15;
      int a = adj[nv*16 + d];
      long srow = (long)(((nv >> 10)<<10) + a)*128;
      *reinterpret_cast<bf16x8*>(&As[r][c8*8])       = *reinterpret_cast<const bf16x8*>(&xn[srow + c8*8]);
      *reinterpret_cast<bf16x8*>(&As[r][128 + c8*8]) = *reinterpret_cast<const bf16x8*>(&hsrc[srow + c8*8]);
    }
  } else {
    #pragma unroll
    for (int e=0;e<4;e++){
      int idx = e*256 + tid;
      int r = idx >> 4, c8 = idx & 15;
      int ge = ge0 + r;
      int nv = ge >> 4, d = ge & 15;
      int a = adj[nv*16 + d];
      long srow = (long)(((nv >> 10)<<10) + a)*128;
      *reinterpret_cast<bf16x8*>(&As[r][c8*8])       = *reinterpret_cast<const bf16x8*>(&xn[srow + c8*8]);
      *reinterpret_cast<bf16x8*>(&As[r][128 + c8*8]) = *reinterpret_cast<const bf16x8*>(&hsrc[(long)ge*128 + c8*8]);
    }
  }
  __syncthreads();
  int w = tid >> 6, lane = tid & 63;
  int l15 = lane & 15, quad = lane >> 4;
  f32x4 acc[4][4][2];
  #pragma unroll
  for (int mt=0;mt<4;mt++)
    #pragma unroll
    for (int g=0;g<4;g++)
      #pragma unroll
      for (int u=0;u<2;u++) acc[mt][g][u] = (f32x4){0.f,0.f,0.f,0.f};

  for (int k8=0;k8<8;k8++){
    int k0 = k8*32;
    int gg = (k8 < 4) ? 2 : 3;
    bf16x8 a[4];
    #pragma unroll
    for (int mt=0;mt<4;mt++)
      a[mt] = *reinterpret_cast<const bf16x8*>(&As[16*mt + l15][k0 + quad*8]);
    bf16x8 bz[2], br[2], bc[2];
    #pragma unroll
    for (int u=0;u<2;u++){
      int ncol = 32*w + 16*u + l15;
      int koff = k0 + quad*8;
      bz[u] = *reinterpret_cast<const bf16x8*>(&Wt[(ncol      )*256 + koff]);
      br[u] = *reinterpret_cast<const bf16x8*>(&Wt[(ncol + 128)*256 + koff]);
      bc[u] = *reinterpret_cast<const bf16x8*>(&Wt[(ncol + gg*128)*256 + koff]);
    }
    #pragma unroll
    for (int mt=0;mt<4;mt++){
      #pragma unroll
      for (int u=0;u<2;u++){
        acc[mt][0][u]  = __builtin_amdgcn_mfma_f32_16x16x32_bf16(a[mt], bz[u], acc[mt][0][u], 0,0,0);
        acc[mt][1][u]  = __builtin_amdgcn_mfma_f32_16x16x32_bf16(a[mt], br[u], acc[mt][1][u], 0,0,0);
        acc[mt][gg][u] = __builtin_amdgcn_mfma_f32_16x16x32_bf16(a[mt], bc[u], acc[mt][gg][u], 0,0,0);
      }
    }
  }
  __syncthreads();   // all waves done reading As x-half; safe to overwrite with h-out
  #pragma unroll
  for (int u=0;u<2;u++){
    int j = 32*w + 16*u + l15;
    float bjz = bgru[j], bjr = bgru[128 + j], bjc = bgru[256 + j];
    #pragma unroll
    for (int mt=0;mt<4;mt++){
      float psum = 0.f;
      #pragma unroll
      for (int reg=0;reg<4;reg++){
        int rl = 16*mt + quad*4 + reg;
        float z = fsig(acc[mt][0][u][reg] + bjz);
        float r = fsig(acc[mt][1][u][reg] + bjr);
        float cand = ftanh(acc[mt][2][u][reg] + bjc + r*acc[mt][3][u][reg]);
        float ho = bf2f(As[rl][128 + j]);
        float hn = z*ho + (1.f - z)*cand;
        As[rl][j] = f2bf(hn);       // park in x-half for coalesced store
        psum += hn;
      }
      if (!layer0){
        psum += __shfl_xor(psum, 16);
        psum += __shfl_xor(psum, 32);
        if (quad == 0) ns_[(long)((ge0 >> 4) + mt)*128 + j] = psum;
      }
    }
  }
  __syncthreads();
  #pragma unroll
  for (int e=0;e<4;e++){
    int idx = e*256 + tid;
    int r = idx >> 4, c8 = idx & 15;
    *reinterpret_cast<bf16x8*>(&hbf[(long)(ge0 + r)*128 + c8*8]) =
        *reinterpret_cast<const bf16x8*>(&As[r][c8*8]);
  }
}

// MFMA decoder: wave-per-16-edges, h bf16 input.
__global__ __launch_bounds__(256) void k_dec_mfma(const short* __restrict__ hbf, const int* __restrict__ adj,
    const short* __restrict__ W1t, const float* __restrict__ b1, const float* __restrict__ W2,
    const float* __restrict__ b2_, float* __restrict__ nw){
  __shared__ short Ds[4][16][264];
  int tid = threadIdx.x;
  int w = tid >> 6, lane = tid & 63;
  int ge0 = blockIdx.x*64 + w*16;
  #pragma unroll
  for (int e=0;e<4;e++){
    int idx = e*64 + lane;          // 256 bf16x8 chunks
    int r = idx >> 4, c8 = idx & 15;
    int ge = ge0 + r;
    int nv = ge >> 4, d = ge & 15, b = nv >> 10;
    int a = adj[nv*16 + d];
    long opp = (long)(((b<<10) + a)*16 + (d^1))*128;
    bf16x8 ov = *reinterpret_cast<const bf16x8*>(&hbf[(long)ge*128 + c8*8]);
    bf16x8 pv = *reinterpret_cast<const bf16x8*>(&hbf[opp + c8*8]);
    *reinterpret_cast<bf16x8*>(&Ds[w][r][c8*8]) = ov;
    bf16x8 sv;
    #pragma unroll
    for (int q=0;q<8;q++) sv[q] = f2bf(bf2f(ov[q]) + bf2f(pv[q]));
    *reinterpret_cast<bf16x8*>(&Ds[w][r][128 + c8*8]) = sv;
  }
  __syncthreads();
  int l15 = lane & 15, quad = lane >> 4;
  f32x4 acc[4];
  #pragma unroll
  for (int u=0;u<4;u++) acc[u] = (f32x4){0.f,0.f,0.f,0.f};
  #pragma unroll
  for (int kc=0;kc<8;kc++){
    int k0 = kc*32;
    bf16x8 av = *reinterpret_cast<const bf16x8*>(&Ds[w][l15][k0 + quad*8]);
    #pragma unroll
    for (int u=0;u<4;u++){
      bf16x8 bfr = *reinterpret_cast<const bf16x8*>(&W1t[(16*u + l15)*256 + k0 + quad*8]);
      acc[u] = __builtin_amdgcn_mfma_f32_16x16x32_bf16(av, bfr, acc[u], 0,0,0);
    }
  }
  float p[4] = {0.f,0.f,0.f,0.f};
  #pragma unroll
  for (int u=0;u<4;u++){
    int c = 16*u + l15;
    float bc = b1[c], wc = W2[c];
    #pragma unroll
    for (int reg=0;reg<4;reg++) p[reg] += ftanh(acc[u][reg] + bc) * wc;
  }
  #pragma unroll
  for (int reg=0;reg<4;reg++){
    p[reg] += __shfl_xor(p[reg], 1);
    p[reg] += __shfl_xor(p[reg], 2);
    p[reg] += __shfl_xor(p[reg], 4);
    p[reg] += __shfl_xor(p[reg], 8);
  }
  if (l15 == 0){
    float b2v = b2_[0];
    #pragma unroll
    for (int reg=0;reg<4;reg++) nw[ge0 + quad*4 + reg] = p[reg] + b2v;
  }
}

// dest_attn = softmax_d( nw[b, inv_adj[v,d], d] )
__global__ __launch_bounds__(256) void k_dattn(const float* __restrict__ nw, const int* __restrict__ invadj,
                                               float* __restrict__ dattn){
  int node = blockIdx.x*256 + threadIdx.x;
  if (node >= BV) return;
  int b = node >> 10;
  float vals[16];
  #pragma unroll
  for (int d=0; d<16; d++){
    int ia = invadj[node*D + d];
    vals[d] = nw[(b*V + ia)*D + d];
  }
  float m = vals[0];
  #pragma unroll
  for (int d=1; d<16; d++) m = fmaxf(m, vals[d]);
  float s = 0.f;
  #pragma unroll
  for (int d=0; d<16; d++){ vals[d] = __expf(vals[d]-m); s += vals[d]; }
  float inv = frcp(s);
  #pragma unroll
  for (int d=0; d<16; d++) dattn[node*D + d] = vals[d]*inv;
}

// normalized = sparsemax_d( dattn[b, adj[v,d], d] )
__global__ __launch_bounds__(256) void k_sparse(const float* __restrict__ dattn, const int* __restrict__ adj,
                                                float* __restrict__ norm_){
  int node = blockIdx.x*256 + threadIdx.x;
  if (node >= BV) return;
  int b = node >> 10;
  float z[16], s[16];
  #pragma unroll
  for (int d=0; d<16; d++){
    int a = adj[node*D + d];
    z[d] = dattn[(b*V + a)*D + d];
    s[d] = z[d];
  }
  #pragma unroll
  for (int k2 = 2; k2 <= 16; k2 <<= 1){
    #pragma unroll
    for (int jj = k2 >> 1; jj > 0; jj >>= 1){
      #pragma unroll
      for (int i = 0; i < 16; i++){
        int l = i ^ jj;
        if (l > i){
          bool up = ((i & k2) == 0);
          float a = s[i], bb = s[l];
          bool sw = up ? (a > bb) : (a < bb);
          if (sw){ s[i]=bb; s[l]=a; }
        }
      }
    }
  }
  float cs = 0.f, zcs = 0.f; int kz = 1;
  #pragma unroll
  for (int j=0;j<16;j++){
    float zj = s[15-j];
    cs += zj;
    if (1.f + (float)(j+1)*zj > cs){ kz = j+1; zcs = cs; }
  }
  float tau = (zcs - 1.f)/(float)kz;
  #pragma unroll
  for (int d=0; d<16; d++) norm_[node*D + d] = fmaxf(z[d]-tau, 0.f);
}

// all 10 MCF iterations fused: one block per batch, flow in LDS d-major.
__global__ __launch_bounds__(1024) void k_flow_fused(const float* __restrict__ norm_,
    const float* __restrict__ dem, const int* __restrict__ invadj, float* __restrict__ flowout){
  __shared__ float fl[D*V];
  int b = blockIdx.x, v = threadIdx.x;
  int base = ((b << 10) + v)*D;
  int ia[16]; float nr[16];
  #pragma unroll
  for (int d4=0; d4<4; d4++){
    int4 i4 = reinterpret_cast<const int4*>(&invadj[base])[d4];
    ia[d4*4+0]=i4.x; ia[d4*4+1]=i4.y; ia[d4*4+2]=i4.z; ia[d4*4+3]=i4.w;
    float4 n4 = reinterpret_cast<const float4*>(&norm_[base])[d4];
    nr[d4*4+0]=n4.x; nr[d4*4+1]=n4.y; nr[d4*4+2]=n4.z; nr[d4*4+3]=n4.w;
  }
  float dm = dem[(b<<10) + v];
  #pragma unroll
  for (int d=0; d<16; d++) fl[d*V + v] = 0.f;
  __syncthreads();
  float s = 0.f;
  for (int it=0; it<10; it++){
    float inflow = 0.f;
    #pragma unroll
    for (int d=0; d<16; d++) inflow += fl[d*V + ia[d]];
    __syncthreads();
    s = fmaxf(inflow - dm, 0.f);
    #pragma unroll
    for (int d=0; d<16; d++) fl[d*V + v] = nr[d]*s;
    __syncthreads();
  }
  #pragma unroll
  for (int d4=0; d4<4; d4++){
    float4 o;
    o.x = nr[d4*4+0]*s; o.y = nr[d4*4+1]*s; o.z = nr[d4*4+2]*s; o.w = nr[d4*4+3]*s;
    reinterpret_cast<float4*>(&flowout[base])[d4] = o;
  }
}

// dual_vars from node_states — 4 nodes/block, one wave each, NO atomics
__global__ __launch_bounds__(256) void k_dualvars(const float* __restrict__ ns_, const float* __restrict__ W1,
    const float* __restrict__ b1, const float* __restrict__ W2, const float* __restrict__ b2_,
    float* __restrict__ dv){
  __shared__ float ns[4][128];
  int w = threadIdx.x >> 6, tid = threadIdx.x & 63;
  int node = blockIdx.x*4 + w;
  ns[w][tid]      = ns_[(long)node*128 + tid];
  ns[w][tid + 64] = ns_[(long)node*128 + 64 + tid];
  float acc = 0.f;
  #pragma unroll 8
  for (int k=0;k<128;k++) acc += ns[w][k]*W1[k*HD + tid];
  float t = ftanh(acc + b1[tid]) * W2[tid];
  #pragma unroll
  for (int off=32; off>0; off>>=1) t += __shfl_down(t, off);
  if (tid == 0) dv[node] = fmaxf(t + b2_[0], 0.f);
}

// dual_demand = sum_v dv*dem per batch — tree reduction, no atomics
__global__ __launch_bounds__(1024) void k_dd(const float* __restrict__ dv, const float* __restrict__ dem,
                                             float* __restrict__ accdd){
  __shared__ float red[16];
  int b = blockIdx.x, v = threadIdx.x;
  float p = dv[(b<<10) + v] * dem[(b<<10) + v];
  #pragma unroll
  for (int off=32; off>0; off>>=1) p += __shfl_down(p, off);
  if ((v & 63) == 0) red[v >> 6] = p;
  __syncthreads();
  if (v == 0){
    float s = 0.f;
    #pragma unroll
    for (int i=0;i<16;i++) s += red[i];
    accdd[b] = s;
  }
}

// flow cost + dual flow iterations + dual cost
__global__ __launch_bounds__(256) void k_cost(const float* __restrict__ flow, const float* __restrict__ dv,
    const int* __restrict__ adj, float* __restrict__ accF, float* __restrict__ accD){
  int gid = blockIdx.x*256 + threadIdx.x;
  int b = gid >> 14;
  int a = adj[gid];
  float diff = dv[b*V + a];
  float f = 0.f, vel = 0.f;
  #pragma unroll
  for (int it=0; it<10; it++){
    float g = 2.f*f + diff;
    vel = 0.9f*vel - 0.01f*g;
    f = fmaxf(f + vel, 0.f);
  }
  float cd = f*f + diff*f;
  float fl = flow[gid];
  float cf = fl*fl;
  #pragma unroll
  for (int off=32; off>0; off>>=1){ cd += __shfl_down(cd, off); cf += __shfl_down(cf, off); }
  __shared__ float r1[4], r2[4];
  int lane = threadIdx.x & 63, w = threadIdx.x >> 6;
  if (lane==0){ r1[w]=cf; r2[w]=cd; }
  __syncthreads();
  if (threadIdx.x==0){
    atomicAdd(&accF[b], r1[0]+r1[1]+r1[2]+r1[3]);
    atomicAdd(&accD[b], r2[0]+r2[1]+r2[2]+r2[3]);
  }
}

__global__ __launch_bounds__(64) void k_final(const float* __restrict__ acc, float* __restrict__ out){
  int b = threadIdx.x;
  if (b < B){
    float fc = acc[b], dc = acc[16+b], dd = acc[32+b];
    out[b] = fc - (dc - dd);
  }
}

extern "C" void kernel_launch(void* const* d_in, const int* in_sizes, int n_in,
                              void* d_out, int out_size, void* d_ws, size_t ws_size,
                              hipStream_t stream){
  (void)in_sizes; (void)n_in; (void)out_size; (void)ws_size;
  const float* demands = (const float*)d_in[0];
  const float* nf      = (const float*)d_in[1];
  const float* emb     = (const float*)d_in[4];
  const float* Wenc    = (const float*)d_in[5];
  const float* benc    = (const float*)d_in[6];
  const float* Wgat    = (const float*)d_in[7];
  const float* bgat    = (const float*)d_in[8];
  const float* agat    = (const float*)d_in[9];
  const float* Wgx     = (const float*)d_in[10];
  const float* Wgh     = (const float*)d_in[11];
  const float* bgru    = (const float*)d_in[12];
  const float* Wd1     = (const float*)d_in[13];
  const float* bd1     = (const float*)d_in[14];
  const float* Wd2     = (const float*)d_in[15];
  const float* bd2     = (const float*)d_in[16];
  const float* Wu1     = (const float*)d_in[17];
  const float* bu1     = (const float*)d_in[18];
  const float* Wu2     = (const float*)d_in[19];
  const float* bu2     = (const float*)d_in[20];
  const int* adj       = (const int*)d_in[21];
  const int* invadj    = (const int*)d_in[22];

  float* ws    = (float*)d_ws;
  short* nebf  = (short*)(ws + OFF_NEBF);
  short* xn    = (short*)(ws + OFF_XN);
  short* hbf   = (short*)(ws + OFF_HBF);
  float* nst   = ws + OFF_NS;
  float* embn  = ws + OFF_EMB;
  float* nw    = ws + OFF_NW;
  float* dattn = ws + OFF_DATTN;
  float* nrm   = ws + OFF_NORM;
  float* fa    = ws + OFF_FLOWA;
  float* dv    = ws + OFF_DV;
  float* acc   = ws + OFF_ACC;
  short* wt    = (short*)(ws + OFF_WT);
  short* wtg   = (short*)(ws + OFF_WTG);
  short* wtd   = (short*)(ws + OFF_WTD);

  k_prep<<<897, 256, 0, stream>>>(Wgx, Wgh, Wgat, Wd1, emb, wt, wtg, wtd, embn, acc);
  k_enc<<<BV/16, 256, 0, stream>>>(embn, nf, Wenc, benc, nebf);
  // layer 0 (h == gather(nebf, adj))
  k_gat_mfma<<<BV/4, 256, 0, stream>>>(nebf, hbf, adj, wtg, bgat, agat, xn, 1);
  k_gru_mfma<<<BVD/64, 256, 0, stream>>>(xn, nebf, adj, wt, bgru, hbf, nst, 1);
  // layer 1
  k_gat_mfma<<<BV/4, 256, 0, stream>>>(nebf, hbf, adj, wtg, bgat, agat, xn, 0);
  k_gru_mfma<<<BVD/64, 256, 0, stream>>>(xn, hbf, adj, wt, bgru, hbf, nst, 0);
  k_dec_mfma<<<BVD/64, 256, 0, stream>>>(hbf, adj, wtd, bd1, Wd2, bd2, nw);
  k_dattn<<<BV/256, 256, 0, stream>>>(nw, invadj, dattn);
  k_sparse<<<BV/256, 256, 0, stream>>>(dattn, adj, nrm);
  k_flow_fused<<<B, 1024, 0, stream>>>(nrm, demands, invadj, fa);
  k_dualvars<<<BV/4, 256, 0, stream>>>(nst, Wu1, bu1, Wu2, bu2, dv);
  k_dd<<<B, 1024, 0, stream>>>(dv, demands, acc+32);
  k_cost<<<BVD/256, 256, 0, stream>>>(fa, dv, adj, acc, acc+16);
  k_final<<<1, 64, 0, stream>>>(acc, (float*)d_out);
}

// Round 9
// 269.422 us; speedup vs baseline: 3.6489x; 2.3149x over previous
//
#include <hip/hip_runtime.h>
#include <hip/hip_bf16.h>

#define B 16
#define V 1024
#define D 16
#define E 64
#define F 16
#define H 128
#define HD 64
#define BV (B*V)      // 16384
#define BVD (B*V*D)   // 262144

// ---- workspace layout (float offsets) ---- all node-level now
#define OFF_NEBF     0                         // node_enc bf16 (BV*H shorts)
#define OFF_XN       (OFF_NEBF + BV*H/2)       // xnode bf16
#define OFF_HNA      (OFF_XN + BV*H/2)         // hnode layer out A bf16
#define OFF_HNB      (OFF_HNA + BV*H/2)        // hnode layer out B bf16
#define OFF_TN       (OFF_HNB + BV*H/2)        // tnode bf16
#define OFF_LN       (OFF_TN + BV*H/2)         // lnode fp32 (BV)
#define OFF_PQ       (OFF_LN + BV)             // [P|Q] fp32 (BV,128)
#define OFF_NW       (OFF_PQ + BV*128)
#define OFF_DATTN    (OFF_NW + BVD)
#define OFF_NORM     (OFF_DATTN + BVD)
#define OFF_FLOWA    (OFF_NORM + BVD)
#define OFF_DV       (OFF_FLOWA + BVD)
#define OFF_ACC      (OFF_DV + BV)             // [0:16) flow, [16:32) dual, [32:48) dual_demand
#define OFF_WT       (OFF_ACC + 64)            // 512x256 bf16 GRU weights
#define OFF_WTG      (OFF_WT + 65536)          // 128x128 bf16 GAT weights
#define OFF_WPQ      (OFF_WTG + 8192)          // 128x128 bf16 dec [P|Q] weights
#define OFF_EMB      (OFF_WPQ + 8192)

typedef __attribute__((ext_vector_type(8))) short bf16x8;
typedef __attribute__((ext_vector_type(4))) float f32x4;

__device__ __forceinline__ short f2bf(float f){
  __hip_bfloat16 b = __float2bfloat16(f);
  return *reinterpret_cast<short*>(&b);
}
__device__ __forceinline__ float bf2f(short s){
  __hip_bfloat16 b; *reinterpret_cast<short*>(&b) = s;
  return __bfloat162float(b);
}
__device__ __forceinline__ float frcp(float x){ return __builtin_amdgcn_rcpf(x); }
__device__ __forceinline__ float fsig(float x){ return frcp(1.f + __expf(-x)); }
__device__ __forceinline__ float ftanh(float x){
  float e = __expf(-2.f*fabsf(x));
  float r = (1.f - e)*frcp(1.f + e);
  return copysignf(r, x);
}

// ---- merged prep ----
// [0,512) GRU Wt | [512,576) Wgt | [576,608) dec P/Q pack | [608,864) embnorm | 864 acc zero
__global__ __launch_bounds__(256) void k_prep(const float* __restrict__ Wx, const float* __restrict__ Wh,
    const float* __restrict__ Wg, const float* __restrict__ W1, const float* __restrict__ emb,
    short* __restrict__ Wt, short* __restrict__ Wgt, short* __restrict__ Wpq,
    float* __restrict__ embn, float* __restrict__ acc){
  int bid = blockIdx.x, tid = threadIdx.x;
  if (bid < 512){
    int n = bid, k = tid;
    int g = n >> 7, j = n & 127;
    float v;
    if (g == 0)      v = (k < 128) ? Wx[k*384 + j]       : Wh[(k-128)*384 + j];
    else if (g == 1) v = (k < 128) ? Wx[k*384 + 128 + j] : Wh[(k-128)*384 + 128 + j];
    else if (g == 2) v = (k < 128) ? Wx[k*384 + 256 + j] : 0.f;
    else             v = (k < 128) ? 0.f                 : Wh[(k-128)*384 + 256 + j];
    Wt[n*256 + k] = f2bf(v);
  } else if (bid < 576){
    int idx = (bid-512)*256 + tid;
    int n = idx >> 7, k = idx & 127;
    Wgt[n*128 + k] = f2bf(Wg[k*128 + n]);
  } else if (bid < 608){
    int idx = (bid-576)*256 + tid;       // 8192: n<64, k<128
    int n = idx >> 7, k = idx & 127;
    float wb = W1[(k+128)*HD + n];
    float wa = W1[k*HD + n];
    Wpq[n*128 + k]        = f2bf(wa + wb);   // P weights
    Wpq[(64+n)*128 + k]   = f2bf(wb);        // Q weights
  } else if (bid < 864){
    int v = (bid-608)*4 + (tid >> 6);
    int e = tid & 63;
    float val = emb[v*E + e];
    float ss = val*val;
    #pragma unroll
    for (int off=32; off>0; off>>=1) ss += __shfl_down(ss, off);
    ss = __shfl(ss, 0);
    embn[v*E + e] = val * frcp(fmaxf(sqrtf(ss), 1.f));
  } else {
    if (tid < 64) acc[tid] = 0.f;
  }
}

// node_enc = [emb_n | node_features] @ W_enc + b_enc -> bf16  (M=BV, K=80, N=128)
__global__ __launch_bounds__(256) void k_enc(const float* __restrict__ embn, const float* __restrict__ nf,
                                             const float* __restrict__ Wenc, const float* __restrict__ benc,
                                             short* __restrict__ nebf){
  __shared__ float As[16][80];
  int tid = threadIdx.x;
  int m0 = blockIdx.x*16;
  for (int idx=tid; idx<16*80; idx+=256){
    int i = idx/80, k = idx%80;
    int m = m0 + i; int v = m & (V-1);
    As[i][k] = (k < E) ? embn[v*E + k] : nf[m*F + (k-E)];
  }
  __syncthreads();
  int c = tid & 127, half = tid >> 7;
  float acc[8] = {0,0,0,0,0,0,0,0};
  for (int kk=0; kk<80; kk+=4){
    float w[4];
    #pragma unroll
    for (int u=0;u<4;u++) w[u] = Wenc[(kk+u)*H + c];
    #pragma unroll
    for (int i=0;i<8;i++){
      const float4 av = *reinterpret_cast<const float4*>(&As[half*8+i][kk]);
      acc[i] += av.x*w[0] + av.y*w[1] + av.z*w[2] + av.w*w[3];
    }
  }
  float bb = benc[c];
  #pragma unroll
  for (int i=0;i<8;i++){
    int m = m0 + half*8 + i;
    nebf[m*H + c] = f2bf(acc[i] + bb);
  }
}

// node-level GAT transform: tnode = tanh(hnode@Wg+bg) bf16, lnode = tnode . ag  (M=BV,K=128,N=128)
__global__ __launch_bounds__(256) void k_gat_node(const short* __restrict__ hn, const short* __restrict__ Wgt,
    const float* __restrict__ bg, const float* __restrict__ ag, short* __restrict__ tn,
    float* __restrict__ ln){
  __shared__ short As[64][136];
  __shared__ float lgp[4][64];
  int tid = threadIdx.x;
  int ge0 = blockIdx.x*64;
  #pragma unroll
  for (int e=0;e<4;e++){
    int idx = e*256 + tid;          // 1024 bf16x8 chunks
    int r = idx >> 4, c8 = idx & 15;
    *reinterpret_cast<bf16x8*>(&As[r][c8*8]) =
        *reinterpret_cast<const bf16x8*>(&hn[(long)(ge0 + r)*128 + c8*8]);
  }
  __syncthreads();
  int w = tid >> 6, lane = tid & 63;
  int l15 = lane & 15, quad = lane >> 4;
  f32x4 acc[4][2];
  #pragma unroll
  for (int mt=0;mt<4;mt++)
    #pragma unroll
    for (int u=0;u<2;u++) acc[mt][u] = (f32x4){0.f,0.f,0.f,0.f};
  #pragma unroll
  for (int kc=0;kc<4;kc++){
    int k0 = kc*32;
    bf16x8 a[4];
    #pragma unroll
    for (int mt=0;mt<4;mt++)
      a[mt] = *reinterpret_cast<const bf16x8*>(&As[16*mt + l15][k0 + quad*8]);
    #pragma unroll
    for (int u=0;u<2;u++){
      bf16x8 bfr = *reinterpret_cast<const bf16x8*>(&Wgt[(32*w + 16*u + l15)*128 + k0 + quad*8]);
      #pragma unroll
      for (int mt=0;mt<4;mt++)
        acc[mt][u] = __builtin_amdgcn_mfma_f32_16x16x32_bf16(a[mt], bfr, acc[mt][u], 0,0,0);
    }
  }
  __syncthreads();
  float lp[16];
  #pragma unroll
  for (int i=0;i<16;i++) lp[i] = 0.f;
  #pragma unroll
  for (int u=0;u<2;u++){
    int c = 32*w + 16*u + l15;
    float bgc = bg[c], agc = ag[c];
    #pragma unroll
    for (int mt=0;mt<4;mt++){
      #pragma unroll
      for (int reg=0;reg<4;reg++){
        float t = ftanh(acc[mt][u][reg] + bgc);
        As[16*mt + quad*4 + reg][c] = f2bf(t);
        lp[mt*4+reg] += t * agc;
      }
    }
  }
  #pragma unroll
  for (int i=0;i<16;i++){
    lp[i] += __shfl_xor(lp[i], 1);
    lp[i] += __shfl_xor(lp[i], 2);
    lp[i] += __shfl_xor(lp[i], 4);
    lp[i] += __shfl_xor(lp[i], 8);
  }
  if (l15 == 0){
    #pragma unroll
    for (int mt=0;mt<4;mt++)
      #pragma unroll
      for (int reg=0;reg<4;reg++)
        lgp[w][16*mt + quad*4 + reg] = lp[mt*4+reg];
  }
  __syncthreads();
  #pragma unroll
  for (int e=0;e<4;e++){
    int idx = e*256 + tid;
    int r = idx >> 4, c8 = idx & 15;
    *reinterpret_cast<bf16x8*>(&tn[(long)(ge0 + r)*128 + c8*8]) =
        *reinterpret_cast<const bf16x8*>(&As[r][c8*8]);
  }
  if (tid < 64) ln[ge0 + tid] = lgp[0][tid]+lgp[1][tid]+lgp[2][tid]+lgp[3][tid];
}

// per-node softmax attention over gathered lnode + weighted gather-sum of tnode;
// xnode = tanh(msg + node_enc). One wave per node.
__global__ __launch_bounds__(256) void k_msg(const short* __restrict__ tn, const float* __restrict__ ln,
    const short* __restrict__ nebf, const int* __restrict__ adj, short* __restrict__ xn){
  __shared__ float at_s[4][16];
  __shared__ int adjs[4][16];
  int tid = threadIdx.x;
  int w = tid >> 6, lane = tid & 63;
  int node = blockIdx.x*4 + w;
  int b = node >> 10;
  int l15 = lane & 15, quad = lane >> 4;
  int a = (b<<10) + adj[node*16 + l15];
  float lval = ln[a];
  float m = lval;
  m = fmaxf(m, __shfl_xor(m, 1)); m = fmaxf(m, __shfl_xor(m, 2));
  m = fmaxf(m, __shfl_xor(m, 4)); m = fmaxf(m, __shfl_xor(m, 8));
  float e = __expf(lval - m);
  float s = e;
  s += __shfl_xor(s, 1); s += __shfl_xor(s, 2);
  s += __shfl_xor(s, 4); s += __shfl_xor(s, 8);
  if (quad == 0){ at_s[w][l15] = e*frcp(s); adjs[w][l15] = a; }
  __syncthreads();
  int c0 = lane, c1 = lane + 64;
  float m0 = 0.f, m1 = 0.f;
  #pragma unroll 4
  for (int d=0; d<16; d++){
    int ad = adjs[w][d];
    float at = at_s[w][d];
    m0 += at * bf2f(tn[(long)ad*128 + c0]);
    m1 += at * bf2f(tn[(long)ad*128 + c1]);
  }
  xn[(long)node*128 + c0] = f2bf(ftanh(m0 + bf2f(nebf[(long)node*128 + c0])));
  xn[(long)node*128 + c1] = f2bf(ftanh(m1 + bf2f(nebf[(long)node*128 + c1])));
}

// node-level GRU: hnew = GRU(xnode, hnode)  (M=BV, K=256, N=384 effective)
__global__ __launch_bounds__(256) void k_gru_node(const short* __restrict__ xn, const short* __restrict__ hn,
    const short* __restrict__ Wt, const float* __restrict__ bgru, short* __restrict__ hnew){
  __shared__ short As[64][264];
  int tid = threadIdx.x;
  int ge0 = blockIdx.x*64;
  #pragma unroll
  for (int e=0;e<4;e++){
    int idx = e*256 + tid;
    int r = idx >> 4, c8 = idx & 15;
    long row = (long)(ge0 + r)*128;
    *reinterpret_cast<bf16x8*>(&As[r][c8*8])       = *reinterpret_cast<const bf16x8*>(&xn[row + c8*8]);
    *reinterpret_cast<bf16x8*>(&As[r][128 + c8*8]) = *reinterpret_cast<const bf16x8*>(&hn[row + c8*8]);
  }
  __syncthreads();
  int w = tid >> 6, lane = tid & 63;
  int l15 = lane & 15, quad = lane >> 4;
  f32x4 acc[4][4][2];
  #pragma unroll
  for (int mt=0;mt<4;mt++)
    #pragma unroll
    for (int g=0;g<4;g++)
      #pragma unroll
      for (int u=0;u<2;u++) acc[mt][g][u] = (f32x4){0.f,0.f,0.f,0.f};
  for (int k8=0;k8<8;k8++){
    int k0 = k8*32;
    int gg = (k8 < 4) ? 2 : 3;
    bf16x8 a[4];
    #pragma unroll
    for (int mt=0;mt<4;mt++)
      a[mt] = *reinterpret_cast<const bf16x8*>(&As[16*mt + l15][k0 + quad*8]);
    bf16x8 bz[2], br[2], bc[2];
    #pragma unroll
    for (int u=0;u<2;u++){
      int ncol = 32*w + 16*u + l15;
      int koff = k0 + quad*8;
      bz[u] = *reinterpret_cast<const bf16x8*>(&Wt[(ncol      )*256 + koff]);
      br[u] = *reinterpret_cast<const bf16x8*>(&Wt[(ncol + 128)*256 + koff]);
      bc[u] = *reinterpret_cast<const bf16x8*>(&Wt[(ncol + gg*128)*256 + koff]);
    }
    #pragma unroll
    for (int mt=0;mt<4;mt++){
      #pragma unroll
      for (int u=0;u<2;u++){
        acc[mt][0][u]  = __builtin_amdgcn_mfma_f32_16x16x32_bf16(a[mt], bz[u], acc[mt][0][u], 0,0,0);
        acc[mt][1][u]  = __builtin_amdgcn_mfma_f32_16x16x32_bf16(a[mt], br[u], acc[mt][1][u], 0,0,0);
        acc[mt][gg][u] = __builtin_amdgcn_mfma_f32_16x16x32_bf16(a[mt], bc[u], acc[mt][gg][u], 0,0,0);
      }
    }
  }
  __syncthreads();
  #pragma unroll
  for (int u=0;u<2;u++){
    int j = 32*w + 16*u + l15;
    float bjz = bgru[j], bjr = bgru[128 + j], bjc = bgru[256 + j];
    #pragma unroll
    for (int mt=0;mt<4;mt++){
      #pragma unroll
      for (int reg=0;reg<4;reg++){
        int rl = 16*mt + quad*4 + reg;
        float z = fsig(acc[mt][0][u][reg] + bjz);
        float r = fsig(acc[mt][1][u][reg] + bjr);
        float cand = ftanh(acc[mt][2][u][reg] + bjc + r*acc[mt][3][u][reg]);
        float ho = bf2f(As[rl][128 + j]);
        As[rl][j] = f2bf(z*ho + (1.f - z)*cand);
      }
    }
  }
  __syncthreads();
  #pragma unroll
  for (int e=0;e<4;e++){
    int idx = e*256 + tid;
    int r = idx >> 4, c8 = idx & 15;
    *reinterpret_cast<bf16x8*>(&hnew[(long)(ge0 + r)*128 + c8*8]) =
        *reinterpret_cast<const bf16x8*>(&As[r][c8*8]);
  }
}

// node-level decoder GEMM: PQ = hnode2 @ Wpq  (M=BV, K=128, N=128) fp32 out
__global__ __launch_bounds__(256) void k_dec_node(const short* __restrict__ hn, const short* __restrict__ Wpq,
                                                  float* __restrict__ PQ){
  __shared__ short As[64][136];
  int tid = threadIdx.x;
  int ge0 = blockIdx.x*64;
  #pragma unroll
  for (int e=0;e<4;e++){
    int idx = e*256 + tid;
    int r = idx >> 4, c8 = idx & 15;
    *reinterpret_cast<bf16x8*>(&As[r][c8*8]) =
        *reinterpret_cast<const bf16x8*>(&hn[(long)(ge0 + r)*128 + c8*8]);
  }
  __syncthreads();
  int w = tid >> 6, lane = tid & 63;
  int l15 = lane & 15, quad = lane >> 4;
  f32x4 acc[4][2];
  #pragma unroll
  for (int mt=0;mt<4;mt++)
    #pragma unroll
    for (int u=0;u<2;u++) acc[mt][u] = (f32x4){0.f,0.f,0.f,0.f};
  #pragma unroll
  for (int kc=0;kc<4;kc++){
    int k0 = kc*32;
    bf16x8 a[4];
    #pragma unroll
    for (int mt=0;mt<4;mt++)
      a[mt] = *reinterpret_cast<const bf16x8*>(&As[16*mt + l15][k0 + quad*8]);
    #pragma unroll
    for (int u=0;u<2;u++){
      bf16x8 bfr = *reinterpret_cast<const bf16x8*>(&Wpq[(32*w + 16*u + l15)*128 + k0 + quad*8]);
      #pragma unroll
      for (int mt=0;mt<4;mt++)
        acc[mt][u] = __builtin_amdgcn_mfma_f32_16x16x32_bf16(a[mt], bfr, acc[mt][u], 0,0,0);
    }
  }
  #pragma unroll
  for (int u=0;u<2;u++){
    int c = 32*w + 16*u + l15;
    #pragma unroll
    for (int mt=0;mt<4;mt++){
      #pragma unroll
      for (int reg=0;reg<4;reg++){
        int row = ge0 + 16*mt + quad*4 + reg;
        PQ[(long)row*128 + c] = acc[mt][u][reg];
      }
    }
  }
}

// per-edge decoder epilogue: nw[v,d] = tanh(P[a]+Q[v]+b1) . W2 + b2. Wave per node, 4 lanes per d.
__global__ __launch_bounds__(256) void k_dec_edge(const float* __restrict__ PQ, const int* __restrict__ adj,
    const float* __restrict__ b1, const float* __restrict__ W2, const float* __restrict__ b2_,
    float* __restrict__ nw){
  int tid = threadIdx.x;
  int w = tid >> 6, lane = tid & 63;
  int node = blockIdx.x*4 + w;
  int b = node >> 10;
  int d = lane >> 2, q = lane & 3;
  int a = (b<<10) + adj[node*16 + d];
  const float4* Pp = reinterpret_cast<const float4*>(&PQ[(long)a*128 + q*16]);
  const float4* Qp = reinterpret_cast<const float4*>(&PQ[(long)node*128 + 64 + q*16]);
  const float4* b1p = reinterpret_cast<const float4*>(&b1[q*16]);
  const float4* w2p = reinterpret_cast<const float4*>(&W2[q*16]);
  float p = 0.f;
  #pragma unroll
  for (int e4=0; e4<4; e4++){
    float4 pv = Pp[e4], qv = Qp[e4], bv = b1p[e4], wv = w2p[e4];
    p += ftanh(pv.x+qv.x+bv.x)*wv.x + ftanh(pv.y+qv.y+bv.y)*wv.y
       + ftanh(pv.z+qv.z+bv.z)*wv.z + ftanh(pv.w+qv.w+bv.w)*wv.w;
  }
  p += __shfl_xor(p, 1);
  p += __shfl_xor(p, 2);
  if (q == 0) nw[node*16 + d] = p + b2_[0];
}

// dest_attn = softmax_d( nw[b, inv_adj[v,d], d] )
__global__ __launch_bounds__(256) void k_dattn(const float* __restrict__ nw, const int* __restrict__ invadj,
                                               float* __restrict__ dattn){
  int node = blockIdx.x*256 + threadIdx.x;
  if (node >= BV) return;
  int b = node >> 10;
  float vals[16];
  #pragma unroll
  for (int d=0; d<16; d++){
    int ia = invadj[node*D + d];
    vals[d] = nw[(b*V + ia)*D + d];
  }
  float m = vals[0];
  #pragma unroll
  for (int d=1; d<16; d++) m = fmaxf(m, vals[d]);
  float s = 0.f;
  #pragma unroll
  for (int d=0; d<16; d++){ vals[d] = __expf(vals[d]-m); s += vals[d]; }
  float inv = frcp(s);
  #pragma unroll
  for (int d=0; d<16; d++) dattn[node*D + d] = vals[d]*inv;
}

// normalized = sparsemax_d( dattn[b, adj[v,d], d] )
__global__ __launch_bounds__(256) void k_sparse(const float* __restrict__ dattn, const int* __restrict__ adj,
                                                float* __restrict__ norm_){
  int node = blockIdx.x*256 + threadIdx.x;
  if (node >= BV) return;
  int b = node >> 10;
  float z[16], s[16];
  #pragma unroll
  for (int d=0; d<16; d++){
    int a = adj[node*D + d];
    z[d] = dattn[(b*V + a)*D + d];
    s[d] = z[d];
  }
  #pragma unroll
  for (int k2 = 2; k2 <= 16; k2 <<= 1){
    #pragma unroll
    for (int jj = k2 >> 1; jj > 0; jj >>= 1){
      #pragma unroll
      for (int i = 0; i < 16; i++){
        int l = i ^ jj;
        if (l > i){
          bool up = ((i & k2) == 0);
          float a = s[i], bb = s[l];
          bool sw = up ? (a > bb) : (a < bb);
          if (sw){ s[i]=bb; s[l]=a; }
        }
      }
    }
  }
  float cs = 0.f, zcs = 0.f; int kz = 1;
  #pragma unroll
  for (int j=0;j<16;j++){
    float zj = s[15-j];
    cs += zj;
    if (1.f + (float)(j+1)*zj > cs){ kz = j+1; zcs = cs; }
  }
  float tau = (zcs - 1.f)/(float)kz;
  #pragma unroll
  for (int d=0; d<16; d++) norm_[node*D + d] = fmaxf(z[d]-tau, 0.f);
}

// all 10 MCF iterations fused
__global__ __launch_bounds__(1024) void k_flow_fused(const float* __restrict__ norm_,
    const float* __restrict__ dem, const int* __restrict__ invadj, float* __restrict__ flowout){
  __shared__ float fl[D*V];
  int b = blockIdx.x, v = threadIdx.x;
  int base = ((b << 10) + v)*D;
  int ia[16]; float nr[16];
  #pragma unroll
  for (int d4=0; d4<4; d4++){
    int4 i4 = reinterpret_cast<const int4*>(&invadj[base])[d4];
    ia[d4*4+0]=i4.x; ia[d4*4+1]=i4.y; ia[d4*4+2]=i4.z; ia[d4*4+3]=i4.w;
    float4 n4 = reinterpret_cast<const float4*>(&norm_[base])[d4];
    nr[d4*4+0]=n4.x; nr[d4*4+1]=n4.y; nr[d4*4+2]=n4.z; nr[d4*4+3]=n4.w;
  }
  float dm = dem[(b<<10) + v];
  #pragma unroll
  for (int d=0; d<16; d++) fl[d*V + v] = 0.f;
  __syncthreads();
  float s = 0.f;
  for (int it=0; it<10; it++){
    float inflow = 0.f;
    #pragma unroll
    for (int d=0; d<16; d++) inflow += fl[d*V + ia[d]];
    __syncthreads();
    s = fmaxf(inflow - dm, 0.f);
    #pragma unroll
    for (int d=0; d<16; d++) fl[d*V + v] = nr[d]*s;
    __syncthreads();
  }
  #pragma unroll
  for (int d4=0; d4<4; d4++){
    float4 o;
    o.x = nr[d4*4+0]*s; o.y = nr[d4*4+1]*s; o.z = nr[d4*4+2]*s; o.w = nr[d4*4+3]*s;
    reinterpret_cast<float4*>(&flowout[base])[d4] = o;
  }
}

// dual_vars: node_states = gather-sum of hnode2 over adj, then MLP. Wave per node, no atomics.
__global__ __launch_bounds__(256) void k_dualvars(const short* __restrict__ hn2, const int* __restrict__ adj,
    const float* __restrict__ W1, const float* __restrict__ b1, const float* __restrict__ W2,
    const float* __restrict__ b2_, float* __restrict__ dv){
  __shared__ float ns[4][128];
  __shared__ int adjs[4][16];
  int tid = threadIdx.x;
  int w = tid >> 6, lane = tid & 63;
  int node = blockIdx.x*4 + w;
  int b = node >> 10;
  if (lane < 16) adjs[w][lane] = (b<<10) + adj[node*16 + lane];
  __syncthreads();
  int c0 = lane, c1 = lane + 64;
  float s0 = 0.f, s1 = 0.f;
  #pragma unroll 4
  for (int d=0; d<16; d++){
    int a = adjs[w][d];
    s0 += bf2f(hn2[(long)a*128 + c0]);
    s1 += bf2f(hn2[(long)a*128 + c1]);
  }
  ns[w][c0] = s0; ns[w][c1] = s1;
  __syncthreads();
  float acc = 0.f;
  #pragma unroll 8
  for (int k=0;k<128;k++) acc += ns[w][k]*W1[k*HD + lane];
  float t = ftanh(acc + b1[lane]) * W2[lane];
  #pragma unroll
  for (int off=32; off>0; off>>=1) t += __shfl_down(t, off);
  if (lane == 0) dv[node] = fmaxf(t + b2_[0], 0.f);
}

// dual_demand = sum_v dv*dem per batch — tree reduction
__global__ __launch_bounds__(1024) void k_dd(const float* __restrict__ dv, const float* __restrict__ dem,
                                             float* __restrict__ accdd){
  __shared__ float red[16];
  int b = blockIdx.x, v = threadIdx.x;
  float p = dv[(b<<10) + v] * dem[(b<<10) + v];
  #pragma unroll
  for (int off=32; off>0; off>>=1) p += __shfl_down(p, off);
  if ((v & 63) == 0) red[v >> 6] = p;
  __syncthreads();
  if (v == 0){
    float s = 0.f;
    #pragma unroll
    for (int i=0;i<16;i++) s += red[i];
    accdd[b] = s;
  }
}

// flow cost + dual flow iterations + dual cost
__global__ __launch_bounds__(256) void k_cost(const float* __restrict__ flow, const float* __restrict__ dv,
    const int* __restrict__ adj, float* __restrict__ accF, float* __restrict__ accD){
  int gid = blockIdx.x*256 + threadIdx.x;
  int b = gid >> 14;
  int a = adj[gid];
  float diff = dv[b*V + a];
  float f = 0.f, vel = 0.f;
  #pragma unroll
  for (int it=0; it<10; it++){
    float g = 2.f*f + diff;
    vel = 0.9f*vel - 0.01f*g;
    f = fmaxf(f + vel, 0.f);
  }
  float cd = f*f + diff*f;
  float fl = flow[gid];
  float cf = fl*fl;
  #pragma unroll
  for (int off=32; off>0; off>>=1){ cd += __shfl_down(cd, off); cf += __shfl_down(cf, off); }
  __shared__ float r1[4], r2[4];
  int lane = threadIdx.x & 63, w = threadIdx.x >> 6;
  if (lane==0){ r1[w]=cf; r2[w]=cd; }
  __syncthreads();
  if (threadIdx.x==0){
    atomicAdd(&accF[b], r1[0]+r1[1]+r1[2]+r1[3]);
    atomicAdd(&accD[b], r2[0]+r2[1]+r2[2]+r2[3]);
  }
}

__global__ __launch_bounds__(64) void k_final(const float* __restrict__ acc, float* __restrict__ out){
  int b = threadIdx.x;
  if (b < B){
    float fc = acc[b], dc = acc[16+b], dd = acc[32+b];
    out[b] = fc - (dc - dd);
  }
}

extern "C" void kernel_launch(void* const* d_in, const int* in_sizes, int n_in,
                              void* d_out, int out_size, void* d_ws, size_t ws_size,
                              hipStream_t stream){
  (void)in_sizes; (void)n_in; (void)out_size; (void)ws_size;
  const float* demands = (const float*)d_in[0];
  const float* nf      = (const float*)d_in[1];
  const float* emb     = (const float*)d_in[4];
  const float* Wenc    = (const float*)d_in[5];
  const float* benc    = (const float*)d_in[6];
  const float* Wgat    = (const float*)d_in[7];
  const float* bgat    = (const float*)d_in[8];
  const float* agat    = (const float*)d_in[9];
  const float* Wgx     = (const float*)d_in[10];
  const float* Wgh     = (const float*)d_in[11];
  const float* bgru    = (const float*)d_in[12];
  const float* Wd1     = (const float*)d_in[13];
  const float* bd1     = (const float*)d_in[14];
  const float* Wd2     = (const float*)d_in[15];
  const float* bd2     = (const float*)d_in[16];
  const float* Wu1     = (const float*)d_in[17];
  const float* bu1     = (const float*)d_in[18];
  const float* Wu2     = (const float*)d_in[19];
  const float* bu2     = (const float*)d_in[20];
  const int* adj       = (const int*)d_in[21];
  const int* invadj    = (const int*)d_in[22];

  float* ws    = (float*)d_ws;
  short* nebf  = (short*)(ws + OFF_NEBF);
  short* xn    = (short*)(ws + OFF_XN);
  short* hnA   = (short*)(ws + OFF_HNA);
  short* hnB   = (short*)(ws + OFF_HNB);
  short* tn    = (short*)(ws + OFF_TN);
  float* ln    = ws + OFF_LN;
  float* PQ    = ws + OFF_PQ;
  float* nw    = ws + OFF_NW;
  float* dattn = ws + OFF_DATTN;
  float* nrm   = ws + OFF_NORM;
  float* fa    = ws + OFF_FLOWA;
  float* dv    = ws + OFF_DV;
  float* acc   = ws + OFF_ACC;
  short* wt    = (short*)(ws + OFF_WT);
  short* wtg   = (short*)(ws + OFF_WTG);
  short* wpq   = (short*)(ws + OFF_WPQ);
  float* embn  = ws + OFF_EMB;

  k_prep<<<865, 256, 0, stream>>>(Wgx, Wgh, Wgat, Wd1, emb, wt, wtg, wpq, embn, acc);
  k_enc<<<BV/16, 256, 0, stream>>>(embn, nf, Wenc, benc, nebf);
  // layer 0: hnode0 = nebf
  k_gat_node<<<BV/64, 256, 0, stream>>>(nebf, wtg, bgat, agat, tn, ln);
  k_msg<<<BV/4, 256, 0, stream>>>(tn, ln, nebf, adj, xn);
  k_gru_node<<<BV/64, 256, 0, stream>>>(xn, nebf, wt, bgru, hnA);
  // layer 1
  k_gat_node<<<BV/64, 256, 0, stream>>>(hnA, wtg, bgat, agat, tn, ln);
  k_msg<<<BV/4, 256, 0, stream>>>(tn, ln, nebf, adj, xn);
  k_gru_node<<<BV/64, 256, 0, stream>>>(xn, hnA, wt, bgru, hnB);
  // decoder
  k_dec_node<<<BV/64, 256, 0, stream>>>(hnB, wpq, PQ);
  k_dec_edge<<<BV/4, 256, 0, stream>>>(PQ, adj, bd1, Wd2, bd2, nw);
  k_dattn<<<BV/256, 256, 0, stream>>>(nw, invadj, dattn);
  k_sparse<<<BV/256, 256, 0, stream>>>(dattn, adj, nrm);
  k_flow_fused<<<B, 1024, 0, stream>>>(nrm, demands, invadj, fa);
  k_dualvars<<<BV/4, 256, 0, stream>>>(hnB, adj, Wu1, bu1, Wu2, bu2, dv);
  k_dd<<<B, 1024, 0, stream>>>(dv, demands, acc+32);
  k_cost<<<BVD/256, 256, 0, stream>>>(fa, dv, adj, acc, acc+16);
  k_final<<<1, 64, 0, stream>>>(acc, (float*)d_out);
}

// Round 10
// 224.133 us; speedup vs baseline: 4.3863x; 1.2021x over previous
//
#include <hip/hip_runtime.h>
#include <hip/hip_bf16.h>

#define B 16
#define V 1024
#define D 16
#define E 64
#define F 16
#define H 128
#define HD 64
#define BV (B*V)      // 16384
#define BVD (B*V*D)   // 262144

// ---- workspace layout (float offsets) ----
#define OFF_NEBF     0                         // node_enc bf16 (BV*H shorts)
#define OFF_HNA      (OFF_NEBF + BV*H/2)       // hnode layer1 bf16
#define OFF_HNB      (OFF_HNA + BV*H/2)        // hnode layer2 bf16
#define OFF_NW       (OFF_HNB + BV*H/2)        // per-edge decoder logits fp32 (BVD)
#define OFF_NORM     (OFF_NW + BVD)            // sparsemax output (BVD)
#define OFF_DV       (OFF_NORM + BVD)          // dual vars (BV)
#define OFF_ACC      (OFF_DV + BV)             // [0:16) flow_cost, [16:32) 16*dualcost, [32:48) dual_demand
#define OFF_WT       (OFF_ACC + 64)            // 512x256 bf16 GRU weights
#define OFF_WTG      (OFF_WT + 65536)          // 128x128 bf16 GAT weights
#define OFF_WPQ      (OFF_WTG + 8192)          // 128x128 bf16 dec [P|Q] weights
#define OFF_EMB      (OFF_WPQ + 8192)

typedef __attribute__((ext_vector_type(8))) short bf16x8;
typedef __attribute__((ext_vector_type(4))) float f32x4;

__device__ __forceinline__ short f2bf(float f){
  __hip_bfloat16 b = __float2bfloat16(f);
  return *reinterpret_cast<short*>(&b);
}
__device__ __forceinline__ float bf2f(short s){
  __hip_bfloat16 b; *reinterpret_cast<short*>(&b) = s;
  return __bfloat162float(b);
}
__device__ __forceinline__ float frcp(float x){ return __builtin_amdgcn_rcpf(x); }
__device__ __forceinline__ float fsig(float x){ return frcp(1.f + __expf(-x)); }
__device__ __forceinline__ float ftanh(float x){
  float e = __expf(-2.f*fabsf(x));
  float r = (1.f - e)*frcp(1.f + e);
  return copysignf(r, x);
}

// ---- merged prep ----
__global__ __launch_bounds__(256) void k_prep(const float* __restrict__ Wx, const float* __restrict__ Wh,
    const float* __restrict__ Wg, const float* __restrict__ W1, const float* __restrict__ emb,
    short* __restrict__ Wt, short* __restrict__ Wgt, short* __restrict__ Wpq,
    float* __restrict__ embn, float* __restrict__ acc){
  int bid = blockIdx.x, tid = threadIdx.x;
  if (bid < 512){
    int n = bid, k = tid;
    int g = n >> 7, j = n & 127;
    float v;
    if (g == 0)      v = (k < 128) ? Wx[k*384 + j]       : Wh[(k-128)*384 + j];
    else if (g == 1) v = (k < 128) ? Wx[k*384 + 128 + j] : Wh[(k-128)*384 + 128 + j];
    else if (g == 2) v = (k < 128) ? Wx[k*384 + 256 + j] : 0.f;
    else             v = (k < 128) ? 0.f                 : Wh[(k-128)*384 + 256 + j];
    Wt[n*256 + k] = f2bf(v);
  } else if (bid < 576){
    int idx = (bid-512)*256 + tid;
    int n = idx >> 7, k = idx & 127;
    Wgt[n*128 + k] = f2bf(Wg[k*128 + n]);
  } else if (bid < 608){
    int idx = (bid-576)*256 + tid;       // n<64, k<128
    int n = idx >> 7, k = idx & 127;
    float wb = W1[(k+128)*HD + n];
    float wa = W1[k*HD + n];
    Wpq[n*128 + k]      = f2bf(wa + wb);   // P weights
    Wpq[(64+n)*128 + k] = f2bf(wb);        // Q weights
  } else if (bid < 864){
    int v = (bid-608)*4 + (tid >> 6);
    int e = tid & 63;
    float val = emb[v*E + e];
    float ss = val*val;
    #pragma unroll
    for (int off=32; off>0; off>>=1) ss += __shfl_down(ss, off);
    ss = __shfl(ss, 0);
    embn[v*E + e] = val * frcp(fmaxf(sqrtf(ss), 1.f));
  } else {
    if (tid < 64) acc[tid] = 0.f;
  }
}

// node_enc = [emb_n | node_features] @ W_enc + b_enc -> bf16
__global__ __launch_bounds__(256) void k_enc(const float* __restrict__ embn, const float* __restrict__ nf,
                                             const float* __restrict__ Wenc, const float* __restrict__ benc,
                                             short* __restrict__ nebf){
  __shared__ float As[16][80];
  int tid = threadIdx.x;
  int m0 = blockIdx.x*16;
  for (int idx=tid; idx<16*80; idx+=256){
    int i = idx/80, k = idx%80;
    int m = m0 + i; int v = m & (V-1);
    As[i][k] = (k < E) ? embn[v*E + k] : nf[m*F + (k-E)];
  }
  __syncthreads();
  int c = tid & 127, half = tid >> 7;
  float acc[8] = {0,0,0,0,0,0,0,0};
  for (int kk=0; kk<80; kk+=4){
    float w[4];
    #pragma unroll
    for (int u=0;u<4;u++) w[u] = Wenc[(kk+u)*H + c];
    #pragma unroll
    for (int i=0;i<8;i++){
      const float4 av = *reinterpret_cast<const float4*>(&As[half*8+i][kk]);
      acc[i] += av.x*w[0] + av.y*w[1] + av.z*w[2] + av.w*w[3];
    }
  }
  float bb = benc[c];
  #pragma unroll
  for (int i=0;i<8;i++){
    int m = m0 + half*8 + i;
    nebf[m*H + c] = f2bf(acc[i] + bb);
  }
}

// Fused GNN layer: per 64-node tile (+8 halo). t=tanh(h@Wg+bg) & logits for 80 rows,
// per-node softmax msg + x = tanh(msg+ne), then GRU -> hout. All in LDS.
__global__ __launch_bounds__(256) void k_layer(const short* __restrict__ hin, const short* __restrict__ nebf,
    const int* __restrict__ adj, const short* __restrict__ Wgt, const float* __restrict__ bg,
    const float* __restrict__ ag, const short* __restrict__ Wt, const float* __restrict__ bgru,
    short* __restrict__ hout){
  __shared__ short Hs[80][136];
  __shared__ short Ts[80][136];
  __shared__ short Xs[64][136];
  __shared__ float Lp[4][80];
  __shared__ float Ls[80];
  int tid = threadIdx.x;
  int blk = blockIdx.x;
  int b = blk >> 4;
  int n0 = (blk & 15) << 6;
  // stage Hs: 80 rows (halo ±8) x 16 bf16x8 chunks
  for (int idx=tid; idx<80*16; idx+=256){
    int r = idx >> 4, c8 = idx & 15;
    int g = (b << 10) + ((n0 - 8 + r) & 1023);
    *reinterpret_cast<bf16x8*>(&Hs[r][c8*8]) =
        *reinterpret_cast<const bf16x8*>(&hin[(long)g*128 + c8*8]);
  }
  __syncthreads();
  int w = tid >> 6, lane = tid & 63;
  int l15 = lane & 15, quad = lane >> 4;
  // ---- phase 1: t + logits for 80 rows ----
  {
    f32x4 acc[5][2];
    #pragma unroll
    for (int mt=0;mt<5;mt++)
      #pragma unroll
      for (int u=0;u<2;u++) acc[mt][u] = (f32x4){0.f,0.f,0.f,0.f};
    #pragma unroll
    for (int kc=0;kc<4;kc++){
      int k0 = kc*32;
      bf16x8 a[5];
      #pragma unroll
      for (int mt=0;mt<5;mt++)
        a[mt] = *reinterpret_cast<const bf16x8*>(&Hs[16*mt + l15][k0 + quad*8]);
      #pragma unroll
      for (int u=0;u<2;u++){
        bf16x8 bfr = *reinterpret_cast<const bf16x8*>(&Wgt[(32*w + 16*u + l15)*128 + k0 + quad*8]);
        #pragma unroll
        for (int mt=0;mt<5;mt++)
          acc[mt][u] = __builtin_amdgcn_mfma_f32_16x16x32_bf16(a[mt], bfr, acc[mt][u], 0,0,0);
      }
    }
    float lp[5][4];
    #pragma unroll
    for (int mt=0;mt<5;mt++)
      #pragma unroll
      for (int reg=0;reg<4;reg++) lp[mt][reg] = 0.f;
    #pragma unroll
    for (int u=0;u<2;u++){
      int c = 32*w + 16*u + l15;
      float bgc = bg[c], agc = ag[c];
      #pragma unroll
      for (int mt=0;mt<5;mt++){
        #pragma unroll
        for (int reg=0;reg<4;reg++){
          float t = ftanh(acc[mt][u][reg] + bgc);
          Ts[16*mt + quad*4 + reg][c] = f2bf(t);
          lp[mt][reg] += t * agc;
        }
      }
    }
    #pragma unroll
    for (int mt=0;mt<5;mt++)
      #pragma unroll
      for (int reg=0;reg<4;reg++){
        lp[mt][reg] += __shfl_xor(lp[mt][reg], 1);
        lp[mt][reg] += __shfl_xor(lp[mt][reg], 2);
        lp[mt][reg] += __shfl_xor(lp[mt][reg], 4);
        lp[mt][reg] += __shfl_xor(lp[mt][reg], 8);
      }
    if (l15 == 0){
      #pragma unroll
      for (int mt=0;mt<5;mt++)
        #pragma unroll
        for (int reg=0;reg<4;reg++)
          Lp[w][16*mt + quad*4 + reg] = lp[mt][reg];
    }
  }
  __syncthreads();
  if (tid < 80) Ls[tid] = Lp[0][tid]+Lp[1][tid]+Lp[2][tid]+Lp[3][tid];
  __syncthreads();
  // ---- phase 2: msg + x for 64 owned nodes (4 threads per node, 32 cols each) ----
  {
    int vl = tid >> 2, seg = tid & 3;
    int vg = (b<<10) + n0 + vl;
    int li[16]; float at[16];
    float m = -1e30f;
    #pragma unroll
    for (int d=0; d<16; d++){
      int a = adj[vg*16 + d];
      li[d] = (a - n0 + 8) & 1023;           // in [0,80)
      m = fmaxf(m, Ls[li[d]]);
    }
    float s = 0.f;
    #pragma unroll
    for (int d=0; d<16; d++){ at[d] = __expf(Ls[li[d]] - m); s += at[d]; }
    float inv = frcp(s);
    #pragma unroll
    for (int d=0; d<16; d++) at[d] *= inv;
    #pragma unroll
    for (int c8=0; c8<4; c8++){
      int c = seg*32 + c8*8;
      float acc8[8] = {0,0,0,0,0,0,0,0};
      #pragma unroll 4
      for (int d=0; d<16; d++){
        bf16x8 tv = *reinterpret_cast<const bf16x8*>(&Ts[li[d]][c]);
        float a = at[d];
        #pragma unroll
        for (int q=0;q<8;q++) acc8[q] += a * bf2f(tv[q]);
      }
      bf16x8 nv = *reinterpret_cast<const bf16x8*>(&nebf[(long)vg*128 + c]);
      bf16x8 xv;
      #pragma unroll
      for (int q=0;q<8;q++) xv[q] = f2bf(ftanh(acc8[q] + bf2f(nv[q])));
      *reinterpret_cast<bf16x8*>(&Xs[vl][c]) = xv;
    }
  }
  __syncthreads();
  // ---- phase 3: GRU for 64 owned rows; x from Xs, h from Hs[r+8] ----
  f32x4 acc[4][4][2];
  #pragma unroll
  for (int mt=0;mt<4;mt++)
    #pragma unroll
    for (int g=0;g<4;g++)
      #pragma unroll
      for (int u=0;u<2;u++) acc[mt][g][u] = (f32x4){0.f,0.f,0.f,0.f};
  for (int k8=0;k8<8;k8++){
    int k0 = k8*32;
    int gg = (k8 < 4) ? 2 : 3;
    bf16x8 a[4];
    #pragma unroll
    for (int mt=0;mt<4;mt++){
      if (k8 < 4) a[mt] = *reinterpret_cast<const bf16x8*>(&Xs[16*mt + l15][k0 + quad*8]);
      else        a[mt] = *reinterpret_cast<const bf16x8*>(&Hs[16*mt + l15 + 8][k0 - 128 + quad*8]);
    }
    bf16x8 bz[2], br[2], bc[2];
    #pragma unroll
    for (int u=0;u<2;u++){
      int ncol = 32*w + 16*u + l15;
      int koff = k0 + quad*8;
      bz[u] = *reinterpret_cast<const bf16x8*>(&Wt[(ncol      )*256 + koff]);
      br[u] = *reinterpret_cast<const bf16x8*>(&Wt[(ncol + 128)*256 + koff]);
      bc[u] = *reinterpret_cast<const bf16x8*>(&Wt[(ncol + gg*128)*256 + koff]);
    }
    #pragma unroll
    for (int mt=0;mt<4;mt++){
      #pragma unroll
      for (int u=0;u<2;u++){
        acc[mt][0][u]  = __builtin_amdgcn_mfma_f32_16x16x32_bf16(a[mt], bz[u], acc[mt][0][u], 0,0,0);
        acc[mt][1][u]  = __builtin_amdgcn_mfma_f32_16x16x32_bf16(a[mt], br[u], acc[mt][1][u], 0,0,0);
        acc[mt][gg][u] = __builtin_amdgcn_mfma_f32_16x16x32_bf16(a[mt], bc[u], acc[mt][gg][u], 0,0,0);
      }
    }
  }
  __syncthreads();   // everyone done reading Xs; safe to overwrite
  #pragma unroll
  for (int u=0;u<2;u++){
    int j = 32*w + 16*u + l15;
    float bjz = bgru[j], bjr = bgru[128 + j], bjc = bgru[256 + j];
    #pragma unroll
    for (int mt=0;mt<4;mt++){
      #pragma unroll
      for (int reg=0;reg<4;reg++){
        int rl = 16*mt + quad*4 + reg;
        float z = fsig(acc[mt][0][u][reg] + bjz);
        float r = fsig(acc[mt][1][u][reg] + bjr);
        float cand = ftanh(acc[mt][2][u][reg] + bjc + r*acc[mt][3][u][reg]);
        float ho = bf2f(Hs[rl + 8][j]);
        Xs[rl][j] = f2bf(z*ho + (1.f - z)*cand);
      }
    }
  }
  __syncthreads();
  for (int idx=tid; idx<64*16; idx+=256){
    int r = idx >> 4, c8 = idx & 15;
    *reinterpret_cast<bf16x8*>(&hout[(long)((b<<10) + n0 + r)*128 + c8*8]) =
        *reinterpret_cast<const bf16x8*>(&Xs[r][c8*8]);
  }
}

// Fused decoder: PQ = h@Wpq in LDS (80 rows incl halo), per-edge tanh reduce -> nw
__global__ __launch_bounds__(256) void k_dec(const short* __restrict__ hn, const int* __restrict__ adj,
    const short* __restrict__ Wpq, const float* __restrict__ b1, const float* __restrict__ W2,
    const float* __restrict__ b2_, float* __restrict__ nw){
  __shared__ short Hs[80][136];
  __shared__ float PQs[80][132];   // padded vs 128 to break bank alignment
  int tid = threadIdx.x;
  int blk = blockIdx.x;
  int b = blk >> 4;
  int n0 = (blk & 15) << 6;
  for (int idx=tid; idx<80*16; idx+=256){
    int r = idx >> 4, c8 = idx & 15;
    int g = (b << 10) + ((n0 - 8 + r) & 1023);
    *reinterpret_cast<bf16x8*>(&Hs[r][c8*8]) =
        *reinterpret_cast<const bf16x8*>(&hn[(long)g*128 + c8*8]);
  }
  __syncthreads();
  int w = tid >> 6, lane = tid & 63;
  int l15 = lane & 15, quad = lane >> 4;
  {
    f32x4 acc[5][2];
    #pragma unroll
    for (int mt=0;mt<5;mt++)
      #pragma unroll
      for (int u=0;u<2;u++) acc[mt][u] = (f32x4){0.f,0.f,0.f,0.f};
    #pragma unroll
    for (int kc=0;kc<4;kc++){
      int k0 = kc*32;
      bf16x8 a[5];
      #pragma unroll
      for (int mt=0;mt<5;mt++)
        a[mt] = *reinterpret_cast<const bf16x8*>(&Hs[16*mt + l15][k0 + quad*8]);
      #pragma unroll
      for (int u=0;u<2;u++){
        bf16x8 bfr = *reinterpret_cast<const bf16x8*>(&Wpq[(32*w + 16*u + l15)*128 + k0 + quad*8]);
        #pragma unroll
        for (int mt=0;mt<5;mt++)
          acc[mt][u] = __builtin_amdgcn_mfma_f32_16x16x32_bf16(a[mt], bfr, acc[mt][u], 0,0,0);
      }
    }
    #pragma unroll
    for (int u=0;u<2;u++){
      int c = 32*w + 16*u + l15;
      #pragma unroll
      for (int mt=0;mt<5;mt++)
        #pragma unroll
        for (int reg=0;reg<4;reg++)
          PQs[16*mt + quad*4 + reg][c] = acc[mt][u][reg];
    }
  }
  __syncthreads();
  float b2v = b2_[0];
  for (int e = tid; e < 1024; e += 256){
    int vl = e >> 4, d = e & 15;
    int vg = (b<<10) + n0 + vl;
    int a = adj[vg*16 + d];
    int al = (a - n0 + 8) & 1023;
    float p = 0.f;
    #pragma unroll 8
    for (int c=0;c<64;c++)
      p += ftanh(PQs[al][c] + PQs[vl + 8][64 + c] + b1[c]) * W2[c];
    nw[vg*16 + d] = p + b2v;
  }
}

// Fused dest-attn softmax + regather + sparsemax. 64 owned nodes, nw halo ±16.
__global__ __launch_bounds__(256) void k_das(const float* __restrict__ nw, const int* __restrict__ adj,
    const int* __restrict__ invadj, float* __restrict__ norm_){
  __shared__ float nws[104][17];
  __shared__ float datt[80][17];
  int tid = threadIdx.x;
  int blk = blockIdx.x;
  int b = blk >> 4;
  int n0 = (blk & 15) << 6;
  for (int idx=tid; idx<104*4; idx+=256){
    int r = idx >> 2, q4 = idx & 3;
    int g = (b << 10) + ((n0 - 16 + r) & 1023);
    float4 v = reinterpret_cast<const float4*>(&nw[(long)g*16])[q4];
    nws[r][q4*4+0]=v.x; nws[r][q4*4+1]=v.y; nws[r][q4*4+2]=v.z; nws[r][q4*4+3]=v.w;
  }
  __syncthreads();
  if (tid < 80){
    int wg = (b<<10) + ((n0 - 8 + tid) & 1023);
    float vals[16];
    float m = -1e30f;
    #pragma unroll
    for (int d=0; d<16; d++){
      int iv = invadj[wg*16 + d];
      int il = (iv - n0 + 16) & 1023;        // in [0,104)
      vals[d] = nws[il][d];
      m = fmaxf(m, vals[d]);
    }
    float s = 0.f;
    #pragma unroll
    for (int d=0; d<16; d++){ vals[d] = __expf(vals[d]-m); s += vals[d]; }
    float inv = frcp(s);
    #pragma unroll
    for (int d=0; d<16; d++) datt[tid][d] = vals[d]*inv;
  }
  __syncthreads();
  if (tid < 64){
    int vg = (b<<10) + n0 + tid;
    float z[16], s[16];
    #pragma unroll
    for (int d=0; d<16; d++){
      int a = adj[vg*16 + d];
      int al = (a - n0 + 8) & 1023;
      z[d] = datt[al][d];
      s[d] = z[d];
    }
    #pragma unroll
    for (int k2 = 2; k2 <= 16; k2 <<= 1){
      #pragma unroll
      for (int jj = k2 >> 1; jj > 0; jj >>= 1){
        #pragma unroll
        for (int i = 0; i < 16; i++){
          int l = i ^ jj;
          if (l > i){
            bool up = ((i & k2) == 0);
            float a = s[i], bb = s[l];
            bool sw = up ? (a > bb) : (a < bb);
            if (sw){ s[i]=bb; s[l]=a; }
          }
        }
      }
    }
    float cs = 0.f, zcs = 0.f; int kz = 1;
    #pragma unroll
    for (int j=0;j<16;j++){
      float zj = s[15-j];
      cs += zj;
      if (1.f + (float)(j+1)*zj > cs){ kz = j+1; zcs = cs; }
    }
    float tau = (zcs - 1.f)/(float)kz;
    #pragma unroll
    for (int d=0; d<16; d++) norm_[vg*16 + d] = fmaxf(z[d]-tau, 0.f);
  }
}

// Flow solver on the rank-1 structure: iterate s[v] only; emit flow_cost[b] directly.
__global__ __launch_bounds__(1024) void k_flow(const float* __restrict__ norm_,
    const float* __restrict__ dem, const int* __restrict__ invadj, float* __restrict__ accF){
  __shared__ float sbuf[2][V];
  __shared__ float red[16];
  int b = blockIdx.x, v = threadIdx.x;
  int gv = (b<<10) + v;
  int iv[16]; float nrg[16];
  float nr2 = 0.f;
  #pragma unroll
  for (int d4=0; d4<4; d4++){
    int4 i4 = reinterpret_cast<const int4*>(&invadj[(long)gv*16])[d4];
    iv[d4*4+0]=i4.x; iv[d4*4+1]=i4.y; iv[d4*4+2]=i4.z; iv[d4*4+3]=i4.w;
    float4 n4 = reinterpret_cast<const float4*>(&norm_[(long)gv*16])[d4];
    nr2 += n4.x*n4.x + n4.y*n4.y + n4.z*n4.z + n4.w*n4.w;
  }
  #pragma unroll
  for (int d=0; d<16; d++) nrg[d] = norm_[((b<<10) + iv[d])*16 + d];
  float dm = dem[gv];
  sbuf[0][v] = 0.f;
  __syncthreads();
  int p = 0;
  float s = 0.f;
  for (int it=0; it<10; it++){
    float inflow = 0.f;
    #pragma unroll
    for (int d=0; d<16; d++) inflow += nrg[d]*sbuf[p][iv[d]];
    s = fmaxf(inflow - dm, 0.f);
    sbuf[1-p][v] = s;
    p ^= 1;
    __syncthreads();
  }
  float part = nr2 * s * s;
  #pragma unroll
  for (int off=32; off>0; off>>=1) part += __shfl_down(part, off);
  if ((v & 63) == 0) red[v >> 6] = part;
  __syncthreads();
  if (v == 0){
    float t = 0.f;
    #pragma unroll
    for (int i=0;i<16;i++) t += red[i];
    accF[b] = t;
  }
}

// dual_vars: node_states = gather-sum of hnode2 over adj (±8), MLP. Wave per node.
__global__ __launch_bounds__(256) void k_dualvars(const short* __restrict__ hn2, const int* __restrict__ adj,
    const float* __restrict__ W1, const float* __restrict__ b1, const float* __restrict__ W2,
    const float* __restrict__ b2_, float* __restrict__ dv){
  __shared__ float ns[4][128];
  __shared__ int adjs[4][16];
  int tid = threadIdx.x;
  int w = tid >> 6, lane = tid & 63;
  int node = blockIdx.x*4 + w;
  int b = node >> 10;
  if (lane < 16) adjs[w][lane] = (b<<10) + adj[node*16 + lane];
  __syncthreads();
  int c0 = lane, c1 = lane + 64;
  float s0 = 0.f, s1 = 0.f;
  #pragma unroll 4
  for (int d=0; d<16; d++){
    int a = adjs[w][d];
    s0 += bf2f(hn2[(long)a*128 + c0]);
    s1 += bf2f(hn2[(long)a*128 + c1]);
  }
  ns[w][c0] = s0; ns[w][c1] = s1;
  __syncthreads();
  float acc = 0.f;
  #pragma unroll 8
  for (int k=0;k<128;k++) acc += ns[w][k]*W1[k*HD + lane];
  float t = ftanh(acc + b1[lane]) * W2[lane];
  #pragma unroll
  for (int off=32; off>0; off>>=1) t += __shfl_down(t, off);
  if (lane == 0) dv[node] = fmaxf(t + b2_[0], 0.f);
}

// dual cost (x16 multiplicity) + dual_demand per batch — per node, tree reduce
__global__ __launch_bounds__(1024) void k_dd2(const float* __restrict__ dv, const float* __restrict__ dem,
                                              float* __restrict__ accD, float* __restrict__ accDD){
  __shared__ float r1[16], r2[16];
  int b = blockIdx.x, v = threadIdx.x;
  int gv = (b<<10) + v;
  float dvv = dv[gv];
  float f = 0.f, vel = 0.f;
  #pragma unroll
  for (int it=0; it<10; it++){
    float g = 2.f*f + dvv;
    vel = 0.9f*vel - 0.01f*g;
    f = fmaxf(f + vel, 0.f);
  }
  float cd = f*f + dvv*f;
  float dd = dvv * dem[gv];
  #pragma unroll
  for (int off=32; off>0; off>>=1){ cd += __shfl_down(cd, off); dd += __shfl_down(dd, off); }
  if ((v & 63) == 0){ r1[v >> 6] = cd; r2[v >> 6] = dd; }
  __syncthreads();
  if (v == 0){
    float s1 = 0.f, s2 = 0.f;
    #pragma unroll
    for (int i=0;i<16;i++){ s1 += r1[i]; s2 += r2[i]; }
    accD[b] = 16.f*s1;
    accDD[b] = s2;
  }
}

__global__ __launch_bounds__(64) void k_final(const float* __restrict__ acc, float* __restrict__ out){
  int b = threadIdx.x;
  if (b < B){
    float fc = acc[b], dc = acc[16+b], dd = acc[32+b];
    out[b] = fc - (dc - dd);
  }
}

extern "C" void kernel_launch(void* const* d_in, const int* in_sizes, int n_in,
                              void* d_out, int out_size, void* d_ws, size_t ws_size,
                              hipStream_t stream){
  (void)in_sizes; (void)n_in; (void)out_size; (void)ws_size;
  const float* demands = (const float*)d_in[0];
  const float* nf      = (const float*)d_in[1];
  const float* emb     = (const float*)d_in[4];
  const float* Wenc    = (const float*)d_in[5];
  const float* benc    = (const float*)d_in[6];
  const float* Wgat    = (const float*)d_in[7];
  const float* bgat    = (const float*)d_in[8];
  const float* agat    = (const float*)d_in[9];
  const float* Wgx     = (const float*)d_in[10];
  const float* Wgh     = (const float*)d_in[11];
  const float* bgru    = (const float*)d_in[12];
  const float* Wd1     = (const float*)d_in[13];
  const float* bd1     = (const float*)d_in[14];
  const float* Wd2     = (const float*)d_in[15];
  const float* bd2     = (const float*)d_in[16];
  const float* Wu1     = (const float*)d_in[17];
  const float* bu1     = (const float*)d_in[18];
  const float* Wu2     = (const float*)d_in[19];
  const float* bu2     = (const float*)d_in[20];
  const int* adj       = (const int*)d_in[21];
  const int* invadj    = (const int*)d_in[22];

  float* ws    = (float*)d_ws;
  short* nebf  = (short*)(ws + OFF_NEBF);
  short* hnA   = (short*)(ws + OFF_HNA);
  short* hnB   = (short*)(ws + OFF_HNB);
  float* nw    = ws + OFF_NW;
  float* nrm   = ws + OFF_NORM;
  float* dv    = ws + OFF_DV;
  float* acc   = ws + OFF_ACC;
  short* wt    = (short*)(ws + OFF_WT);
  short* wtg   = (short*)(ws + OFF_WTG);
  short* wpq   = (short*)(ws + OFF_WPQ);
  float* embn  = ws + OFF_EMB;

  k_prep<<<865, 256, 0, stream>>>(Wgx, Wgh, Wgat, Wd1, emb, wt, wtg, wpq, embn, acc);
  k_enc<<<BV/16, 256, 0, stream>>>(embn, nf, Wenc, benc, nebf);
  k_layer<<<BV/64, 256, 0, stream>>>(nebf, nebf, adj, wtg, bgat, agat, wt, bgru, hnA);
  k_layer<<<BV/64, 256, 0, stream>>>(hnA, nebf, adj, wtg, bgat, agat, wt, bgru, hnB);
  k_dec<<<BV/64, 256, 0, stream>>>(hnB, adj, wpq, bd1, Wd2, bd2, nw);
  k_das<<<BV/64, 256, 0, stream>>>(nw, adj, invadj, nrm);
  k_flow<<<B, 1024, 0, stream>>>(nrm, demands, invadj, acc);
  k_dualvars<<<BV/4, 256, 0, stream>>>(hnB, adj, Wu1, bu1, Wu2, bu2, dv);
  k_dd2<<<B, 1024, 0, stream>>>(dv, demands, acc+16, acc+32);
  k_final<<<1, 64, 0, stream>>>(acc, (float*)d_out);
}

// Round 11
// 221.044 us; speedup vs baseline: 4.4476x; 1.0140x over previous
//
#include <hip/hip_runtime.h>
#include <hip/hip_bf16.h>

#define B 16
#define V 1024
#define D 16
#define E 64
#define F 16
#define H 128
#define HD 64
#define BV (B*V)      // 16384
#define BVD (B*V*D)   // 262144

// ---- workspace layout (float offsets) ----
#define OFF_NEBF     0                         // node_enc bf16 (BV*H shorts)
#define OFF_HNA      (OFF_NEBF + BV*H/2)       // hnode layer1 bf16
#define OFF_HNB      (OFF_HNA + BV*H/2)        // hnode layer2 bf16
#define OFF_NORM     (OFF_HNB + BV*H/2)        // sparsemax output fp32 (BVD)
#define OFF_DV       (OFF_NORM + BVD)          // dual vars (BV)
#define OFF_WT       (OFF_DV + BV)             // 512x256 bf16 GRU weights
#define OFF_WTG      (OFF_WT + 65536)          // 128x128 bf16 GAT weights
#define OFF_WPQ      (OFF_WTG + 8192)          // 128x128 bf16 dec [P|Q] weights

typedef __attribute__((ext_vector_type(8))) short bf16x8;
typedef __attribute__((ext_vector_type(4))) float f32x4;

__device__ __forceinline__ short f2bf(float f){
  __hip_bfloat16 b = __float2bfloat16(f);
  return *reinterpret_cast<short*>(&b);
}
__device__ __forceinline__ float bf2f(short s){
  __hip_bfloat16 b; *reinterpret_cast<short*>(&b) = s;
  return __bfloat162float(b);
}
__device__ __forceinline__ float frcp(float x){ return __builtin_amdgcn_rcpf(x); }
__device__ __forceinline__ float fsig(float x){ return frcp(1.f + __expf(-x)); }
__device__ __forceinline__ float ftanh(float x){
  float e = __expf(-2.f*fabsf(x));
  float r = (1.f - e)*frcp(1.f + e);
  return copysignf(r, x);
}

// ---- merged prep + encoder ----
// blocks [0,512) GRU pack | [512,576) GAT pack | [576,608) dec P/Q pack | [608,1632) enc (inline embnorm)
__global__ __launch_bounds__(256) void k_pre(const float* __restrict__ Wx, const float* __restrict__ Wh,
    const float* __restrict__ Wg, const float* __restrict__ W1, const float* __restrict__ emb,
    const float* __restrict__ nf, const float* __restrict__ Wenc, const float* __restrict__ benc,
    short* __restrict__ Wt, short* __restrict__ Wgt, short* __restrict__ Wpq,
    short* __restrict__ nebf){
  int bid = blockIdx.x, tid = threadIdx.x;
  if (bid < 512){
    int n = bid, k = tid;
    int g = n >> 7, j = n & 127;
    float v;
    if (g == 0)      v = (k < 128) ? Wx[k*384 + j]       : Wh[(k-128)*384 + j];
    else if (g == 1) v = (k < 128) ? Wx[k*384 + 128 + j] : Wh[(k-128)*384 + 128 + j];
    else if (g == 2) v = (k < 128) ? Wx[k*384 + 256 + j] : 0.f;
    else             v = (k < 128) ? 0.f                 : Wh[(k-128)*384 + 256 + j];
    Wt[n*256 + k] = f2bf(v);
    return;
  }
  if (bid < 576){
    int idx = (bid-512)*256 + tid;
    int n = idx >> 7, k = idx & 127;
    Wgt[n*128 + k] = f2bf(Wg[k*128 + n]);
    return;
  }
  if (bid < 608){
    int idx = (bid-576)*256 + tid;       // n<64, k<128
    int n = idx >> 7, k = idx & 127;
    float wb = W1[(k+128)*HD + n];
    float wa = W1[k*HD + n];
    Wpq[n*128 + k]      = f2bf(wa + wb);   // P weights
    Wpq[(64+n)*128 + k] = f2bf(wb);        // Q weights
    return;
  }
  // ---- encoder block ----
  __shared__ float As[16][80];
  __shared__ float nrmv[16];
  int m0 = (bid - 608)*16;
  {
    int i = tid >> 4, sl = tid & 15;
    int v = (m0 + i) & (V-1);
    float p = 0.f;
    #pragma unroll
    for (int j=0;j<4;j++){ float val = emb[v*E + sl*4 + j]; p += val*val; }
    p += __shfl_down(p, 8);
    p += __shfl_down(p, 4);
    p += __shfl_down(p, 2);
    p += __shfl_down(p, 1);
    if (sl == 0) nrmv[i] = frcp(fmaxf(sqrtf(p), 1.f));
  }
  __syncthreads();
  for (int idx=tid; idx<16*80; idx+=256){
    int i = idx/80, k = idx%80;
    int m = m0 + i; int v = m & (V-1);
    As[i][k] = (k < E) ? emb[v*E + k]*nrmv[i] : nf[m*F + (k-E)];
  }
  __syncthreads();
  int c = tid & 127, half = tid >> 7;
  float acc[8] = {0,0,0,0,0,0,0,0};
  for (int kk=0; kk<80; kk+=4){
    float w[4];
    #pragma unroll
    for (int u=0;u<4;u++) w[u] = Wenc[(kk+u)*H + c];
    #pragma unroll
    for (int i=0;i<8;i++){
      const float4 av = *reinterpret_cast<const float4*>(&As[half*8+i][kk]);
      acc[i] += av.x*w[0] + av.y*w[1] + av.z*w[2] + av.w*w[3];
    }
  }
  float bb = benc[c];
  #pragma unroll
  for (int i=0;i<8;i++){
    int m = m0 + half*8 + i;
    nebf[m*H + c] = f2bf(acc[i] + bb);
  }
}

// Fused GNN layer: per 64-node tile (+8 halo). t=tanh(h@Wg+bg) & logits for 80 rows,
// per-node softmax msg + x = tanh(msg+ne), then GRU -> hout. All in LDS.
__global__ __launch_bounds__(256) void k_layer(const short* __restrict__ hin, const short* __restrict__ nebf,
    const int* __restrict__ adj, const short* __restrict__ Wgt, const float* __restrict__ bg,
    const float* __restrict__ ag, const short* __restrict__ Wt, const float* __restrict__ bgru,
    short* __restrict__ hout){
  __shared__ short Hs[80][136];
  __shared__ short Ts[80][136];
  __shared__ short Xs[64][136];
  __shared__ float Lp[4][80];
  __shared__ float Ls[80];
  int tid = threadIdx.x;
  int blk = blockIdx.x;
  int b = blk >> 4;
  int n0 = (blk & 15) << 6;
  for (int idx=tid; idx<80*16; idx+=256){
    int r = idx >> 4, c8 = idx & 15;
    int g = (b << 10) + ((n0 - 8 + r) & 1023);
    *reinterpret_cast<bf16x8*>(&Hs[r][c8*8]) =
        *reinterpret_cast<const bf16x8*>(&hin[(long)g*128 + c8*8]);
  }
  __syncthreads();
  int w = tid >> 6, lane = tid & 63;
  int l15 = lane & 15, quad = lane >> 4;
  // ---- phase 1: t + logits for 80 rows ----
  {
    f32x4 acc[5][2];
    #pragma unroll
    for (int mt=0;mt<5;mt++)
      #pragma unroll
      for (int u=0;u<2;u++) acc[mt][u] = (f32x4){0.f,0.f,0.f,0.f};
    #pragma unroll
    for (int kc=0;kc<4;kc++){
      int k0 = kc*32;
      bf16x8 a[5];
      #pragma unroll
      for (int mt=0;mt<5;mt++)
        a[mt] = *reinterpret_cast<const bf16x8*>(&Hs[16*mt + l15][k0 + quad*8]);
      #pragma unroll
      for (int u=0;u<2;u++){
        bf16x8 bfr = *reinterpret_cast<const bf16x8*>(&Wgt[(32*w + 16*u + l15)*128 + k0 + quad*8]);
        #pragma unroll
        for (int mt=0;mt<5;mt++)
          acc[mt][u] = __builtin_amdgcn_mfma_f32_16x16x32_bf16(a[mt], bfr, acc[mt][u], 0,0,0);
      }
    }
    float lp[5][4];
    #pragma unroll
    for (int mt=0;mt<5;mt++)
      #pragma unroll
      for (int reg=0;reg<4;reg++) lp[mt][reg] = 0.f;
    #pragma unroll
    for (int u=0;u<2;u++){
      int c = 32*w + 16*u + l15;
      float bgc = bg[c], agc = ag[c];
      #pragma unroll
      for (int mt=0;mt<5;mt++){
        #pragma unroll
        for (int reg=0;reg<4;reg++){
          float t = ftanh(acc[mt][u][reg] + bgc);
          Ts[16*mt + quad*4 + reg][c] = f2bf(t);
          lp[mt][reg] += t * agc;
        }
      }
    }
    #pragma unroll
    for (int mt=0;mt<5;mt++)
      #pragma unroll
      for (int reg=0;reg<4;reg++){
        lp[mt][reg] += __shfl_xor(lp[mt][reg], 1);
        lp[mt][reg] += __shfl_xor(lp[mt][reg], 2);
        lp[mt][reg] += __shfl_xor(lp[mt][reg], 4);
        lp[mt][reg] += __shfl_xor(lp[mt][reg], 8);
      }
    if (l15 == 0){
      #pragma unroll
      for (int mt=0;mt<5;mt++)
        #pragma unroll
        for (int reg=0;reg<4;reg++)
          Lp[w][16*mt + quad*4 + reg] = lp[mt][reg];
    }
  }
  __syncthreads();
  if (tid < 80) Ls[tid] = Lp[0][tid]+Lp[1][tid]+Lp[2][tid]+Lp[3][tid];
  __syncthreads();
  // ---- phase 2: msg + x for 64 owned nodes ----
  {
    int vl = tid >> 2, seg = tid & 3;
    int vg = (b<<10) + n0 + vl;
    int li[16]; float at[16];
    float m = -1e30f;
    #pragma unroll
    for (int d=0; d<16; d++){
      int a = adj[vg*16 + d];
      li[d] = (a - n0 + 8) & 1023;
      m = fmaxf(m, Ls[li[d]]);
    }
    float s = 0.f;
    #pragma unroll
    for (int d=0; d<16; d++){ at[d] = __expf(Ls[li[d]] - m); s += at[d]; }
    float inv = frcp(s);
    #pragma unroll
    for (int d=0; d<16; d++) at[d] *= inv;
    #pragma unroll
    for (int c8=0; c8<4; c8++){
      int c = seg*32 + c8*8;
      float acc8[8] = {0,0,0,0,0,0,0,0};
      #pragma unroll 4
      for (int d=0; d<16; d++){
        bf16x8 tv = *reinterpret_cast<const bf16x8*>(&Ts[li[d]][c]);
        float a = at[d];
        #pragma unroll
        for (int q=0;q<8;q++) acc8[q] += a * bf2f(tv[q]);
      }
      bf16x8 nv = *reinterpret_cast<const bf16x8*>(&nebf[(long)vg*128 + c]);
      bf16x8 xv;
      #pragma unroll
      for (int q=0;q<8;q++) xv[q] = f2bf(ftanh(acc8[q] + bf2f(nv[q])));
      *reinterpret_cast<bf16x8*>(&Xs[vl][c]) = xv;
    }
  }
  __syncthreads();
  // ---- phase 3: GRU for 64 owned rows ----
  f32x4 acc[4][4][2];
  #pragma unroll
  for (int mt=0;mt<4;mt++)
    #pragma unroll
    for (int g=0;g<4;g++)
      #pragma unroll
      for (int u=0;u<2;u++) acc[mt][g][u] = (f32x4){0.f,0.f,0.f,0.f};
  for (int k8=0;k8<8;k8++){
    int k0 = k8*32;
    int gg = (k8 < 4) ? 2 : 3;
    bf16x8 a[4];
    #pragma unroll
    for (int mt=0;mt<4;mt++){
      if (k8 < 4) a[mt] = *reinterpret_cast<const bf16x8*>(&Xs[16*mt + l15][k0 + quad*8]);
      else        a[mt] = *reinterpret_cast<const bf16x8*>(&Hs[16*mt + l15 + 8][k0 - 128 + quad*8]);
    }
    bf16x8 bz[2], br[2], bc[2];
    #pragma unroll
    for (int u=0;u<2;u++){
      int ncol = 32*w + 16*u + l15;
      int koff = k0 + quad*8;
      bz[u] = *reinterpret_cast<const bf16x8*>(&Wt[(ncol      )*256 + koff]);
      br[u] = *reinterpret_cast<const bf16x8*>(&Wt[(ncol + 128)*256 + koff]);
      bc[u] = *reinterpret_cast<const bf16x8*>(&Wt[(ncol + gg*128)*256 + koff]);
    }
    #pragma unroll
    for (int mt=0;mt<4;mt++){
      #pragma unroll
      for (int u=0;u<2;u++){
        acc[mt][0][u]  = __builtin_amdgcn_mfma_f32_16x16x32_bf16(a[mt], bz[u], acc[mt][0][u], 0,0,0);
        acc[mt][1][u]  = __builtin_amdgcn_mfma_f32_16x16x32_bf16(a[mt], br[u], acc[mt][1][u], 0,0,0);
        acc[mt][gg][u] = __builtin_amdgcn_mfma_f32_16x16x32_bf16(a[mt], bc[u], acc[mt][gg][u], 0,0,0);
      }
    }
  }
  __syncthreads();
  #pragma unroll
  for (int u=0;u<2;u++){
    int j = 32*w + 16*u + l15;
    float bjz = bgru[j], bjr = bgru[128 + j], bjc = bgru[256 + j];
    #pragma unroll
    for (int mt=0;mt<4;mt++){
      #pragma unroll
      for (int reg=0;reg<4;reg++){
        int rl = 16*mt + quad*4 + reg;
        float z = fsig(acc[mt][0][u][reg] + bjz);
        float r = fsig(acc[mt][1][u][reg] + bjr);
        float cand = ftanh(acc[mt][2][u][reg] + bjc + r*acc[mt][3][u][reg]);
        float ho = bf2f(Hs[rl + 8][j]);
        Xs[rl][j] = f2bf(z*ho + (1.f - z)*cand);
      }
    }
  }
  __syncthreads();
  for (int idx=tid; idx<64*16; idx+=256){
    int r = idx >> 4, c8 = idx & 15;
    *reinterpret_cast<bf16x8*>(&hout[(long)((b<<10) + n0 + r)*128 + c8*8]) =
        *reinterpret_cast<const bf16x8*>(&Xs[r][c8*8]);
  }
}

// Fully fused decoder + dest-attn + sparsemax per 64-node tile.
// PQ (bf16) for 112 rows (±24 halo), nw for 96 rows (±16), datt for 80 (±8), sparsemax 64.
__global__ __launch_bounds__(256) void k_decdas(const short* __restrict__ hn, const int* __restrict__ adj,
    const int* __restrict__ invadj, const short* __restrict__ Wpq, const float* __restrict__ b1,
    const float* __restrict__ W2, const float* __restrict__ b2_, float* __restrict__ norm_){
  __shared__ short Hs[112][136];     // 30464 B; later overlaid with nws[96][17] fp32
  __shared__ short PQb[112][132];    // 29568 B; later overlaid with datt[80][17] fp32
  __shared__ float b1s[64], w2s[64];
  int tid = threadIdx.x;
  int blk = blockIdx.x;
  int b = blk >> 4;
  int n0 = (blk & 15) << 6;
  if (tid < 64){ b1s[tid] = b1[tid]; w2s[tid] = W2[tid]; }
  for (int idx=tid; idx<112*16; idx+=256){
    int r = idx >> 4, c8 = idx & 15;
    int g = (b << 10) + ((n0 - 24 + r) & 1023);
    *reinterpret_cast<bf16x8*>(&Hs[r][c8*8]) =
        *reinterpret_cast<const bf16x8*>(&hn[(long)g*128 + c8*8]);
  }
  __syncthreads();
  int w = tid >> 6, lane = tid & 63;
  int l15 = lane & 15, quad = lane >> 4;
  // ---- PQ GEMM: 7 m-tiles x 128 cols ----
  {
    f32x4 acc[7][2];
    #pragma unroll
    for (int mt=0;mt<7;mt++)
      #pragma unroll
      for (int u=0;u<2;u++) acc[mt][u] = (f32x4){0.f,0.f,0.f,0.f};
    #pragma unroll
    for (int kc=0;kc<4;kc++){
      int k0 = kc*32;
      bf16x8 a[7];
      #pragma unroll
      for (int mt=0;mt<7;mt++)
        a[mt] = *reinterpret_cast<const bf16x8*>(&Hs[16*mt + l15][k0 + quad*8]);
      #pragma unroll
      for (int u=0;u<2;u++){
        bf16x8 bfr = *reinterpret_cast<const bf16x8*>(&Wpq[(32*w + 16*u + l15)*128 + k0 + quad*8]);
        #pragma unroll
        for (int mt=0;mt<7;mt++)
          acc[mt][u] = __builtin_amdgcn_mfma_f32_16x16x32_bf16(a[mt], bfr, acc[mt][u], 0,0,0);
      }
    }
    #pragma unroll
    for (int u=0;u<2;u++){
      int c = 32*w + 16*u + l15;
      #pragma unroll
      for (int mt=0;mt<7;mt++)
        #pragma unroll
        for (int reg=0;reg<4;reg++)
          PQb[16*mt + quad*4 + reg][c] = f2bf(acc[mt][u][reg]);
    }
  }
  __syncthreads();
  // ---- nw for 96 rows x 16 d -> overlay on Hs ----
  float* nws = reinterpret_cast<float*>(&Hs[0][0]);   // [96][17]
  float b2v = b2_[0];
  for (int e = tid; e < 96*16; e += 256){
    int rr = e >> 4, d = e & 15;
    int wnode = (n0 + rr - 16) & 1023;
    int wg = (b<<10) + wnode;
    int a = adj[wg*16 + d];
    int al = (a - n0 + 24) & 1023;      // PQ row of neighbor
    int wl = rr + 8;                    // PQ row of w
    float p = 0.f;
    #pragma unroll 8
    for (int c=0;c<64;c++)
      p += ftanh(bf2f(PQb[al][c]) + bf2f(PQb[wl][64 + c]) + b1s[c]) * w2s[c];
    nws[rr*17 + d] = p + b2v;
  }
  __syncthreads();
  // ---- dest softmax for 80 rows -> overlay on PQb ----
  float* datt = reinterpret_cast<float*>(&PQb[0][0]); // [80][17]
  if (tid < 80){
    int wnode = (n0 + tid - 8) & 1023;
    int wg = (b<<10) + wnode;
    float vals[16];
    float m = -1e30f;
    #pragma unroll
    for (int d=0; d<16; d++){
      int iv = invadj[wg*16 + d];
      int il = (iv - n0 + 16) & 1023;   // nw row
      vals[d] = nws[il*17 + d];
      m = fmaxf(m, vals[d]);
    }
    float s = 0.f;
    #pragma unroll
    for (int d=0; d<16; d++){ vals[d] = __expf(vals[d]-m); s += vals[d]; }
    float inv = frcp(s);
    #pragma unroll
    for (int d=0; d<16; d++) datt[tid*17 + d] = vals[d]*inv;
  }
  __syncthreads();
  // ---- sparsemax for 64 owned nodes ----
  if (tid < 64){
    int vg = (b<<10) + n0 + tid;
    float z[16], s[16];
    #pragma unroll
    for (int d=0; d<16; d++){
      int a = adj[vg*16 + d];
      int al = (a - n0 + 8) & 1023;     // datt row
      z[d] = datt[al*17 + d];
      s[d] = z[d];
    }
    #pragma unroll
    for (int k2 = 2; k2 <= 16; k2 <<= 1){
      #pragma unroll
      for (int jj = k2 >> 1; jj > 0; jj >>= 1){
        #pragma unroll
        for (int i = 0; i < 16; i++){
          int l = i ^ jj;
          if (l > i){
            bool up = ((i & k2) == 0);
            float a = s[i], bb = s[l];
            bool sw = up ? (a > bb) : (a < bb);
            if (sw){ s[i]=bb; s[l]=a; }
          }
        }
      }
    }
    float cs = 0.f, zcs = 0.f; int kz = 1;
    #pragma unroll
    for (int j=0;j<16;j++){
      float zj = s[15-j];
      cs += zj;
      if (1.f + (float)(j+1)*zj > cs){ kz = j+1; zcs = cs; }
    }
    float tau = (zcs - 1.f)/(float)kz;
    #pragma unroll
    for (int d=0; d<16; d++) norm_[(long)vg*16 + d] = fmaxf(z[d]-tau, 0.f);
  }
}

// dual_vars: node_states = gather-sum of hnode2 over adj, MLP. Wave per node.
__global__ __launch_bounds__(256) void k_dualvars(const short* __restrict__ hn2, const int* __restrict__ adj,
    const float* __restrict__ W1, const float* __restrict__ b1, const float* __restrict__ W2,
    const float* __restrict__ b2_, float* __restrict__ dv){
  __shared__ float ns[4][128];
  __shared__ int adjs[4][16];
  int tid = threadIdx.x;
  int w = tid >> 6, lane = tid & 63;
  int node = blockIdx.x*4 + w;
  int b = node >> 10;
  if (lane < 16) adjs[w][lane] = (b<<10) + adj[node*16 + lane];
  __syncthreads();
  int c0 = lane, c1 = lane + 64;
  float s0 = 0.f, s1 = 0.f;
  #pragma unroll 4
  for (int d=0; d<16; d++){
    int a = adjs[w][d];
    s0 += bf2f(hn2[(long)a*128 + c0]);
    s1 += bf2f(hn2[(long)a*128 + c1]);
  }
  ns[w][c0] = s0; ns[w][c1] = s1;
  __syncthreads();
  float acc = 0.f;
  #pragma unroll 8
  for (int k=0;k<128;k++) acc += ns[w][k]*W1[k*HD + lane];
  float t = ftanh(acc + b1[lane]) * W2[lane];
  #pragma unroll
  for (int off=32; off>0; off>>=1) t += __shfl_down(t, off);
  if (lane == 0) dv[node] = fmaxf(t + b2_[0], 0.f);
}

// Fused flow solver + dual cost + dual demand + final output. One block per batch.
__global__ __launch_bounds__(1024) void k_flowfin(const float* __restrict__ norm_,
    const float* __restrict__ dem, const int* __restrict__ invadj, const float* __restrict__ dv,
    float* __restrict__ out){
  __shared__ float sbuf[2][V];
  __shared__ float r1[16], r2[16], r3[16];
  int b = blockIdx.x, v = threadIdx.x;
  int gv = (b<<10) + v;
  int iv[16]; float nrg[16];
  float nr2 = 0.f;
  #pragma unroll
  for (int d4=0; d4<4; d4++){
    int4 i4 = reinterpret_cast<const int4*>(&invadj[(long)gv*16])[d4];
    iv[d4*4+0]=i4.x; iv[d4*4+1]=i4.y; iv[d4*4+2]=i4.z; iv[d4*4+3]=i4.w;
    float4 n4 = reinterpret_cast<const float4*>(&norm_[(long)gv*16])[d4];
    nr2 += n4.x*n4.x + n4.y*n4.y + n4.z*n4.z + n4.w*n4.w;
  }
  #pragma unroll
  for (int d=0; d<16; d++) nrg[d] = norm_[((b<<10) + iv[d])*16 + d];
  float dm = dem[gv];
  sbuf[0][v] = 0.f;
  __syncthreads();
  int p = 0;
  float s = 0.f;
  for (int it=0; it<10; it++){
    float inflow = 0.f;
    #pragma unroll
    for (int d=0; d<16; d++) inflow += nrg[d]*sbuf[p][iv[d]];
    s = fmaxf(inflow - dm, 0.f);
    sbuf[1-p][v] = s;
    p ^= 1;
    __syncthreads();
  }
  float partF = nr2 * s * s;
  // dual flow per node (x16 edge multiplicity)
  float dvv = dv[gv];
  float f = 0.f, vel = 0.f;
  #pragma unroll
  for (int it=0; it<10; it++){
    float g = 2.f*f + dvv;
    vel = 0.9f*vel - 0.01f*g;
    f = fmaxf(f + vel, 0.f);
  }
  float partD = f*f + dvv*f;
  float partDD = dvv * dm;
  #pragma unroll
  for (int off=32; off>0; off>>=1){
    partF  += __shfl_down(partF, off);
    partD  += __shfl_down(partD, off);
    partDD += __shfl_down(partDD, off);
  }
  if ((v & 63) == 0){ r1[v>>6] = partF; r2[v>>6] = partD; r3[v>>6] = partDD; }
  __syncthreads();
  if (v == 0){
    float sf = 0.f, sd = 0.f, sdd = 0.f;
    #pragma unroll
    for (int i=0;i<16;i++){ sf += r1[i]; sd += r2[i]; sdd += r3[i]; }
    out[b] = sf - (16.f*sd - sdd);
  }
}

extern "C" void kernel_launch(void* const* d_in, const int* in_sizes, int n_in,
                              void* d_out, int out_size, void* d_ws, size_t ws_size,
                              hipStream_t stream){
  (void)in_sizes; (void)n_in; (void)out_size; (void)ws_size;
  const float* demands = (const float*)d_in[0];
  const float* nf      = (const float*)d_in[1];
  const float* emb     = (const float*)d_in[4];
  const float* Wenc    = (const float*)d_in[5];
  const float* benc    = (const float*)d_in[6];
  const float* Wgat    = (const float*)d_in[7];
  const float* bgat    = (const float*)d_in[8];
  const float* agat    = (const float*)d_in[9];
  const float* Wgx     = (const float*)d_in[10];
  const float* Wgh     = (const float*)d_in[11];
  const float* bgru    = (const float*)d_in[12];
  const float* Wd1     = (const float*)d_in[13];
  const float* bd1     = (const float*)d_in[14];
  const float* Wd2     = (const float*)d_in[15];
  const float* bd2     = (const float*)d_in[16];
  const float* Wu1     = (const float*)d_in[17];
  const float* bu1     = (const float*)d_in[18];
  const float* Wu2     = (const float*)d_in[19];
  const float* bu2     = (const float*)d_in[20];
  const int* adj       = (const int*)d_in[21];
  const int* invadj    = (const int*)d_in[22];

  float* ws    = (float*)d_ws;
  short* nebf  = (short*)(ws + OFF_NEBF);
  short* hnA   = (short*)(ws + OFF_HNA);
  short* hnB   = (short*)(ws + OFF_HNB);
  float* nrm   = ws + OFF_NORM;
  float* dv    = ws + OFF_DV;
  short* wt    = (short*)(ws + OFF_WT);
  short* wtg   = (short*)(ws + OFF_WTG);
  short* wpq   = (short*)(ws + OFF_WPQ);

  k_pre<<<1632, 256, 0, stream>>>(Wgx, Wgh, Wgat, Wd1, emb, nf, Wenc, benc, wt, wtg, wpq, nebf);
  k_layer<<<BV/64, 256, 0, stream>>>(nebf, nebf, adj, wtg, bgat, agat, wt, bgru, hnA);
  k_layer<<<BV/64, 256, 0, stream>>>(hnA, nebf, adj, wtg, bgat, agat, wt, bgru, hnB);
  k_decdas<<<BV/64, 256, 0, stream>>>(hnB, adj, invadj, wpq, bd1, Wd2, bd2, nrm);
  k_dualvars<<<BV/4, 256, 0, stream>>>(hnB, adj, Wu1, bu1, Wu2, bu2, dv);
  k_flowfin<<<B, 1024, 0, stream>>>(nrm, demands, invadj, dv, (float*)d_out);
}

// Round 12
// 205.712 us; speedup vs baseline: 4.7791x; 1.0745x over previous
//
#include <hip/hip_runtime.h>
#include <hip/hip_bf16.h>

#define B 16
#define V 1024
#define D 16
#define E 64
#define F 16
#define H 128
#define HD 64
#define BV (B*V)      // 16384
#define BVD (B*V*D)   // 262144

// ---- workspace layout (float offsets) ----
#define OFF_NEBF     0                         // node_enc bf16 (BV*H shorts)
#define OFF_HNA      (OFF_NEBF + BV*H/2)       // hnode layer1 bf16
#define OFF_HNB      (OFF_HNA + BV*H/2)        // hnode layer2 bf16
#define OFF_NORM     (OFF_HNB + BV*H/2)        // sparsemax output fp32 (BVD)
#define OFF_DV       (OFF_NORM + BVD)          // dual vars (BV)
#define OFF_WT       (OFF_DV + BV)             // 512x256 bf16 GRU weights
#define OFF_WTG      (OFF_WT + 65536)          // 128x128 bf16 GAT weights
#define OFF_WPQ      (OFF_WTG + 8192)          // 128x128 bf16 dec [P|Q] weights
#define OFF_WU1T     (OFF_WPQ + 8192)          // 64x128 bf16 dual W1^T

typedef __attribute__((ext_vector_type(8))) short bf16x8;
typedef __attribute__((ext_vector_type(4))) float f32x4;

__device__ __forceinline__ short f2bf(float f){
  __hip_bfloat16 b = __float2bfloat16(f);
  return *reinterpret_cast<short*>(&b);
}
__device__ __forceinline__ float bf2f(short s){
  __hip_bfloat16 b; *reinterpret_cast<short*>(&b) = s;
  return __bfloat162float(b);
}
__device__ __forceinline__ float frcp(float x){ return __builtin_amdgcn_rcpf(x); }
__device__ __forceinline__ float fsig(float x){ return frcp(1.f + __expf(-x)); }
__device__ __forceinline__ float ftanh(float x){
  float e = __expf(-2.f*fabsf(x));
  float r = (1.f - e)*frcp(1.f + e);
  return copysignf(r, x);
}

// ---- merged prep + encoder ----
// [0,512) GRU | [512,576) GAT | [576,608) dec P/Q | [608,640) dual W1^T | [640,1664) enc
__global__ __launch_bounds__(256) void k_pre(const float* __restrict__ Wx, const float* __restrict__ Wh,
    const float* __restrict__ Wg, const float* __restrict__ W1, const float* __restrict__ Wu1,
    const float* __restrict__ emb, const float* __restrict__ nf,
    const float* __restrict__ Wenc, const float* __restrict__ benc,
    short* __restrict__ Wt, short* __restrict__ Wgt, short* __restrict__ Wpq,
    short* __restrict__ Wu1t, short* __restrict__ nebf){
  int bid = blockIdx.x, tid = threadIdx.x;
  if (bid < 512){
    int n = bid, k = tid;
    int g = n >> 7, j = n & 127;
    float v;
    if (g == 0)      v = (k < 128) ? Wx[k*384 + j]       : Wh[(k-128)*384 + j];
    else if (g == 1) v = (k < 128) ? Wx[k*384 + 128 + j] : Wh[(k-128)*384 + 128 + j];
    else if (g == 2) v = (k < 128) ? Wx[k*384 + 256 + j] : 0.f;
    else             v = (k < 128) ? 0.f                 : Wh[(k-128)*384 + 256 + j];
    Wt[n*256 + k] = f2bf(v);
    return;
  }
  if (bid < 576){
    int idx = (bid-512)*256 + tid;
    int n = idx >> 7, k = idx & 127;
    Wgt[n*128 + k] = f2bf(Wg[k*128 + n]);
    return;
  }
  if (bid < 608){
    int idx = (bid-576)*256 + tid;       // n<64, k<128
    int n = idx >> 7, k = idx & 127;
    float wb = W1[(k+128)*HD + n];
    float wa = W1[k*HD + n];
    Wpq[n*128 + k]      = f2bf(wa + wb);   // P weights
    Wpq[(64+n)*128 + k] = f2bf(wb);        // Q weights
    return;
  }
  if (bid < 640){
    int idx = (bid-608)*256 + tid;       // n<64, k<128
    int n = idx >> 7, k = idx & 127;
    Wu1t[n*128 + k] = f2bf(Wu1[k*HD + n]);
    return;
  }
  // ---- encoder block ----
  __shared__ float As[16][80];
  __shared__ float nrmv[16];
  int m0 = (bid - 640)*16;
  {
    int i = tid >> 4, sl = tid & 15;
    int v = (m0 + i) & (V-1);
    float p = 0.f;
    #pragma unroll
    for (int j=0;j<4;j++){ float val = emb[v*E + sl*4 + j]; p += val*val; }
    p += __shfl_down(p, 8);
    p += __shfl_down(p, 4);
    p += __shfl_down(p, 2);
    p += __shfl_down(p, 1);
    if (sl == 0) nrmv[i] = frcp(fmaxf(sqrtf(p), 1.f));
  }
  __syncthreads();
  for (int idx=tid; idx<16*80; idx+=256){
    int i = idx/80, k = idx%80;
    int m = m0 + i; int v = m & (V-1);
    As[i][k] = (k < E) ? emb[v*E + k]*nrmv[i] : nf[m*F + (k-E)];
  }
  __syncthreads();
  int c = tid & 127, half = tid >> 7;
  float acc[8] = {0,0,0,0,0,0,0,0};
  for (int kk=0; kk<80; kk+=4){
    float w[4];
    #pragma unroll
    for (int u=0;u<4;u++) w[u] = Wenc[(kk+u)*H + c];
    #pragma unroll
    for (int i=0;i<8;i++){
      const float4 av = *reinterpret_cast<const float4*>(&As[half*8+i][kk]);
      acc[i] += av.x*w[0] + av.y*w[1] + av.z*w[2] + av.w*w[3];
    }
  }
  float bb = benc[c];
  #pragma unroll
  for (int i=0;i<8;i++){
    int m = m0 + half*8 + i;
    nebf[m*H + c] = f2bf(acc[i] + bb);
  }
}

// Fused GNN layer: per 64-node tile (+8 halo).
__global__ __launch_bounds__(256) void k_layer(const short* __restrict__ hin, const short* __restrict__ nebf,
    const int* __restrict__ adj, const short* __restrict__ Wgt, const float* __restrict__ bg,
    const float* __restrict__ ag, const short* __restrict__ Wt, const float* __restrict__ bgru,
    short* __restrict__ hout){
  __shared__ short Hs[80][136];
  __shared__ short Ts[80][136];
  __shared__ short Xs[64][136];
  __shared__ float Lp[4][80];
  __shared__ float Ls[80];
  int tid = threadIdx.x;
  int blk = blockIdx.x;
  int b = blk >> 4;
  int n0 = (blk & 15) << 6;
  for (int idx=tid; idx<80*16; idx+=256){
    int r = idx >> 4, c8 = idx & 15;
    int g = (b << 10) + ((n0 - 8 + r) & 1023);
    *reinterpret_cast<bf16x8*>(&Hs[r][c8*8]) =
        *reinterpret_cast<const bf16x8*>(&hin[(long)g*128 + c8*8]);
  }
  __syncthreads();
  int w = tid >> 6, lane = tid & 63;
  int l15 = lane & 15, quad = lane >> 4;
  // ---- phase 1: t + logits for 80 rows ----
  {
    f32x4 acc[5][2];
    #pragma unroll
    for (int mt=0;mt<5;mt++)
      #pragma unroll
      for (int u=0;u<2;u++) acc[mt][u] = (f32x4){0.f,0.f,0.f,0.f};
    #pragma unroll
    for (int kc=0;kc<4;kc++){
      int k0 = kc*32;
      bf16x8 a[5];
      #pragma unroll
      for (int mt=0;mt<5;mt++)
        a[mt] = *reinterpret_cast<const bf16x8*>(&Hs[16*mt + l15][k0 + quad*8]);
      #pragma unroll
      for (int u=0;u<2;u++){
        bf16x8 bfr = *reinterpret_cast<const bf16x8*>(&Wgt[(32*w + 16*u + l15)*128 + k0 + quad*8]);
        #pragma unroll
        for (int mt=0;mt<5;mt++)
          acc[mt][u] = __builtin_amdgcn_mfma_f32_16x16x32_bf16(a[mt], bfr, acc[mt][u], 0,0,0);
      }
    }
    float lp[5][4];
    #pragma unroll
    for (int mt=0;mt<5;mt++)
      #pragma unroll
      for (int reg=0;reg<4;reg++) lp[mt][reg] = 0.f;
    #pragma unroll
    for (int u=0;u<2;u++){
      int c = 32*w + 16*u + l15;
      float bgc = bg[c], agc = ag[c];
      #pragma unroll
      for (int mt=0;mt<5;mt++){
        #pragma unroll
        for (int reg=0;reg<4;reg++){
          float t = ftanh(acc[mt][u][reg] + bgc);
          Ts[16*mt + quad*4 + reg][c] = f2bf(t);
          lp[mt][reg] += t * agc;
        }
      }
    }
    #pragma unroll
    for (int mt=0;mt<5;mt++)
      #pragma unroll
      for (int reg=0;reg<4;reg++){
        lp[mt][reg] += __shfl_xor(lp[mt][reg], 1);
        lp[mt][reg] += __shfl_xor(lp[mt][reg], 2);
        lp[mt][reg] += __shfl_xor(lp[mt][reg], 4);
        lp[mt][reg] += __shfl_xor(lp[mt][reg], 8);
      }
    if (l15 == 0){
      #pragma unroll
      for (int mt=0;mt<5;mt++)
        #pragma unroll
        for (int reg=0;reg<4;reg++)
          Lp[w][16*mt + quad*4 + reg] = lp[mt][reg];
    }
  }
  __syncthreads();
  if (tid < 80) Ls[tid] = Lp[0][tid]+Lp[1][tid]+Lp[2][tid]+Lp[3][tid];
  __syncthreads();
  // ---- phase 2: msg + x for 64 owned nodes ----
  {
    int vl = tid >> 2, seg = tid & 3;
    int vg = (b<<10) + n0 + vl;
    int li[16]; float at[16];
    float m = -1e30f;
    #pragma unroll
    for (int d=0; d<16; d++){
      int a = adj[vg*16 + d];
      li[d] = (a - n0 + 8) & 1023;
      m = fmaxf(m, Ls[li[d]]);
    }
    float s = 0.f;
    #pragma unroll
    for (int d=0; d<16; d++){ at[d] = __expf(Ls[li[d]] - m); s += at[d]; }
    float inv = frcp(s);
    #pragma unroll
    for (int d=0; d<16; d++) at[d] *= inv;
    #pragma unroll
    for (int c8=0; c8<4; c8++){
      int c = seg*32 + c8*8;
      float acc8[8] = {0,0,0,0,0,0,0,0};
      #pragma unroll 4
      for (int d=0; d<16; d++){
        bf16x8 tv = *reinterpret_cast<const bf16x8*>(&Ts[li[d]][c]);
        float a = at[d];
        #pragma unroll
        for (int q=0;q<8;q++) acc8[q] += a * bf2f(tv[q]);
      }
      bf16x8 nv = *reinterpret_cast<const bf16x8*>(&nebf[(long)vg*128 + c]);
      bf16x8 xv;
      #pragma unroll
      for (int q=0;q<8;q++) xv[q] = f2bf(ftanh(acc8[q] + bf2f(nv[q])));
      *reinterpret_cast<bf16x8*>(&Xs[vl][c]) = xv;
    }
  }
  __syncthreads();
  // ---- phase 3: GRU for 64 owned rows ----
  f32x4 acc[4][4][2];
  #pragma unroll
  for (int mt=0;mt<4;mt++)
    #pragma unroll
    for (int g=0;g<4;g++)
      #pragma unroll
      for (int u=0;u<2;u++) acc[mt][g][u] = (f32x4){0.f,0.f,0.f,0.f};
  for (int k8=0;k8<8;k8++){
    int k0 = k8*32;
    int gg = (k8 < 4) ? 2 : 3;
    bf16x8 a[4];
    #pragma unroll
    for (int mt=0;mt<4;mt++){
      if (k8 < 4) a[mt] = *reinterpret_cast<const bf16x8*>(&Xs[16*mt + l15][k0 + quad*8]);
      else        a[mt] = *reinterpret_cast<const bf16x8*>(&Hs[16*mt + l15 + 8][k0 - 128 + quad*8]);
    }
    bf16x8 bz[2], br[2], bc[2];
    #pragma unroll
    for (int u=0;u<2;u++){
      int ncol = 32*w + 16*u + l15;
      int koff = k0 + quad*8;
      bz[u] = *reinterpret_cast<const bf16x8*>(&Wt[(ncol      )*256 + koff]);
      br[u] = *reinterpret_cast<const bf16x8*>(&Wt[(ncol + 128)*256 + koff]);
      bc[u] = *reinterpret_cast<const bf16x8*>(&Wt[(ncol + gg*128)*256 + koff]);
    }
    #pragma unroll
    for (int mt=0;mt<4;mt++){
      #pragma unroll
      for (int u=0;u<2;u++){
        acc[mt][0][u]  = __builtin_amdgcn_mfma_f32_16x16x32_bf16(a[mt], bz[u], acc[mt][0][u], 0,0,0);
        acc[mt][1][u]  = __builtin_amdgcn_mfma_f32_16x16x32_bf16(a[mt], br[u], acc[mt][1][u], 0,0,0);
        acc[mt][gg][u] = __builtin_amdgcn_mfma_f32_16x16x32_bf16(a[mt], bc[u], acc[mt][gg][u], 0,0,0);
      }
    }
  }
  __syncthreads();
  #pragma unroll
  for (int u=0;u<2;u++){
    int j = 32*w + 16*u + l15;
    float bjz = bgru[j], bjr = bgru[128 + j], bjc = bgru[256 + j];
    #pragma unroll
    for (int mt=0;mt<4;mt++){
      #pragma unroll
      for (int reg=0;reg<4;reg++){
        int rl = 16*mt + quad*4 + reg;
        float z = fsig(acc[mt][0][u][reg] + bjz);
        float r = fsig(acc[mt][1][u][reg] + bjr);
        float cand = ftanh(acc[mt][2][u][reg] + bjc + r*acc[mt][3][u][reg]);
        float ho = bf2f(Hs[rl + 8][j]);
        Xs[rl][j] = f2bf(z*ho + (1.f - z)*cand);
      }
    }
  }
  __syncthreads();
  for (int idx=tid; idx<64*16; idx+=256){
    int r = idx >> 4, c8 = idx & 15;
    *reinterpret_cast<bf16x8*>(&hout[(long)((b<<10) + n0 + r)*128 + c8*8]) =
        *reinterpret_cast<const bf16x8*>(&Xs[r][c8*8]);
  }
}

// Fully fused decoder + dest-attn + sparsemax + dual-vars per 64-node tile.
__global__ __launch_bounds__(256) void k_decdas(const short* __restrict__ hn, const int* __restrict__ adj,
    const int* __restrict__ invadj, const short* __restrict__ Wpq, const float* __restrict__ b1,
    const float* __restrict__ W2, const float* __restrict__ b2_,
    const short* __restrict__ Wu1t, const float* __restrict__ bu1, const float* __restrict__ Wu2,
    const float* __restrict__ bu2_, float* __restrict__ norm_, float* __restrict__ dv){
  __shared__ short Hs[112][136];     // later overlaid with nws[96][17] fp32
  __shared__ short PQb[112][132];    // later overlaid with datt[80][17] fp32
  __shared__ short NSs[64][136];     // node_states bf16
  __shared__ int adjL[64][16];       // halo-relative adj (+24 offset)
  __shared__ float dvp[64][4];
  __shared__ float b1s[64], w2s[64], bu1s[64], wu2s[64];
  int tid = threadIdx.x;
  int blk = blockIdx.x;
  int b = blk >> 4;
  int n0 = (blk & 15) << 6;
  if (tid < 64){ b1s[tid] = b1[tid]; w2s[tid] = W2[tid]; bu1s[tid] = bu1[tid]; wu2s[tid] = Wu2[tid]; }
  for (int idx=tid; idx<112*16; idx+=256){
    int r = idx >> 4, c8 = idx & 15;
    int g = (b << 10) + ((n0 - 24 + r) & 1023);
    *reinterpret_cast<bf16x8*>(&Hs[r][c8*8]) =
        *reinterpret_cast<const bf16x8*>(&hn[(long)g*128 + c8*8]);
  }
  #pragma unroll
  for (int e=0;e<4;e++){
    int idx = e*256 + tid;
    int r = idx >> 4, d = idx & 15;
    int a = adj[((b<<10) + n0 + r)*16 + d];
    adjL[r][d] = (a - n0 + 24) & 1023;   // in [16,96)
  }
  __syncthreads();
  int w = tid >> 6, lane = tid & 63;
  int l15 = lane & 15, quad = lane >> 4;
  // ---- PQ GEMM: 7 m-tiles x 128 cols ----
  {
    f32x4 acc[7][2];
    #pragma unroll
    for (int mt=0;mt<7;mt++)
      #pragma unroll
      for (int u=0;u<2;u++) acc[mt][u] = (f32x4){0.f,0.f,0.f,0.f};
    #pragma unroll
    for (int kc=0;kc<4;kc++){
      int k0 = kc*32;
      bf16x8 a[7];
      #pragma unroll
      for (int mt=0;mt<7;mt++)
        a[mt] = *reinterpret_cast<const bf16x8*>(&Hs[16*mt + l15][k0 + quad*8]);
      #pragma unroll
      for (int u=0;u<2;u++){
        bf16x8 bfr = *reinterpret_cast<const bf16x8*>(&Wpq[(32*w + 16*u + l15)*128 + k0 + quad*8]);
        #pragma unroll
        for (int mt=0;mt<7;mt++)
          acc[mt][u] = __builtin_amdgcn_mfma_f32_16x16x32_bf16(a[mt], bfr, acc[mt][u], 0,0,0);
      }
    }
    #pragma unroll
    for (int u=0;u<2;u++){
      int c = 32*w + 16*u + l15;
      #pragma unroll
      for (int mt=0;mt<7;mt++)
        #pragma unroll
        for (int reg=0;reg<4;reg++)
          PQb[16*mt + quad*4 + reg][c] = f2bf(acc[mt][u][reg]);
    }
  }
  // ---- node_states gather: ns[r] = sum_d Hs[adjL[r][d]]  (64 rows) ----
  #pragma unroll
  for (int e=0;e<4;e++){
    int idx = e*256 + tid;
    int r = idx >> 4, c8 = idx & 15;
    float acc8[8] = {0,0,0,0,0,0,0,0};
    #pragma unroll 4
    for (int d=0; d<16; d++){
      bf16x8 hv = *reinterpret_cast<const bf16x8*>(&Hs[adjL[r][d]][c8*8]);
      #pragma unroll
      for (int q=0;q<8;q++) acc8[q] += bf2f(hv[q]);
    }
    bf16x8 sv;
    #pragma unroll
    for (int q=0;q<8;q++) sv[q] = f2bf(acc8[q]);
    *reinterpret_cast<bf16x8*>(&NSs[r][c8*8]) = sv;
  }
  __syncthreads();
  // ---- dual MLP MFMA: ns(64x128) @ Wu1t -> 64 cols; tanh*W2 reduce -> dvp ----
  {
    f32x4 acc[4];
    #pragma unroll
    for (int mt=0;mt<4;mt++) acc[mt] = (f32x4){0.f,0.f,0.f,0.f};
    #pragma unroll
    for (int kc=0;kc<4;kc++){
      int k0 = kc*32;
      bf16x8 bfr = *reinterpret_cast<const bf16x8*>(&Wu1t[(16*w + l15)*128 + k0 + quad*8]);
      #pragma unroll
      for (int mt=0;mt<4;mt++){
        bf16x8 a = *reinterpret_cast<const bf16x8*>(&NSs[16*mt + l15][k0 + quad*8]);
        acc[mt] = __builtin_amdgcn_mfma_f32_16x16x32_bf16(a, bfr, acc[mt], 0,0,0);
      }
    }
    int n = 16*w + l15;
    float bn = bu1s[n], wn = wu2s[n];
    #pragma unroll
    for (int mt=0;mt<4;mt++){
      #pragma unroll
      for (int reg=0;reg<4;reg++){
        float p = ftanh(acc[mt][reg] + bn) * wn;
        p += __shfl_xor(p, 1);
        p += __shfl_xor(p, 2);
        p += __shfl_xor(p, 4);
        p += __shfl_xor(p, 8);
        if (l15 == 0) dvp[16*mt + quad*4 + reg][w] = p;
      }
    }
  }
  // ---- nw for 96 rows x 16 d -> overlay on Hs ----
  // (NSs phase already read Hs; PQb complete after the earlier sync chain)
  __syncthreads();
  float* nws = reinterpret_cast<float*>(&Hs[0][0]);   // [96][17]
  float b2v = b2_[0];
  for (int e = tid; e < 96*16; e += 256){
    int rr = e >> 4, d = e & 15;
    int wnode = (n0 + rr - 16) & 1023;
    int wg = (b<<10) + wnode;
    int a = adj[wg*16 + d];
    int al = (a - n0 + 24) & 1023;      // PQ row of neighbor
    int wl = rr + 8;                    // PQ row of w
    float p = 0.f;
    #pragma unroll 8
    for (int c=0;c<64;c++)
      p += ftanh(bf2f(PQb[al][c]) + bf2f(PQb[wl][64 + c]) + b1s[c]) * w2s[c];
    nws[rr*17 + d] = p + b2v;
  }
  __syncthreads();
  // ---- dv finalize + dest softmax (disjoint LDS) ----
  if (tid < 64){
    float val = dvp[tid][0]+dvp[tid][1]+dvp[tid][2]+dvp[tid][3];
    dv[(b<<10) + n0 + tid] = fmaxf(val + bu2_[0], 0.f);
  }
  float* datt = reinterpret_cast<float*>(&PQb[0][0]); // [80][17]
  if (tid < 80){
    int wnode = (n0 + tid - 8) & 1023;
    int wg = (b<<10) + wnode;
    float vals[16];
    float m = -1e30f;
    #pragma unroll
    for (int d=0; d<16; d++){
      int iv = invadj[wg*16 + d];
      int il = (iv - n0 + 16) & 1023;   // nw row
      vals[d] = nws[il*17 + d];
      m = fmaxf(m, vals[d]);
    }
    float s = 0.f;
    #pragma unroll
    for (int d=0; d<16; d++){ vals[d] = __expf(vals[d]-m); s += vals[d]; }
    float inv = frcp(s);
    #pragma unroll
    for (int d=0; d<16; d++) datt[tid*17 + d] = vals[d]*inv;
  }
  __syncthreads();
  // ---- sparsemax for 64 owned nodes ----
  if (tid < 64){
    int vg = (b<<10) + n0 + tid;
    float z[16], s[16];
    #pragma unroll
    for (int d=0; d<16; d++){
      int al = adjL[tid][d] - 16;       // datt row (+8 offset frame)
      z[d] = datt[al*17 + d];
      s[d] = z[d];
    }
    #pragma unroll
    for (int k2 = 2; k2 <= 16; k2 <<= 1){
      #pragma unroll
      for (int jj = k2 >> 1; jj > 0; jj >>= 1){
        #pragma unroll
        for (int i = 0; i < 16; i++){
          int l = i ^ jj;
          if (l > i){
            bool up = ((i & k2) == 0);
            float a = s[i], bb = s[l];
            bool sw = up ? (a > bb) : (a < bb);
            if (sw){ s[i]=bb; s[l]=a; }
          }
        }
      }
    }
    float cs = 0.f, zcs = 0.f; int kz = 1;
    #pragma unroll
    for (int j=0;j<16;j++){
      float zj = s[15-j];
      cs += zj;
      if (1.f + (float)(j+1)*zj > cs){ kz = j+1; zcs = cs; }
    }
    float tau = (zcs - 1.f)/(float)kz;
    #pragma unroll
    for (int d=0; d<16; d++) norm_[(long)vg*16 + d] = fmaxf(z[d]-tau, 0.f);
  }
}

// Fused flow solver + dual cost + dual demand + final output. One block per batch.
__global__ __launch_bounds__(1024) void k_flowfin(const float* __restrict__ norm_,
    const float* __restrict__ dem, const int* __restrict__ invadj, const float* __restrict__ dv,
    float* __restrict__ out){
  __shared__ float nrmS[V*17];       // padded x17: conflict-free gather
  __shared__ float sbuf[2][V];
  __shared__ float r1[16], r2[16], r3[16];
  int b = blockIdx.x, v = threadIdx.x;
  int gv = (b<<10) + v;
  // stage this batch's norm rows into LDS
  {
    const float4* src = reinterpret_cast<const float4*>(&norm_[(long)gv*16]);
    #pragma unroll
    for (int q4=0; q4<4; q4++){
      float4 x = src[q4];
      nrmS[v*17 + q4*4+0] = x.x; nrmS[v*17 + q4*4+1] = x.y;
      nrmS[v*17 + q4*4+2] = x.z; nrmS[v*17 + q4*4+3] = x.w;
    }
  }
  int iv[16];
  #pragma unroll
  for (int d4=0; d4<4; d4++){
    int4 i4 = reinterpret_cast<const int4*>(&invadj[(long)gv*16])[d4];
    iv[d4*4+0]=i4.x; iv[d4*4+1]=i4.y; iv[d4*4+2]=i4.z; iv[d4*4+3]=i4.w;
  }
  float dm = dem[gv];
  sbuf[0][v] = 0.f;
  __syncthreads();
  float nrg[16]; float nr2 = 0.f;
  #pragma unroll
  for (int d=0; d<16; d++){
    nrg[d] = nrmS[iv[d]*17 + d];
    float nv = nrmS[v*17 + d];
    nr2 += nv*nv;
  }
  int p = 0;
  float s = 0.f;
  for (int it=0; it<10; it++){
    float inflow = 0.f;
    #pragma unroll
    for (int d=0; d<16; d++) inflow += nrg[d]*sbuf[p][iv[d]];
    s = fmaxf(inflow - dm, 0.f);
    sbuf[1-p][v] = s;
    p ^= 1;
    __syncthreads();
  }
  float partF = nr2 * s * s;
  float dvv = dv[gv];
  float f = 0.f, vel = 0.f;
  #pragma unroll
  for (int it=0; it<10; it++){
    float g = 2.f*f + dvv;
    vel = 0.9f*vel - 0.01f*g;
    f = fmaxf(f + vel, 0.f);
  }
  float partD = f*f + dvv*f;
  float partDD = dvv * dm;
  #pragma unroll
  for (int off=32; off>0; off>>=1){
    partF  += __shfl_down(partF, off);
    partD  += __shfl_down(partD, off);
    partDD += __shfl_down(partDD, off);
  }
  if ((v & 63) == 0){ r1[v>>6] = partF; r2[v>>6] = partD; r3[v>>6] = partDD; }
  __syncthreads();
  if (v == 0){
    float sf = 0.f, sd = 0.f, sdd = 0.f;
    #pragma unroll
    for (int i=0;i<16;i++){ sf += r1[i]; sd += r2[i]; sdd += r3[i]; }
    out[b] = sf - (16.f*sd - sdd);
  }
}

extern "C" void kernel_launch(void* const* d_in, const int* in_sizes, int n_in,
                              void* d_out, int out_size, void* d_ws, size_t ws_size,
                              hipStream_t stream){
  (void)in_sizes; (void)n_in; (void)out_size; (void)ws_size;
  const float* demands = (const float*)d_in[0];
  const float* nf      = (const float*)d_in[1];
  const float* emb     = (const float*)d_in[4];
  const float* Wenc    = (const float*)d_in[5];
  const float* benc    = (const float*)d_in[6];
  const float* Wgat    = (const float*)d_in[7];
  const float* bgat    = (const float*)d_in[8];
  const float* agat    = (const float*)d_in[9];
  const float* Wgx     = (const float*)d_in[10];
  const float* Wgh     = (const float*)d_in[11];
  const float* bgru    = (const float*)d_in[12];
  const float* Wd1     = (const float*)d_in[13];
  const float* bd1     = (const float*)d_in[14];
  const float* Wd2     = (const float*)d_in[15];
  const float* bd2     = (const float*)d_in[16];
  const float* Wu1     = (const float*)d_in[17];
  const float* bu1     = (const float*)d_in[18];
  const float* Wu2     = (const float*)d_in[19];
  const float* bu2     = (const float*)d_in[20];
  const int* adj       = (const int*)d_in[21];
  const int* invadj    = (const int*)d_in[22];

  float* ws    = (float*)d_ws;
  short* nebf  = (short*)(ws + OFF_NEBF);
  short* hnA   = (short*)(ws + OFF_HNA);
  short* hnB   = (short*)(ws + OFF_HNB);
  float* nrm   = ws + OFF_NORM;
  float* dv    = ws + OFF_DV;
  short* wt    = (short*)(ws + OFF_WT);
  short* wtg   = (short*)(ws + OFF_WTG);
  short* wpq   = (short*)(ws + OFF_WPQ);
  short* wu1t  = (short*)(ws + OFF_WU1T);

  k_pre<<<1664, 256, 0, stream>>>(Wgx, Wgh, Wgat, Wd1, Wu1, emb, nf, Wenc, benc,
                                  wt, wtg, wpq, wu1t, nebf);
  k_layer<<<BV/64, 256, 0, stream>>>(nebf, nebf, adj, wtg, bgat, agat, wt, bgru, hnA);
  k_layer<<<BV/64, 256, 0, stream>>>(hnA, nebf, adj, wtg, bgat, agat, wt, bgru, hnB);
  k_decdas<<<BV/64, 256, 0, stream>>>(hnB, adj, invadj, wpq, bd1, Wd2, bd2,
                                      wu1t, bu1, Wu2, bu2, nrm, dv);
  k_flowfin<<<B, 1024, 0, stream>>>(nrm, demands, invadj, dv, (float*)d_out);
}

// Round 13
// 201.880 us; speedup vs baseline: 4.8698x; 1.0190x over previous
//
#include <hip/hip_runtime.h>
#include <hip/hip_bf16.h>

#define B 16
#define V 1024
#define D 16
#define E 64
#define F 16
#define H 128
#define HD 64
#define BV (B*V)      // 16384
#define BVD (B*V*D)   // 262144

// ---- workspace layout (float offsets) ----
#define OFF_HNB      0                         // hnode layer2 bf16 (BV*H shorts)
#define OFF_NORM     (OFF_HNB + BV*H/2)        // sparsemax output fp32 (BVD)
#define OFF_DV       (OFF_NORM + BVD)          // dual vars (BV)
#define OFF_WT       (OFF_DV + BV)             // 512x256 bf16 GRU weights
#define OFF_WTG      (OFF_WT + 65536)          // 128x128 bf16 GAT weights
#define OFF_WPQ      (OFF_WTG + 8192)          // 128x128 bf16 dec [P|Q] weights
#define OFF_WU1T     (OFF_WPQ + 8192)          // 64x128 bf16 dual W1^T
#define OFF_WENCT    (OFF_WU1T + 4096)         // 128x96 bf16 enc W^T (K padded 80->96)

typedef __attribute__((ext_vector_type(8))) short bf16x8;
typedef __attribute__((ext_vector_type(4))) float f32x4;

__device__ __forceinline__ short f2bf(float f){
  __hip_bfloat16 b = __float2bfloat16(f);
  return *reinterpret_cast<short*>(&b);
}
__device__ __forceinline__ float bf2f(short s){
  __hip_bfloat16 b; *reinterpret_cast<short*>(&b) = s;
  return __bfloat162float(b);
}
__device__ __forceinline__ float frcp(float x){ return __builtin_amdgcn_rcpf(x); }
__device__ __forceinline__ float fsig(float x){ return frcp(1.f + __expf(-x)); }
__device__ __forceinline__ float ftanh(float x){
  float e = __expf(-2.f*fabsf(x));
  float r = (1.f - e)*frcp(1.f + e);
  return copysignf(r, x);
}

// ---- weight packs only ----
// [0,512) GRU | [512,576) GAT | [576,608) dec P/Q | [608,640) dual W1^T | [640,704) enc W^T
__global__ __launch_bounds__(256) void k_pre(const float* __restrict__ Wx, const float* __restrict__ Wh,
    const float* __restrict__ Wg, const float* __restrict__ W1, const float* __restrict__ Wu1,
    const float* __restrict__ Wenc,
    short* __restrict__ Wt, short* __restrict__ Wgt, short* __restrict__ Wpq,
    short* __restrict__ Wu1t, short* __restrict__ Wenct){
  int bid = blockIdx.x, tid = threadIdx.x;
  if (bid < 512){
    int n = bid, k = tid;
    int g = n >> 7, j = n & 127;
    float v;
    if (g == 0)      v = (k < 128) ? Wx[k*384 + j]       : Wh[(k-128)*384 + j];
    else if (g == 1) v = (k < 128) ? Wx[k*384 + 128 + j] : Wh[(k-128)*384 + 128 + j];
    else if (g == 2) v = (k < 128) ? Wx[k*384 + 256 + j] : 0.f;
    else             v = (k < 128) ? 0.f                 : Wh[(k-128)*384 + 256 + j];
    Wt[n*256 + k] = f2bf(v);
    return;
  }
  if (bid < 576){
    int idx = (bid-512)*256 + tid;
    int n = idx >> 7, k = idx & 127;
    Wgt[n*128 + k] = f2bf(Wg[k*128 + n]);
    return;
  }
  if (bid < 608){
    int idx = (bid-576)*256 + tid;       // n<64, k<128
    int n = idx >> 7, k = idx & 127;
    float wb = W1[(k+128)*HD + n];
    float wa = W1[k*HD + n];
    Wpq[n*128 + k]      = f2bf(wa + wb);   // P weights
    Wpq[(64+n)*128 + k] = f2bf(wb);        // Q weights
    return;
  }
  if (bid < 640){
    int idx = (bid-608)*256 + tid;       // n<64, k<128
    int n = idx >> 7, k = idx & 127;
    Wu1t[n*128 + k] = f2bf(Wu1[k*HD + n]);
    return;
  }
  // enc W^T: n<128, k<96 (zero-pad k>=80)
  {
    int nn = (bid-640)*2 + (tid >> 7);
    int kk = tid & 127;
    if (kk < 96) Wenct[nn*96 + kk] = f2bf(kk < 80 ? Wenc[kk*128 + nn] : 0.f);
  }
}

// MEGA: per 64-node tile (+16 halo): emb-norm + encoder + GAT1 + GRU1 + GAT2 + GRU2 -> hnB
__global__ __launch_bounds__(256) void k_mega(const float* __restrict__ emb, const float* __restrict__ nf,
    const short* __restrict__ Wenct, const float* __restrict__ benc, const int* __restrict__ adj,
    const short* __restrict__ Wgt, const float* __restrict__ bg, const float* __restrict__ ag,
    const short* __restrict__ Wt, const float* __restrict__ bgru, short* __restrict__ hout){
  __shared__ short NE[96][136];    // node_enc, frame rows (n0-16..n0+80)
  __shared__ short T[96][136];     // t (layer1: 96 rows; layer2: 80 rows)
  __shared__ short H1[80][136];    // layer-1 h (frame rows 8..88)
  __shared__ short X[80][136];     // x (layer1: 80 rows; layer2/h2: 64 rows)
  __shared__ float Lp[4][96];
  __shared__ float Ls[96];
  __shared__ float nrmv[96];
  short (*As)[104] = reinterpret_cast<short(*)[104]>(&H1[0][0]);  // enc staging overlay (19968B<=21760B)

  int tid = threadIdx.x;
  int blk = blockIdx.x;
  int b = blk >> 4;
  int n0 = (blk & 15) << 6;
  int w = tid >> 6, lane = tid & 63;
  int l15 = lane & 15, quad = lane >> 4;

  // ---- E1: emb norms for 96 frame rows ----
  if (tid < 96){
    int v = (n0 - 16 + tid) & 1023;
    const float4* e4 = reinterpret_cast<const float4*>(&emb[v*E]);
    float ss = 0.f;
    #pragma unroll
    for (int q=0;q<16;q++){ float4 x = e4[q]; ss += x.x*x.x + x.y*x.y + x.z*x.z + x.w*x.w; }
    nrmv[tid] = frcp(fmaxf(sqrtf(ss), 1.f));
  }
  __syncthreads();
  // ---- E2: stage As[96][96] bf16 ----
  for (int e=tid; e<96*16; e+=256){
    int r = e >> 4, q = e & 15;
    int v = (n0 - 16 + r) & 1023;
    float4 x = reinterpret_cast<const float4*>(&emb[v*E])[q];
    float iv = nrmv[r];
    short4 s; s.x=f2bf(x.x*iv); s.y=f2bf(x.y*iv); s.z=f2bf(x.z*iv); s.w=f2bf(x.w*iv);
    *reinterpret_cast<short4*>(&As[r][q*4]) = s;
  }
  for (int e=tid; e<96*4; e+=256){
    int r = e >> 2, q = e & 3;
    int m = (b<<10) + ((n0 - 16 + r) & 1023);
    float4 x = reinterpret_cast<const float4*>(&nf[(long)m*F])[q];
    short4 s; s.x=f2bf(x.x); s.y=f2bf(x.y); s.z=f2bf(x.z); s.w=f2bf(x.w);
    *reinterpret_cast<short4*>(&As[r][64 + q*4]) = s;
    short4 z; z.x=0; z.y=0; z.z=0; z.w=0;
    *reinterpret_cast<short4*>(&As[r][80 + q*4]) = z;
  }
  __syncthreads();
  // ---- E3: encoder MFMA (96x128, K=96) -> NE ----
  {
    f32x4 acc[6][2];
    #pragma unroll
    for (int mt=0;mt<6;mt++)
      #pragma unroll
      for (int u=0;u<2;u++) acc[mt][u] = (f32x4){0.f,0.f,0.f,0.f};
    #pragma unroll
    for (int kc=0;kc<3;kc++){
      int k0 = kc*32;
      bf16x8 a[6];
      #pragma unroll
      for (int mt=0;mt<6;mt++)
        a[mt] = *reinterpret_cast<const bf16x8*>(&As[16*mt + l15][k0 + quad*8]);
      #pragma unroll
      for (int u=0;u<2;u++){
        bf16x8 bfr = *reinterpret_cast<const bf16x8*>(&Wenct[(32*w + 16*u + l15)*96 + k0 + quad*8]);
        #pragma unroll
        for (int mt=0;mt<6;mt++)
          acc[mt][u] = __builtin_amdgcn_mfma_f32_16x16x32_bf16(a[mt], bfr, acc[mt][u], 0,0,0);
      }
    }
    #pragma unroll
    for (int u=0;u<2;u++){
      int c = 32*w + 16*u + l15;
      float bb = benc[c];
      #pragma unroll
      for (int mt=0;mt<6;mt++)
        #pragma unroll
        for (int reg=0;reg<4;reg++)
          NE[16*mt + quad*4 + reg][c] = f2bf(acc[mt][u][reg] + bb);
    }
  }
  __syncthreads();
  // ---- P1: GAT-1 t + logits for 96 rows ----
  {
    f32x4 acc[6][2];
    #pragma unroll
    for (int mt=0;mt<6;mt++)
      #pragma unroll
      for (int u=0;u<2;u++) acc[mt][u] = (f32x4){0.f,0.f,0.f,0.f};
    #pragma unroll
    for (int kc=0;kc<4;kc++){
      int k0 = kc*32;
      bf16x8 a[6];
      #pragma unroll
      for (int mt=0;mt<6;mt++)
        a[mt] = *reinterpret_cast<const bf16x8*>(&NE[16*mt + l15][k0 + quad*8]);
      #pragma unroll
      for (int u=0;u<2;u++){
        bf16x8 bfr = *reinterpret_cast<const bf16x8*>(&Wgt[(32*w + 16*u + l15)*128 + k0 + quad*8]);
        #pragma unroll
        for (int mt=0;mt<6;mt++)
          acc[mt][u] = __builtin_amdgcn_mfma_f32_16x16x32_bf16(a[mt], bfr, acc[mt][u], 0,0,0);
      }
    }
    float lp[6][4];
    #pragma unroll
    for (int mt=0;mt<6;mt++)
      #pragma unroll
      for (int reg=0;reg<4;reg++) lp[mt][reg] = 0.f;
    #pragma unroll
    for (int u=0;u<2;u++){
      int c = 32*w + 16*u + l15;
      float bgc = bg[c], agc = ag[c];
      #pragma unroll
      for (int mt=0;mt<6;mt++){
        #pragma unroll
        for (int reg=0;reg<4;reg++){
          float t = ftanh(acc[mt][u][reg] + bgc);
          T[16*mt + quad*4 + reg][c] = f2bf(t);
          lp[mt][reg] += t * agc;
        }
      }
    }
    #pragma unroll
    for (int mt=0;mt<6;mt++)
      #pragma unroll
      for (int reg=0;reg<4;reg++){
        lp[mt][reg] += __shfl_xor(lp[mt][reg], 1);
        lp[mt][reg] += __shfl_xor(lp[mt][reg], 2);
        lp[mt][reg] += __shfl_xor(lp[mt][reg], 4);
        lp[mt][reg] += __shfl_xor(lp[mt][reg], 8);
      }
    if (l15 == 0){
      #pragma unroll
      for (int mt=0;mt<6;mt++)
        #pragma unroll
        for (int reg=0;reg<4;reg++)
          Lp[w][16*mt + quad*4 + reg] = lp[mt][reg];
    }
  }
  __syncthreads();
  if (tid < 96) Ls[tid] = Lp[0][tid]+Lp[1][tid]+Lp[2][tid]+Lp[3][tid];
  __syncthreads();
  // ---- P2: msg1 + x1 for 80 rows (frame 8..88) -> X[0..80) ----
  for (int e=tid; e<320; e+=256){
    int vl = e >> 2, seg = e & 3;
    int wg = (b<<10) + ((n0 - 8 + vl) & 1023);
    int li[16]; float at[16];
    float m = -1e30f;
    #pragma unroll
    for (int d=0; d<16; d++){
      int a = adj[wg*16 + d];
      li[d] = (a - n0 + 16) & 1023;          // in [0,96)
      m = fmaxf(m, Ls[li[d]]);
    }
    float s = 0.f;
    #pragma unroll
    for (int d=0; d<16; d++){ at[d] = __expf(Ls[li[d]] - m); s += at[d]; }
    float inv = frcp(s);
    #pragma unroll
    for (int d=0; d<16; d++) at[d] *= inv;
    #pragma unroll
    for (int c8=0; c8<4; c8++){
      int c = seg*32 + c8*8;
      float acc8[8] = {0,0,0,0,0,0,0,0};
      #pragma unroll 4
      for (int d=0; d<16; d++){
        bf16x8 tv = *reinterpret_cast<const bf16x8*>(&T[li[d]][c]);
        float a = at[d];
        #pragma unroll
        for (int q=0;q<8;q++) acc8[q] += a * bf2f(tv[q]);
      }
      bf16x8 nv = *reinterpret_cast<const bf16x8*>(&NE[vl + 8][c]);
      bf16x8 xv;
      #pragma unroll
      for (int q=0;q<8;q++) xv[q] = f2bf(ftanh(acc8[q] + bf2f(nv[q])));
      *reinterpret_cast<bf16x8*>(&X[vl][c]) = xv;
    }
  }
  __syncthreads();
  // ---- P3: GRU-1 for 80 rows: x=X, h=NE[+8] -> H1 ----
  {
    f32x4 acc[5][4][2];
    #pragma unroll
    for (int mt=0;mt<5;mt++)
      #pragma unroll
      for (int g=0;g<4;g++)
        #pragma unroll
        for (int u=0;u<2;u++) acc[mt][g][u] = (f32x4){0.f,0.f,0.f,0.f};
    for (int k8=0;k8<8;k8++){
      int k0 = k8*32;
      int gg = (k8 < 4) ? 2 : 3;
      bf16x8 a[5];
      #pragma unroll
      for (int mt=0;mt<5;mt++){
        if (k8 < 4) a[mt] = *reinterpret_cast<const bf16x8*>(&X[16*mt + l15][k0 + quad*8]);
        else        a[mt] = *reinterpret_cast<const bf16x8*>(&NE[16*mt + l15 + 8][k0 - 128 + quad*8]);
      }
      bf16x8 bz[2], br[2], bc[2];
      #pragma unroll
      for (int u=0;u<2;u++){
        int ncol = 32*w + 16*u + l15;
        int koff = k0 + quad*8;
        bz[u] = *reinterpret_cast<const bf16x8*>(&Wt[(ncol      )*256 + koff]);
        br[u] = *reinterpret_cast<const bf16x8*>(&Wt[(ncol + 128)*256 + koff]);
        bc[u] = *reinterpret_cast<const bf16x8*>(&Wt[(ncol + gg*128)*256 + koff]);
      }
      #pragma unroll
      for (int mt=0;mt<5;mt++){
        #pragma unroll
        for (int u=0;u<2;u++){
          acc[mt][0][u]  = __builtin_amdgcn_mfma_f32_16x16x32_bf16(a[mt], bz[u], acc[mt][0][u], 0,0,0);
          acc[mt][1][u]  = __builtin_amdgcn_mfma_f32_16x16x32_bf16(a[mt], br[u], acc[mt][1][u], 0,0,0);
          acc[mt][gg][u] = __builtin_amdgcn_mfma_f32_16x16x32_bf16(a[mt], bc[u], acc[mt][gg][u], 0,0,0);
        }
      }
    }
    // epilogue writes H1 (overlays dead As) — no race with concurrent MFMA reads of X/NE
    #pragma unroll
    for (int u=0;u<2;u++){
      int j = 32*w + 16*u + l15;
      float bjz = bgru[j], bjr = bgru[128 + j], bjc = bgru[256 + j];
      #pragma unroll
      for (int mt=0;mt<5;mt++){
        #pragma unroll
        for (int reg=0;reg<4;reg++){
          int rl = 16*mt + quad*4 + reg;
          float z = fsig(acc[mt][0][u][reg] + bjz);
          float r = fsig(acc[mt][1][u][reg] + bjr);
          float cand = ftanh(acc[mt][2][u][reg] + bjc + r*acc[mt][3][u][reg]);
          float ho = bf2f(NE[rl + 8][j]);
          H1[rl][j] = f2bf(z*ho + (1.f - z)*cand);
        }
      }
    }
  }
  __syncthreads();
  // ---- P4: GAT-2 t + logits for 80 rows (H1) ----
  {
    f32x4 acc[5][2];
    #pragma unroll
    for (int mt=0;mt<5;mt++)
      #pragma unroll
      for (int u=0;u<2;u++) acc[mt][u] = (f32x4){0.f,0.f,0.f,0.f};
    #pragma unroll
    for (int kc=0;kc<4;kc++){
      int k0 = kc*32;
      bf16x8 a[5];
      #pragma unroll
      for (int mt=0;mt<5;mt++)
        a[mt] = *reinterpret_cast<const bf16x8*>(&H1[16*mt + l15][k0 + quad*8]);
      #pragma unroll
      for (int u=0;u<2;u++){
        bf16x8 bfr = *reinterpret_cast<const bf16x8*>(&Wgt[(32*w + 16*u + l15)*128 + k0 + quad*8]);
        #pragma unroll
        for (int mt=0;mt<5;mt++)
          acc[mt][u] = __builtin_amdgcn_mfma_f32_16x16x32_bf16(a[mt], bfr, acc[mt][u], 0,0,0);
      }
    }
    float lp[5][4];
    #pragma unroll
    for (int mt=0;mt<5;mt++)
      #pragma unroll
      for (int reg=0;reg<4;reg++) lp[mt][reg] = 0.f;
    #pragma unroll
    for (int u=0;u<2;u++){
      int c = 32*w + 16*u + l15;
      float bgc = bg[c], agc = ag[c];
      #pragma unroll
      for (int mt=0;mt<5;mt++){
        #pragma unroll
        for (int reg=0;reg<4;reg++){
          float t = ftanh(acc[mt][u][reg] + bgc);
          T[16*mt + quad*4 + reg][c] = f2bf(t);
          lp[mt][reg] += t * agc;
        }
      }
    }
    #pragma unroll
    for (int mt=0;mt<5;mt++)
      #pragma unroll
      for (int reg=0;reg<4;reg++){
        lp[mt][reg] += __shfl_xor(lp[mt][reg], 1);
        lp[mt][reg] += __shfl_xor(lp[mt][reg], 2);
        lp[mt][reg] += __shfl_xor(lp[mt][reg], 4);
        lp[mt][reg] += __shfl_xor(lp[mt][reg], 8);
      }
    if (l15 == 0){
      #pragma unroll
      for (int mt=0;mt<5;mt++)
        #pragma unroll
        for (int reg=0;reg<4;reg++)
          Lp[w][16*mt + quad*4 + reg] = lp[mt][reg];
    }
  }
  __syncthreads();
  if (tid < 80) Ls[tid] = Lp[0][tid]+Lp[1][tid]+Lp[2][tid]+Lp[3][tid];
  __syncthreads();
  // ---- P5: msg2 + x2 for 64 owned -> X[0..64) ----
  {
    int vl = tid >> 2, seg = tid & 3;
    int vg = (b<<10) + n0 + vl;
    int li[16]; float at[16];
    float m = -1e30f;
    #pragma unroll
    for (int d=0; d<16; d++){
      int a = adj[vg*16 + d];
      li[d] = (a - n0 + 8) & 1023;           // in [0,80), H1/T frame
      m = fmaxf(m, Ls[li[d]]);
    }
    float s = 0.f;
    #pragma unroll
    for (int d=0; d<16; d++){ at[d] = __expf(Ls[li[d]] - m); s += at[d]; }
    float inv = frcp(s);
    #pragma unroll
    for (int d=0; d<16; d++) at[d] *= inv;
    #pragma unroll
    for (int c8=0; c8<4; c8++){
      int c = seg*32 + c8*8;
      float acc8[8] = {0,0,0,0,0,0,0,0};
      #pragma unroll 4
      for (int d=0; d<16; d++){
        bf16x8 tv = *reinterpret_cast<const bf16x8*>(&T[li[d]][c]);
        float a = at[d];
        #pragma unroll
        for (int q=0;q<8;q++) acc8[q] += a * bf2f(tv[q]);
      }
      bf16x8 nv = *reinterpret_cast<const bf16x8*>(&NE[vl + 16][c]);
      bf16x8 xv;
      #pragma unroll
      for (int q=0;q<8;q++) xv[q] = f2bf(ftanh(acc8[q] + bf2f(nv[q])));
      *reinterpret_cast<bf16x8*>(&X[vl][c]) = xv;
    }
  }
  __syncthreads();
  // ---- P6: GRU-2 for 64 owned: x=X, h=H1[+8] -> store hnB ----
  {
    f32x4 acc[4][4][2];
    #pragma unroll
    for (int mt=0;mt<4;mt++)
      #pragma unroll
      for (int g=0;g<4;g++)
        #pragma unroll
        for (int u=0;u<2;u++) acc[mt][g][u] = (f32x4){0.f,0.f,0.f,0.f};
    for (int k8=0;k8<8;k8++){
      int k0 = k8*32;
      int gg = (k8 < 4) ? 2 : 3;
      bf16x8 a[4];
      #pragma unroll
      for (int mt=0;mt<4;mt++){
        if (k8 < 4) a[mt] = *reinterpret_cast<const bf16x8*>(&X[16*mt + l15][k0 + quad*8]);
        else        a[mt] = *reinterpret_cast<const bf16x8*>(&H1[16*mt + l15 + 8][k0 - 128 + quad*8]);
      }
      bf16x8 bz[2], br[2], bc[2];
      #pragma unroll
      for (int u=0;u<2;u++){
        int ncol = 32*w + 16*u + l15;
        int koff = k0 + quad*8;
        bz[u] = *reinterpret_cast<const bf16x8*>(&Wt[(ncol      )*256 + koff]);
        br[u] = *reinterpret_cast<const bf16x8*>(&Wt[(ncol + 128)*256 + koff]);
        bc[u] = *reinterpret_cast<const bf16x8*>(&Wt[(ncol + gg*128)*256 + koff]);
      }
      #pragma unroll
      for (int mt=0;mt<4;mt++){
        #pragma unroll
        for (int u=0;u<2;u++){
          acc[mt][0][u]  = __builtin_amdgcn_mfma_f32_16x16x32_bf16(a[mt], bz[u], acc[mt][0][u], 0,0,0);
          acc[mt][1][u]  = __builtin_amdgcn_mfma_f32_16x16x32_bf16(a[mt], br[u], acc[mt][1][u], 0,0,0);
          acc[mt][gg][u] = __builtin_amdgcn_mfma_f32_16x16x32_bf16(a[mt], bc[u], acc[mt][gg][u], 0,0,0);
        }
      }
    }
    __syncthreads();   // X is MFMA input above and epilogue output below
    #pragma unroll
    for (int u=0;u<2;u++){
      int j = 32*w + 16*u + l15;
      float bjz = bgru[j], bjr = bgru[128 + j], bjc = bgru[256 + j];
      #pragma unroll
      for (int mt=0;mt<4;mt++){
        #pragma unroll
        for (int reg=0;reg<4;reg++){
          int rl = 16*mt + quad*4 + reg;
          float z = fsig(acc[mt][0][u][reg] + bjz);
          float r = fsig(acc[mt][1][u][reg] + bjr);
          float cand = ftanh(acc[mt][2][u][reg] + bjc + r*acc[mt][3][u][reg]);
          float ho = bf2f(H1[rl + 8][j]);
          X[rl][j] = f2bf(z*ho + (1.f - z)*cand);
        }
      }
    }
  }
  __syncthreads();
  for (int idx=tid; idx<64*16; idx+=256){
    int r = idx >> 4, c8 = idx & 15;
    *reinterpret_cast<bf16x8*>(&hout[(long)((b<<10) + n0 + r)*128 + c8*8]) =
        *reinterpret_cast<const bf16x8*>(&X[r][c8*8]);
  }
}

// Fully fused decoder + dest-attn + sparsemax + dual-vars per 64-node tile. (unchanged)
__global__ __launch_bounds__(256) void k_decdas(const short* __restrict__ hn, const int* __restrict__ adj,
    const int* __restrict__ invadj, const short* __restrict__ Wpq, const float* __restrict__ b1,
    const float* __restrict__ W2, const float* __restrict__ b2_,
    const short* __restrict__ Wu1t, const float* __restrict__ bu1, const float* __restrict__ Wu2,
    const float* __restrict__ bu2_, float* __restrict__ norm_, float* __restrict__ dv){
  __shared__ short Hs[112][136];
  __shared__ short PQb[112][132];
  __shared__ short NSs[64][136];
  __shared__ int adjL[64][16];
  __shared__ float dvp[64][4];
  __shared__ float b1s[64], w2s[64], bu1s[64], wu2s[64];
  int tid = threadIdx.x;
  int blk = blockIdx.x;
  int b = blk >> 4;
  int n0 = (blk & 15) << 6;
  if (tid < 64){ b1s[tid] = b1[tid]; w2s[tid] = W2[tid]; bu1s[tid] = bu1[tid]; wu2s[tid] = Wu2[tid]; }
  for (int idx=tid; idx<112*16; idx+=256){
    int r = idx >> 4, c8 = idx & 15;
    int g = (b << 10) + ((n0 - 24 + r) & 1023);
    *reinterpret_cast<bf16x8*>(&Hs[r][c8*8]) =
        *reinterpret_cast<const bf16x8*>(&hn[(long)g*128 + c8*8]);
  }
  #pragma unroll
  for (int e=0;e<4;e++){
    int idx = e*256 + tid;
    int r = idx >> 4, d = idx & 15;
    int a = adj[((b<<10) + n0 + r)*16 + d];
    adjL[r][d] = (a - n0 + 24) & 1023;
  }
  __syncthreads();
  int w = tid >> 6, lane = tid & 63;
  int l15 = lane & 15, quad = lane >> 4;
  {
    f32x4 acc[7][2];
    #pragma unroll
    for (int mt=0;mt<7;mt++)
      #pragma unroll
      for (int u=0;u<2;u++) acc[mt][u] = (f32x4){0.f,0.f,0.f,0.f};
    #pragma unroll
    for (int kc=0;kc<4;kc++){
      int k0 = kc*32;
      bf16x8 a[7];
      #pragma unroll
      for (int mt=0;mt<7;mt++)
        a[mt] = *reinterpret_cast<const bf16x8*>(&Hs[16*mt + l15][k0 + quad*8]);
      #pragma unroll
      for (int u=0;u<2;u++){
        bf16x8 bfr = *reinterpret_cast<const bf16x8*>(&Wpq[(32*w + 16*u + l15)*128 + k0 + quad*8]);
        #pragma unroll
        for (int mt=0;mt<7;mt++)
          acc[mt][u] = __builtin_amdgcn_mfma_f32_16x16x32_bf16(a[mt], bfr, acc[mt][u], 0,0,0);
      }
    }
    #pragma unroll
    for (int u=0;u<2;u++){
      int c = 32*w + 16*u + l15;
      #pragma unroll
      for (int mt=0;mt<7;mt++)
        #pragma unroll
        for (int reg=0;reg<4;reg++)
          PQb[16*mt + quad*4 + reg][c] = f2bf(acc[mt][u][reg]);
    }
  }
  #pragma unroll
  for (int e=0;e<4;e++){
    int idx = e*256 + tid;
    int r = idx >> 4, c8 = idx & 15;
    float acc8[8] = {0,0,0,0,0,0,0,0};
    #pragma unroll 4
    for (int d=0; d<16; d++){
      bf16x8 hv = *reinterpret_cast<const bf16x8*>(&Hs[adjL[r][d]][c8*8]);
      #pragma unroll
      for (int q=0;q<8;q++) acc8[q] += bf2f(hv[q]);
    }
    bf16x8 sv;
    #pragma unroll
    for (int q=0;q<8;q++) sv[q] = f2bf(acc8[q]);
    *reinterpret_cast<bf16x8*>(&NSs[r][c8*8]) = sv;
  }
  __syncthreads();
  {
    f32x4 acc[4];
    #pragma unroll
    for (int mt=0;mt<4;mt++) acc[mt] = (f32x4){0.f,0.f,0.f,0.f};
    #pragma unroll
    for (int kc=0;kc<4;kc++){
      int k0 = kc*32;
      bf16x8 bfr = *reinterpret_cast<const bf16x8*>(&Wu1t[(16*w + l15)*128 + k0 + quad*8]);
      #pragma unroll
      for (int mt=0;mt<4;mt++){
        bf16x8 a = *reinterpret_cast<const bf16x8*>(&NSs[16*mt + l15][k0 + quad*8]);
        acc[mt] = __builtin_amdgcn_mfma_f32_16x16x32_bf16(a, bfr, acc[mt], 0,0,0);
      }
    }
    int n = 16*w + l15;
    float bn = bu1s[n], wn = wu2s[n];
    #pragma unroll
    for (int mt=0;mt<4;mt++){
      #pragma unroll
      for (int reg=0;reg<4;reg++){
        float p = ftanh(acc[mt][reg] + bn) * wn;
        p += __shfl_xor(p, 1);
        p += __shfl_xor(p, 2);
        p += __shfl_xor(p, 4);
        p += __shfl_xor(p, 8);
        if (l15 == 0) dvp[16*mt + quad*4 + reg][w] = p;
      }
    }
  }
  __syncthreads();
  float* nws = reinterpret_cast<float*>(&Hs[0][0]);   // [96][17]
  float b2v = b2_[0];
  for (int e = tid; e < 96*16; e += 256){
    int rr = e >> 4, d = e & 15;
    int wnode = (n0 + rr - 16) & 1023;
    int wg = (b<<10) + wnode;
    int a = adj[wg*16 + d];
    int al = (a - n0 + 24) & 1023;
    int wl = rr + 8;
    float p = 0.f;
    #pragma unroll 8
    for (int c=0;c<64;c++)
      p += ftanh(bf2f(PQb[al][c]) + bf2f(PQb[wl][64 + c]) + b1s[c]) * w2s[c];
    nws[rr*17 + d] = p + b2v;
  }
  __syncthreads();
  if (tid < 64){
    float val = dvp[tid][0]+dvp[tid][1]+dvp[tid][2]+dvp[tid][3];
    dv[(b<<10) + n0 + tid] = fmaxf(val + bu2_[0], 0.f);
  }
  float* datt = reinterpret_cast<float*>(&PQb[0][0]); // [80][17]
  if (tid < 80){
    int wnode = (n0 + tid - 8) & 1023;
    int wg = (b<<10) + wnode;
    float vals[16];
    float m = -1e30f;
    #pragma unroll
    for (int d=0; d<16; d++){
      int iv = invadj[wg*16 + d];
      int il = (iv - n0 + 16) & 1023;
      vals[d] = nws[il*17 + d];
      m = fmaxf(m, vals[d]);
    }
    float s = 0.f;
    #pragma unroll
    for (int d=0; d<16; d++){ vals[d] = __expf(vals[d]-m); s += vals[d]; }
    float inv = frcp(s);
    #pragma unroll
    for (int d=0; d<16; d++) datt[tid*17 + d] = vals[d]*inv;
  }
  __syncthreads();
  if (tid < 64){
    int vg = (b<<10) + n0 + tid;
    float z[16], s[16];
    #pragma unroll
    for (int d=0; d<16; d++){
      int al = adjL[tid][d] - 16;
      z[d] = datt[al*17 + d];
      s[d] = z[d];
    }
    #pragma unroll
    for (int k2 = 2; k2 <= 16; k2 <<= 1){
      #pragma unroll
      for (int jj = k2 >> 1; jj > 0; jj >>= 1){
        #pragma unroll
        for (int i = 0; i < 16; i++){
          int l = i ^ jj;
          if (l > i){
            bool up = ((i & k2) == 0);
            float a = s[i], bb = s[l];
            bool sw = up ? (a > bb) : (a < bb);
            if (sw){ s[i]=bb; s[l]=a; }
          }
        }
      }
    }
    float cs = 0.f, zcs = 0.f; int kz = 1;
    #pragma unroll
    for (int j=0;j<16;j++){
      float zj = s[15-j];
      cs += zj;
      if (1.f + (float)(j+1)*zj > cs){ kz = j+1; zcs = cs; }
    }
    float tau = (zcs - 1.f)/(float)kz;
    #pragma unroll
    for (int d=0; d<16; d++) norm_[(long)vg*16 + d] = fmaxf(z[d]-tau, 0.f);
  }
}

// Fused flow solver + dual cost + dual demand + final output. (unchanged)
__global__ __launch_bounds__(1024) void k_flowfin(const float* __restrict__ norm_,
    const float* __restrict__ dem, const int* __restrict__ invadj, const float* __restrict__ dv,
    float* __restrict__ out){
  __shared__ float nrmS[V*17];
  __shared__ float sbuf[2][V];
  __shared__ float r1[16], r2[16], r3[16];
  int b = blockIdx.x, v = threadIdx.x;
  int gv = (b<<10) + v;
  {
    const float4* src = reinterpret_cast<const float4*>(&norm_[(long)gv*16]);
    #pragma unroll
    for (int q4=0; q4<4; q4++){
      float4 x = src[q4];
      nrmS[v*17 + q4*4+0] = x.x; nrmS[v*17 + q4*4+1] = x.y;
      nrmS[v*17 + q4*4+2] = x.z; nrmS[v*17 + q4*4+3] = x.w;
    }
  }
  int iv[16];
  #pragma unroll
  for (int d4=0; d4<4; d4++){
    int4 i4 = reinterpret_cast<const int4*>(&invadj[(long)gv*16])[d4];
    iv[d4*4+0]=i4.x; iv[d4*4+1]=i4.y; iv[d4*4+2]=i4.z; iv[d4*4+3]=i4.w;
  }
  float dm = dem[gv];
  sbuf[0][v] = 0.f;
  __syncthreads();
  float nrg[16]; float nr2 = 0.f;
  #pragma unroll
  for (int d=0; d<16; d++){
    nrg[d] = nrmS[iv[d]*17 + d];
    float nv = nrmS[v*17 + d];
    nr2 += nv*nv;
  }
  int p = 0;
  float s = 0.f;
  for (int it=0; it<10; it++){
    float inflow = 0.f;
    #pragma unroll
    for (int d=0; d<16; d++) inflow += nrg[d]*sbuf[p][iv[d]];
    s = fmaxf(inflow - dm, 0.f);
    sbuf[1-p][v] = s;
    p ^= 1;
    __syncthreads();
  }
  float partF = nr2 * s * s;
  float dvv = dv[gv];
  float f = 0.f, vel = 0.f;
  #pragma unroll
  for (int it=0; it<10; it++){
    float g = 2.f*f + dvv;
    vel = 0.9f*vel - 0.01f*g;
    f = fmaxf(f + vel, 0.f);
  }
  float partD = f*f + dvv*f;
  float partDD = dvv * dm;
  #pragma unroll
  for (int off=32; off>0; off>>=1){
    partF  += __shfl_down(partF, off);
    partD  += __shfl_down(partD, off);
    partDD += __shfl_down(partDD, off);
  }
  if ((v & 63) == 0){ r1[v>>6] = partF; r2[v>>6] = partD; r3[v>>6] = partDD; }
  __syncthreads();
  if (v == 0){
    float sf = 0.f, sd = 0.f, sdd = 0.f;
    #pragma unroll
    for (int i=0;i<16;i++){ sf += r1[i]; sd += r2[i]; sdd += r3[i]; }
    out[b] = sf - (16.f*sd - sdd);
  }
}

extern "C" void kernel_launch(void* const* d_in, const int* in_sizes, int n_in,
                              void* d_out, int out_size, void* d_ws, size_t ws_size,
                              hipStream_t stream){
  (void)in_sizes; (void)n_in; (void)out_size; (void)ws_size;
  const float* demands = (const float*)d_in[0];
  const float* nf      = (const float*)d_in[1];
  const float* emb     = (const float*)d_in[4];
  const float* Wenc    = (const float*)d_in[5];
  const float* benc    = (const float*)d_in[6];
  const float* Wgat    = (const float*)d_in[7];
  const float* bgat    = (const float*)d_in[8];
  const float* agat    = (const float*)d_in[9];
  const float* Wgx     = (const float*)d_in[10];
  const float* Wgh     = (const float*)d_in[11];
  const float* bgru    = (const float*)d_in[12];
  const float* Wd1     = (const float*)d_in[13];
  const float* bd1     = (const float*)d_in[14];
  const float* Wd2     = (const float*)d_in[15];
  const float* bd2     = (const float*)d_in[16];
  const float* Wu1     = (const float*)d_in[17];
  const float* bu1     = (const float*)d_in[18];
  const float* Wu2     = (const float*)d_in[19];
  const float* bu2     = (const float*)d_in[20];
  const int* adj       = (const int*)d_in[21];
  const int* invadj    = (const int*)d_in[22];

  float* ws    = (float*)d_ws;
  short* hnB   = (short*)(ws + OFF_HNB);
  float* nrm   = ws + OFF_NORM;
  float* dv    = ws + OFF_DV;
  short* wt    = (short*)(ws + OFF_WT);
  short* wtg   = (short*)(ws + OFF_WTG);
  short* wpq   = (short*)(ws + OFF_WPQ);
  short* wu1t  = (short*)(ws + OFF_WU1T);
  short* wenct = (short*)(ws + OFF_WENCT);

  k_pre<<<704, 256, 0, stream>>>(Wgx, Wgh, Wgat, Wd1, Wu1, Wenc, wt, wtg, wpq, wu1t, wenct);
  k_mega<<<BV/64, 256, 0, stream>>>(emb, nf, wenct, benc, adj, wtg, bgat, agat, wt, bgru, hnB);
  k_decdas<<<BV/64, 256, 0, stream>>>(hnB, adj, invadj, wpq, bd1, Wd2, bd2,
                                      wu1t, bu1, Wu2, bu2, nrm, dv);
  k_flowfin<<<B, 1024, 0, stream>>>(nrm, demands, invadj, dv, (float*)d_out);
}

// Round 14
// 184.476 us; speedup vs baseline: 5.3292x; 1.0943x over previous
//
#include <hip/hip_runtime.h>
#include <hip/hip_bf16.h>

#define B 16
#define V 1024
#define D 16
#define E 64
#define F 16
#define H 128
#define HD 64
#define BV (B*V)      // 16384
#define BVD (B*V*D)   // 262144

// ---- workspace layout (float offsets) ----
#define OFF_HNB      0                         // hnode layer2 bf16 (BV*H shorts)
#define OFF_NORM     (OFF_HNB + BV*H/2)        // sparsemax output fp32 (BVD)
#define OFF_DV       (OFF_NORM + BVD)          // dual vars (BV)
#define OFF_WT       (OFF_DV + BV)             // 512x256 bf16 GRU weights
#define OFF_WTG      (OFF_WT + 65536)          // 128x128 bf16 GAT weights
#define OFF_WPQ      (OFF_WTG + 8192)          // 128x128 bf16 dec [P|Q] weights
#define OFF_WU1T     (OFF_WPQ + 8192)          // 64x128 bf16 dual W1^T
#define OFF_WENCT    (OFF_WU1T + 4096)         // 128x96 bf16 enc W^T (K padded 80->96)

typedef __attribute__((ext_vector_type(8))) short bf16x8;
typedef __attribute__((ext_vector_type(4))) float f32x4;

__device__ __forceinline__ short f2bf(float f){
  __hip_bfloat16 b = __float2bfloat16(f);
  return *reinterpret_cast<short*>(&b);
}
__device__ __forceinline__ float bf2f(short s){
  __hip_bfloat16 b; *reinterpret_cast<short*>(&b) = s;
  return __bfloat162float(b);
}
__device__ __forceinline__ float frcp(float x){ return __builtin_amdgcn_rcpf(x); }
__device__ __forceinline__ float fsig(float x){ return frcp(1.f + __expf(-x)); }
__device__ __forceinline__ float ftanh(float x){
  float e = __expf(-2.f*fabsf(x));
  float r = (1.f - e)*frcp(1.f + e);
  return copysignf(r, x);
}

// ---- weight packs only ----
__global__ __launch_bounds__(256) void k_pre(const float* __restrict__ Wx, const float* __restrict__ Wh,
    const float* __restrict__ Wg, const float* __restrict__ W1, const float* __restrict__ Wu1,
    const float* __restrict__ Wenc,
    short* __restrict__ Wt, short* __restrict__ Wgt, short* __restrict__ Wpq,
    short* __restrict__ Wu1t, short* __restrict__ Wenct){
  int bid = blockIdx.x, tid = threadIdx.x;
  if (bid < 512){
    int n = bid, k = tid;
    int g = n >> 7, j = n & 127;
    float v;
    if (g == 0)      v = (k < 128) ? Wx[k*384 + j]       : Wh[(k-128)*384 + j];
    else if (g == 1) v = (k < 128) ? Wx[k*384 + 128 + j] : Wh[(k-128)*384 + 128 + j];
    else if (g == 2) v = (k < 128) ? Wx[k*384 + 256 + j] : 0.f;
    else             v = (k < 128) ? 0.f                 : Wh[(k-128)*384 + 256 + j];
    Wt[n*256 + k] = f2bf(v);
    return;
  }
  if (bid < 576){
    int idx = (bid-512)*256 + tid;
    int n = idx >> 7, k = idx & 127;
    Wgt[n*128 + k] = f2bf(Wg[k*128 + n]);
    return;
  }
  if (bid < 608){
    int idx = (bid-576)*256 + tid;
    int n = idx >> 7, k = idx & 127;
    float wb = W1[(k+128)*HD + n];
    float wa = W1[k*HD + n];
    Wpq[n*128 + k]      = f2bf(wa + wb);
    Wpq[(64+n)*128 + k] = f2bf(wb);
    return;
  }
  if (bid < 640){
    int idx = (bid-608)*256 + tid;
    int n = idx >> 7, k = idx & 127;
    Wu1t[n*128 + k] = f2bf(Wu1[k*HD + n]);
    return;
  }
  {
    int nn = (bid-640)*2 + (tid >> 7);
    int kk = tid & 127;
    if (kk < 96) Wenct[nn*96 + kk] = f2bf(kk < 80 ? Wenc[kk*128 + nn] : 0.f);
  }
}

// MEGA: per 64-node tile (+16 halo), 512 threads (8 waves) for latency hiding.
__global__ __launch_bounds__(512,2) void k_mega(const float* __restrict__ emb, const float* __restrict__ nf,
    const short* __restrict__ Wenct, const float* __restrict__ benc, const int* __restrict__ adj,
    const short* __restrict__ Wgt, const float* __restrict__ bg, const float* __restrict__ ag,
    const short* __restrict__ Wt, const float* __restrict__ bgru, short* __restrict__ hout){
  __shared__ short NE[96][136];
  __shared__ short T[96][136];
  __shared__ short H1[80][136];
  __shared__ short X[80][136];
  __shared__ float Lp[8][96];
  __shared__ float Ls[96];
  __shared__ float nrmv[96];
  short (*As)[104] = reinterpret_cast<short(*)[104]>(&H1[0][0]);  // enc staging overlay

  int tid = threadIdx.x;
  int blk = blockIdx.x;
  int b = blk >> 4;
  int n0 = (blk & 15) << 6;
  int w = tid >> 6, lane = tid & 63;
  int l15 = lane & 15, quad = lane >> 4;

  // ---- E1: emb norms for 96 frame rows ----
  if (tid < 96){
    int v = (n0 - 16 + tid) & 1023;
    const float4* e4 = reinterpret_cast<const float4*>(&emb[v*E]);
    float ss = 0.f;
    #pragma unroll
    for (int q=0;q<16;q++){ float4 x = e4[q]; ss += x.x*x.x + x.y*x.y + x.z*x.z + x.w*x.w; }
    nrmv[tid] = frcp(fmaxf(sqrtf(ss), 1.f));
  }
  __syncthreads();
  // ---- E2: stage As[96][96] bf16 ----
  for (int e=tid; e<96*16; e+=512){
    int r = e >> 4, q = e & 15;
    int v = (n0 - 16 + r) & 1023;
    float4 x = reinterpret_cast<const float4*>(&emb[v*E])[q];
    float iv = nrmv[r];
    short4 s; s.x=f2bf(x.x*iv); s.y=f2bf(x.y*iv); s.z=f2bf(x.z*iv); s.w=f2bf(x.w*iv);
    *reinterpret_cast<short4*>(&As[r][q*4]) = s;
  }
  for (int e=tid; e<96*4; e+=512){
    int r = e >> 2, q = e & 3;
    int m = (b<<10) + ((n0 - 16 + r) & 1023);
    float4 x = reinterpret_cast<const float4*>(&nf[(long)m*F])[q];
    short4 s; s.x=f2bf(x.x); s.y=f2bf(x.y); s.z=f2bf(x.z); s.w=f2bf(x.w);
    *reinterpret_cast<short4*>(&As[r][64 + q*4]) = s;
    short4 z; z.x=0; z.y=0; z.z=0; z.w=0;
    *reinterpret_cast<short4*>(&As[r][80 + q*4]) = z;
  }
  __syncthreads();
  // ---- E3: encoder MFMA (96 rows x 128 cols, K=96); wave w owns cols 16w..16w+16 ----
  {
    f32x4 acc[6];
    #pragma unroll
    for (int mt=0;mt<6;mt++) acc[mt] = (f32x4){0.f,0.f,0.f,0.f};
    #pragma unroll
    for (int kc=0;kc<3;kc++){
      int k0 = kc*32;
      bf16x8 bfr = *reinterpret_cast<const bf16x8*>(&Wenct[(16*w + l15)*96 + k0 + quad*8]);
      #pragma unroll
      for (int mt=0;mt<6;mt++){
        bf16x8 a = *reinterpret_cast<const bf16x8*>(&As[16*mt + l15][k0 + quad*8]);
        acc[mt] = __builtin_amdgcn_mfma_f32_16x16x32_bf16(a, bfr, acc[mt], 0,0,0);
      }
    }
    int c = 16*w + l15;
    float bb = benc[c];
    #pragma unroll
    for (int mt=0;mt<6;mt++)
      #pragma unroll
      for (int reg=0;reg<4;reg++)
        NE[16*mt + quad*4 + reg][c] = f2bf(acc[mt][reg] + bb);
  }
  __syncthreads();
  // ---- P1: GAT-1 t + logits for 96 rows ----
  {
    f32x4 acc[6];
    #pragma unroll
    for (int mt=0;mt<6;mt++) acc[mt] = (f32x4){0.f,0.f,0.f,0.f};
    #pragma unroll
    for (int kc=0;kc<4;kc++){
      int k0 = kc*32;
      bf16x8 bfr = *reinterpret_cast<const bf16x8*>(&Wgt[(16*w + l15)*128 + k0 + quad*8]);
      #pragma unroll
      for (int mt=0;mt<6;mt++){
        bf16x8 a = *reinterpret_cast<const bf16x8*>(&NE[16*mt + l15][k0 + quad*8]);
        acc[mt] = __builtin_amdgcn_mfma_f32_16x16x32_bf16(a, bfr, acc[mt], 0,0,0);
      }
    }
    int c = 16*w + l15;
    float bgc = bg[c], agc = ag[c];
    float lp[6][4];
    #pragma unroll
    for (int mt=0;mt<6;mt++)
      #pragma unroll
      for (int reg=0;reg<4;reg++){
        float t = ftanh(acc[mt][reg] + bgc);
        T[16*mt + quad*4 + reg][c] = f2bf(t);
        lp[mt][reg] = t * agc;
      }
    #pragma unroll
    for (int mt=0;mt<6;mt++)
      #pragma unroll
      for (int reg=0;reg<4;reg++){
        lp[mt][reg] += __shfl_xor(lp[mt][reg], 1);
        lp[mt][reg] += __shfl_xor(lp[mt][reg], 2);
        lp[mt][reg] += __shfl_xor(lp[mt][reg], 4);
        lp[mt][reg] += __shfl_xor(lp[mt][reg], 8);
      }
    if (l15 == 0){
      #pragma unroll
      for (int mt=0;mt<6;mt++)
        #pragma unroll
        for (int reg=0;reg<4;reg++)
          Lp[w][16*mt + quad*4 + reg] = lp[mt][reg];
    }
  }
  __syncthreads();
  if (tid < 96){
    float s = 0.f;
    #pragma unroll
    for (int i=0;i<8;i++) s += Lp[i][tid];
    Ls[tid] = s;
  }
  __syncthreads();
  // ---- P2: msg1 + x1 for 80 rows -> X[0..80) ----
  if (tid < 320){
    int vl = tid >> 2, seg = tid & 3;
    int wg = (b<<10) + ((n0 - 8 + vl) & 1023);
    int li[16]; float at[16];
    float m = -1e30f;
    #pragma unroll
    for (int d=0; d<16; d++){
      int a = adj[wg*16 + d];
      li[d] = (a - n0 + 16) & 1023;
      m = fmaxf(m, Ls[li[d]]);
    }
    float s = 0.f;
    #pragma unroll
    for (int d=0; d<16; d++){ at[d] = __expf(Ls[li[d]] - m); s += at[d]; }
    float inv = frcp(s);
    #pragma unroll
    for (int d=0; d<16; d++) at[d] *= inv;
    #pragma unroll
    for (int c8=0; c8<4; c8++){
      int c = seg*32 + c8*8;
      float acc8[8] = {0,0,0,0,0,0,0,0};
      #pragma unroll 4
      for (int d=0; d<16; d++){
        bf16x8 tv = *reinterpret_cast<const bf16x8*>(&T[li[d]][c]);
        float a = at[d];
        #pragma unroll
        for (int q=0;q<8;q++) acc8[q] += a * bf2f(tv[q]);
      }
      bf16x8 nv = *reinterpret_cast<const bf16x8*>(&NE[vl + 8][c]);
      bf16x8 xv;
      #pragma unroll
      for (int q=0;q<8;q++) xv[q] = f2bf(ftanh(acc8[q] + bf2f(nv[q])));
      *reinterpret_cast<bf16x8*>(&X[vl][c]) = xv;
    }
  }
  __syncthreads();
  // ---- P3: GRU-1 for 80 rows: wave w owns gate-col j = 16w+l15 in all groups ----
  {
    f32x4 acc[5][4];
    #pragma unroll
    for (int mt=0;mt<5;mt++)
      #pragma unroll
      for (int g=0;g<4;g++) acc[mt][g] = (f32x4){0.f,0.f,0.f,0.f};
    for (int k8=0;k8<8;k8++){
      int k0 = k8*32;
      int gg = (k8 < 4) ? 2 : 3;
      int ncol = 16*w + l15;
      int koff = k0 + quad*8;
      bf16x8 bz = *reinterpret_cast<const bf16x8*>(&Wt[(ncol      )*256 + koff]);
      bf16x8 br = *reinterpret_cast<const bf16x8*>(&Wt[(ncol + 128)*256 + koff]);
      bf16x8 bc = *reinterpret_cast<const bf16x8*>(&Wt[(ncol + gg*128)*256 + koff]);
      #pragma unroll
      for (int mt=0;mt<5;mt++){
        bf16x8 a;
        if (k8 < 4) a = *reinterpret_cast<const bf16x8*>(&X[16*mt + l15][k0 + quad*8]);
        else        a = *reinterpret_cast<const bf16x8*>(&NE[16*mt + l15 + 8][k0 - 128 + quad*8]);
        acc[mt][0]  = __builtin_amdgcn_mfma_f32_16x16x32_bf16(a, bz, acc[mt][0], 0,0,0);
        acc[mt][1]  = __builtin_amdgcn_mfma_f32_16x16x32_bf16(a, br, acc[mt][1], 0,0,0);
        acc[mt][gg] = __builtin_amdgcn_mfma_f32_16x16x32_bf16(a, bc, acc[mt][gg], 0,0,0);
      }
    }
    int j = 16*w + l15;
    float bjz = bgru[j], bjr = bgru[128 + j], bjc = bgru[256 + j];
    #pragma unroll
    for (int mt=0;mt<5;mt++){
      #pragma unroll
      for (int reg=0;reg<4;reg++){
        int rl = 16*mt + quad*4 + reg;
        float z = fsig(acc[mt][0][reg] + bjz);
        float r = fsig(acc[mt][1][reg] + bjr);
        float cand = ftanh(acc[mt][2][reg] + bjc + r*acc[mt][3][reg]);
        float ho = bf2f(NE[rl + 8][j]);
        H1[rl][j] = f2bf(z*ho + (1.f - z)*cand);
      }
    }
  }
  __syncthreads();
  // ---- P4: GAT-2 t + logits for 80 rows ----
  {
    f32x4 acc[5];
    #pragma unroll
    for (int mt=0;mt<5;mt++) acc[mt] = (f32x4){0.f,0.f,0.f,0.f};
    #pragma unroll
    for (int kc=0;kc<4;kc++){
      int k0 = kc*32;
      bf16x8 bfr = *reinterpret_cast<const bf16x8*>(&Wgt[(16*w + l15)*128 + k0 + quad*8]);
      #pragma unroll
      for (int mt=0;mt<5;mt++){
        bf16x8 a = *reinterpret_cast<const bf16x8*>(&H1[16*mt + l15][k0 + quad*8]);
        acc[mt] = __builtin_amdgcn_mfma_f32_16x16x32_bf16(a, bfr, acc[mt], 0,0,0);
      }
    }
    int c = 16*w + l15;
    float bgc = bg[c], agc = ag[c];
    float lp[5][4];
    #pragma unroll
    for (int mt=0;mt<5;mt++)
      #pragma unroll
      for (int reg=0;reg<4;reg++){
        float t = ftanh(acc[mt][reg] + bgc);
        T[16*mt + quad*4 + reg][c] = f2bf(t);
        lp[mt][reg] = t * agc;
      }
    #pragma unroll
    for (int mt=0;mt<5;mt++)
      #pragma unroll
      for (int reg=0;reg<4;reg++){
        lp[mt][reg] += __shfl_xor(lp[mt][reg], 1);
        lp[mt][reg] += __shfl_xor(lp[mt][reg], 2);
        lp[mt][reg] += __shfl_xor(lp[mt][reg], 4);
        lp[mt][reg] += __shfl_xor(lp[mt][reg], 8);
      }
    if (l15 == 0){
      #pragma unroll
      for (int mt=0;mt<5;mt++)
        #pragma unroll
        for (int reg=0;reg<4;reg++)
          Lp[w][16*mt + quad*4 + reg] = lp[mt][reg];
    }
  }
  __syncthreads();
  if (tid < 80){
    float s = 0.f;
    #pragma unroll
    for (int i=0;i<8;i++) s += Lp[i][tid];
    Ls[tid] = s;
  }
  __syncthreads();
  // ---- P5: msg2 + x2 for 64 owned -> X[0..64) ----
  if (tid < 256){
    int vl = tid >> 2, seg = tid & 3;
    int vg = (b<<10) + n0 + vl;
    int li[16]; float at[16];
    float m = -1e30f;
    #pragma unroll
    for (int d=0; d<16; d++){
      int a = adj[vg*16 + d];
      li[d] = (a - n0 + 8) & 1023;
      m = fmaxf(m, Ls[li[d]]);
    }
    float s = 0.f;
    #pragma unroll
    for (int d=0; d<16; d++){ at[d] = __expf(Ls[li[d]] - m); s += at[d]; }
    float inv = frcp(s);
    #pragma unroll
    for (int d=0; d<16; d++) at[d] *= inv;
    #pragma unroll
    for (int c8=0; c8<4; c8++){
      int c = seg*32 + c8*8;
      float acc8[8] = {0,0,0,0,0,0,0,0};
      #pragma unroll 4
      for (int d=0; d<16; d++){
        bf16x8 tv = *reinterpret_cast<const bf16x8*>(&T[li[d]][c]);
        float a = at[d];
        #pragma unroll
        for (int q=0;q<8;q++) acc8[q] += a * bf2f(tv[q]);
      }
      bf16x8 nv = *reinterpret_cast<const bf16x8*>(&NE[vl + 16][c]);
      bf16x8 xv;
      #pragma unroll
      for (int q=0;q<8;q++) xv[q] = f2bf(ftanh(acc8[q] + bf2f(nv[q])));
      *reinterpret_cast<bf16x8*>(&X[vl][c]) = xv;
    }
  }
  __syncthreads();
  // ---- P6: GRU-2 for 64 owned ----
  {
    f32x4 acc[4][4];
    #pragma unroll
    for (int mt=0;mt<4;mt++)
      #pragma unroll
      for (int g=0;g<4;g++) acc[mt][g] = (f32x4){0.f,0.f,0.f,0.f};
    for (int k8=0;k8<8;k8++){
      int k0 = k8*32;
      int gg = (k8 < 4) ? 2 : 3;
      int ncol = 16*w + l15;
      int koff = k0 + quad*8;
      bf16x8 bz = *reinterpret_cast<const bf16x8*>(&Wt[(ncol      )*256 + koff]);
      bf16x8 br = *reinterpret_cast<const bf16x8*>(&Wt[(ncol + 128)*256 + koff]);
      bf16x8 bc = *reinterpret_cast<const bf16x8*>(&Wt[(ncol + gg*128)*256 + koff]);
      #pragma unroll
      for (int mt=0;mt<4;mt++){
        bf16x8 a;
        if (k8 < 4) a = *reinterpret_cast<const bf16x8*>(&X[16*mt + l15][k0 + quad*8]);
        else        a = *reinterpret_cast<const bf16x8*>(&H1[16*mt + l15 + 8][k0 - 128 + quad*8]);
        acc[mt][0]  = __builtin_amdgcn_mfma_f32_16x16x32_bf16(a, bz, acc[mt][0], 0,0,0);
        acc[mt][1]  = __builtin_amdgcn_mfma_f32_16x16x32_bf16(a, br, acc[mt][1], 0,0,0);
        acc[mt][gg] = __builtin_amdgcn_mfma_f32_16x16x32_bf16(a, bc, acc[mt][gg], 0,0,0);
      }
    }
    __syncthreads();   // X is MFMA input above, epilogue output below
    int j = 16*w + l15;
    float bjz = bgru[j], bjr = bgru[128 + j], bjc = bgru[256 + j];
    #pragma unroll
    for (int mt=0;mt<4;mt++){
      #pragma unroll
      for (int reg=0;reg<4;reg++){
        int rl = 16*mt + quad*4 + reg;
        float z = fsig(acc[mt][0][reg] + bjz);
        float r = fsig(acc[mt][1][reg] + bjr);
        float cand = ftanh(acc[mt][2][reg] + bjc + r*acc[mt][3][reg]);
        float ho = bf2f(H1[rl + 8][j]);
        X[rl][j] = f2bf(z*ho + (1.f - z)*cand);
      }
    }
  }
  __syncthreads();
  for (int idx=tid; idx<64*16; idx+=512){
    int r = idx >> 4, c8 = idx & 15;
    *reinterpret_cast<bf16x8*>(&hout[(long)((b<<10) + n0 + r)*128 + c8*8]) =
        *reinterpret_cast<const bf16x8*>(&X[r][c8*8]);
  }
}

// Fused decoder + dest-attn + sparsemax + dual-vars, 512 threads.
__global__ __launch_bounds__(512,2) void k_decdas(const short* __restrict__ hn, const int* __restrict__ adj,
    const int* __restrict__ invadj, const short* __restrict__ Wpq, const float* __restrict__ b1,
    const float* __restrict__ W2, const float* __restrict__ b2_,
    const short* __restrict__ Wu1t, const float* __restrict__ bu1, const float* __restrict__ Wu2,
    const float* __restrict__ bu2_, float* __restrict__ norm_, float* __restrict__ dv){
  __shared__ short Hs[112][136];
  __shared__ short PQb[112][132];
  __shared__ short NSs[64][136];
  __shared__ int adjL[64][16];
  __shared__ float dvp[64][4];
  __shared__ float b1s[64], w2s[64], bu1s[64], wu2s[64];
  int tid = threadIdx.x;
  int blk = blockIdx.x;
  int b = blk >> 4;
  int n0 = (blk & 15) << 6;
  if (tid < 64){ b1s[tid] = b1[tid]; w2s[tid] = W2[tid]; bu1s[tid] = bu1[tid]; wu2s[tid] = Wu2[tid]; }
  for (int idx=tid; idx<112*16; idx+=512){
    int r = idx >> 4, c8 = idx & 15;
    int g = (b << 10) + ((n0 - 24 + r) & 1023);
    *reinterpret_cast<bf16x8*>(&Hs[r][c8*8]) =
        *reinterpret_cast<const bf16x8*>(&hn[(long)g*128 + c8*8]);
  }
  for (int idx=tid; idx<1024; idx+=512){
    int r = idx >> 4, d = idx & 15;
    int a = adj[((b<<10) + n0 + r)*16 + d];
    adjL[r][d] = (a - n0 + 24) & 1023;
  }
  __syncthreads();
  int w = tid >> 6, lane = tid & 63;
  int l15 = lane & 15, quad = lane >> 4;
  // ---- PQ GEMM: wave w owns cols 16w..16w+16 ----
  {
    f32x4 acc[7];
    #pragma unroll
    for (int mt=0;mt<7;mt++) acc[mt] = (f32x4){0.f,0.f,0.f,0.f};
    #pragma unroll
    for (int kc=0;kc<4;kc++){
      int k0 = kc*32;
      bf16x8 bfr = *reinterpret_cast<const bf16x8*>(&Wpq[(16*w + l15)*128 + k0 + quad*8]);
      #pragma unroll
      for (int mt=0;mt<7;mt++){
        bf16x8 a = *reinterpret_cast<const bf16x8*>(&Hs[16*mt + l15][k0 + quad*8]);
        acc[mt] = __builtin_amdgcn_mfma_f32_16x16x32_bf16(a, bfr, acc[mt], 0,0,0);
      }
    }
    int c = 16*w + l15;
    #pragma unroll
    for (int mt=0;mt<7;mt++)
      #pragma unroll
      for (int reg=0;reg<4;reg++)
        PQb[16*mt + quad*4 + reg][c] = f2bf(acc[mt][reg]);
  }
  // ---- node_states gather ----
  for (int idx=tid; idx<64*16; idx+=512){
    int r = idx >> 4, c8 = idx & 15;
    float acc8[8] = {0,0,0,0,0,0,0,0};
    #pragma unroll 4
    for (int d=0; d<16; d++){
      bf16x8 hv = *reinterpret_cast<const bf16x8*>(&Hs[adjL[r][d]][c8*8]);
      #pragma unroll
      for (int q=0;q<8;q++) acc8[q] += bf2f(hv[q]);
    }
    bf16x8 sv;
    #pragma unroll
    for (int q=0;q<8;q++) sv[q] = f2bf(acc8[q]);
    *reinterpret_cast<bf16x8*>(&NSs[r][c8*8]) = sv;
  }
  __syncthreads();
  // ---- dual MLP MFMA on waves 0-3 ----
  if (w < 4){
    f32x4 acc[4];
    #pragma unroll
    for (int mt=0;mt<4;mt++) acc[mt] = (f32x4){0.f,0.f,0.f,0.f};
    #pragma unroll
    for (int kc=0;kc<4;kc++){
      int k0 = kc*32;
      bf16x8 bfr = *reinterpret_cast<const bf16x8*>(&Wu1t[(16*w + l15)*128 + k0 + quad*8]);
      #pragma unroll
      for (int mt=0;mt<4;mt++){
        bf16x8 a = *reinterpret_cast<const bf16x8*>(&NSs[16*mt + l15][k0 + quad*8]);
        acc[mt] = __builtin_amdgcn_mfma_f32_16x16x32_bf16(a, bfr, acc[mt], 0,0,0);
      }
    }
    int n = 16*w + l15;
    float bn = bu1s[n], wn = wu2s[n];
    #pragma unroll
    for (int mt=0;mt<4;mt++){
      #pragma unroll
      for (int reg=0;reg<4;reg++){
        float p = ftanh(acc[mt][reg] + bn) * wn;
        p += __shfl_xor(p, 1);
        p += __shfl_xor(p, 2);
        p += __shfl_xor(p, 4);
        p += __shfl_xor(p, 8);
        if (l15 == 0) dvp[16*mt + quad*4 + reg][w] = p;
      }
    }
  }
  __syncthreads();
  float* nws = reinterpret_cast<float*>(&Hs[0][0]);   // [96][17]
  float b2v = b2_[0];
  for (int e = tid; e < 96*16; e += 512){
    int rr = e >> 4, d = e & 15;
    int wnode = (n0 + rr - 16) & 1023;
    int wg = (b<<10) + wnode;
    int a = adj[wg*16 + d];
    int al = (a - n0 + 24) & 1023;
    int wl = rr + 8;
    float p = 0.f;
    #pragma unroll 8
    for (int c=0;c<64;c++)
      p += ftanh(bf2f(PQb[al][c]) + bf2f(PQb[wl][64 + c]) + b1s[c]) * w2s[c];
    nws[rr*17 + d] = p + b2v;
  }
  __syncthreads();
  if (tid < 64){
    float val = dvp[tid][0]+dvp[tid][1]+dvp[tid][2]+dvp[tid][3];
    dv[(b<<10) + n0 + tid] = fmaxf(val + bu2_[0], 0.f);
  }
  float* datt = reinterpret_cast<float*>(&PQb[0][0]); // [80][17]
  if (tid < 80){
    int wnode = (n0 + tid - 8) & 1023;
    int wg = (b<<10) + wnode;
    float vals[16];
    float m = -1e30f;
    #pragma unroll
    for (int d=0; d<16; d++){
      int iv = invadj[wg*16 + d];
      int il = (iv - n0 + 16) & 1023;
      vals[d] = nws[il*17 + d];
      m = fmaxf(m, vals[d]);
    }
    float s = 0.f;
    #pragma unroll
    for (int d=0; d<16; d++){ vals[d] = __expf(vals[d]-m); s += vals[d]; }
    float inv = frcp(s);
    #pragma unroll
    for (int d=0; d<16; d++) datt[tid*17 + d] = vals[d]*inv;
  }
  __syncthreads();
  if (tid < 64){
    int vg = (b<<10) + n0 + tid;
    float z[16], s[16];
    #pragma unroll
    for (int d=0; d<16; d++){
      int al = adjL[tid][d] - 16;
      z[d] = datt[al*17 + d];
      s[d] = z[d];
    }
    #pragma unroll
    for (int k2 = 2; k2 <= 16; k2 <<= 1){
      #pragma unroll
      for (int jj = k2 >> 1; jj > 0; jj >>= 1){
        #pragma unroll
        for (int i = 0; i < 16; i++){
          int l = i ^ jj;
          if (l > i){
            bool up = ((i & k2) == 0);
            float a = s[i], bb = s[l];
            bool sw = up ? (a > bb) : (a < bb);
            if (sw){ s[i]=bb; s[l]=a; }
          }
        }
      }
    }
    float cs = 0.f, zcs = 0.f; int kz = 1;
    #pragma unroll
    for (int j=0;j<16;j++){
      float zj = s[15-j];
      cs += zj;
      if (1.f + (float)(j+1)*zj > cs){ kz = j+1; zcs = cs; }
    }
    float tau = (zcs - 1.f)/(float)kz;
    #pragma unroll
    for (int d=0; d<16; d++) norm_[(long)vg*16 + d] = fmaxf(z[d]-tau, 0.f);
  }
}

// Fused flow solver + dual cost + dual demand + final output. (unchanged)
__global__ __launch_bounds__(1024) void k_flowfin(const float* __restrict__ norm_,
    const float* __restrict__ dem, const int* __restrict__ invadj, const float* __restrict__ dv,
    float* __restrict__ out){
  __shared__ float nrmS[V*17];
  __shared__ float sbuf[2][V];
  __shared__ float r1[16], r2[16], r3[16];
  int b = blockIdx.x, v = threadIdx.x;
  int gv = (b<<10) + v;
  {
    const float4* src = reinterpret_cast<const float4*>(&norm_[(long)gv*16]);
    #pragma unroll
    for (int q4=0; q4<4; q4++){
      float4 x = src[q4];
      nrmS[v*17 + q4*4+0] = x.x; nrmS[v*17 + q4*4+1] = x.y;
      nrmS[v*17 + q4*4+2] = x.z; nrmS[v*17 + q4*4+3] = x.w;
    }
  }
  int iv[16];
  #pragma unroll
  for (int d4=0; d4<4; d4++){
    int4 i4 = reinterpret_cast<const int4*>(&invadj[(long)gv*16])[d4];
    iv[d4*4+0]=i4.x; iv[d4*4+1]=i4.y; iv[d4*4+2]=i4.z; iv[d4*4+3]=i4.w;
  }
  float dm = dem[gv];
  sbuf[0][v] = 0.f;
  __syncthreads();
  float nrg[16]; float nr2 = 0.f;
  #pragma unroll
  for (int d=0; d<16; d++){
    nrg[d] = nrmS[iv[d]*17 + d];
    float nv = nrmS[v*17 + d];
    nr2 += nv*nv;
  }
  int p = 0;
  float s = 0.f;
  for (int it=0; it<10; it++){
    float inflow = 0.f;
    #pragma unroll
    for (int d=0; d<16; d++) inflow += nrg[d]*sbuf[p][iv[d]];
    s = fmaxf(inflow - dm, 0.f);
    sbuf[1-p][v] = s;
    p ^= 1;
    __syncthreads();
  }
  float partF = nr2 * s * s;
  float dvv = dv[gv];
  float f = 0.f, vel = 0.f;
  #pragma unroll
  for (int it=0; it<10; it++){
    float g = 2.f*f + dvv;
    vel = 0.9f*vel - 0.01f*g;
    f = fmaxf(f + vel, 0.f);
  }
  float partD = f*f + dvv*f;
  float partDD = dvv * dm;
  #pragma unroll
  for (int off=32; off>0; off>>=1){
    partF  += __shfl_down(partF, off);
    partD  += __shfl_down(partD, off);
    partDD += __shfl_down(partDD, off);
  }
  if ((v & 63) == 0){ r1[v>>6] = partF; r2[v>>6] = partD; r3[v>>6] = partDD; }
  __syncthreads();
  if (v == 0){
    float sf = 0.f, sd = 0.f, sdd = 0.f;
    #pragma unroll
    for (int i=0;i<16;i++){ sf += r1[i]; sd += r2[i]; sdd += r3[i]; }
    out[b] = sf - (16.f*sd - sdd);
  }
}

extern "C" void kernel_launch(void* const* d_in, const int* in_sizes, int n_in,
                              void* d_out, int out_size, void* d_ws, size_t ws_size,
                              hipStream_t stream){
  (void)in_sizes; (void)n_in; (void)out_size; (void)ws_size;
  const float* demands = (const float*)d_in[0];
  const float* nf      = (const float*)d_in[1];
  const float* emb     = (const float*)d_in[4];
  const float* Wenc    = (const float*)d_in[5];
  const float* benc    = (const float*)d_in[6];
  const float* Wgat    = (const float*)d_in[7];
  const float* bgat    = (const float*)d_in[8];
  const float* agat    = (const float*)d_in[9];
  const float* Wgx     = (const float*)d_in[10];
  const float* Wgh     = (const float*)d_in[11];
  const float* bgru    = (const float*)d_in[12];
  const float* Wd1     = (const float*)d_in[13];
  const float* bd1     = (const float*)d_in[14];
  const float* Wd2     = (const float*)d_in[15];
  const float* bd2     = (const float*)d_in[16];
  const float* Wu1     = (const float*)d_in[17];
  const float* bu1     = (const float*)d_in[18];
  const float* Wu2     = (const float*)d_in[19];
  const float* bu2     = (const float*)d_in[20];
  const int* adj       = (const int*)d_in[21];
  const int* invadj    = (const int*)d_in[22];

  float* ws    = (float*)d_ws;
  short* hnB   = (short*)(ws + OFF_HNB);
  float* nrm   = ws + OFF_NORM;
  float* dv    = ws + OFF_DV;
  short* wt    = (short*)(ws + OFF_WT);
  short* wtg   = (short*)(ws + OFF_WTG);
  short* wpq   = (short*)(ws + OFF_WPQ);
  short* wu1t  = (short*)(ws + OFF_WU1T);
  short* wenct = (short*)(ws + OFF_WENCT);

  k_pre<<<704, 256, 0, stream>>>(Wgx, Wgh, Wgat, Wd1, Wu1, Wenc, wt, wtg, wpq, wu1t, wenct);
  k_mega<<<BV/64, 512, 0, stream>>>(emb, nf, wenct, benc, adj, wtg, bgat, agat, wt, bgru, hnB);
  k_decdas<<<BV/64, 512, 0, stream>>>(hnB, adj, invadj, wpq, bd1, Wd2, bd2,
                                      wu1t, bu1, Wu2, bu2, nrm, dv);
  k_flowfin<<<B, 1024, 0, stream>>>(nrm, demands, invadj, dv, (float*)d_out);
}